// Round 3
// baseline (21907.118 us; speedup 1.0000x reference)
//
#include <hip/hip_runtime.h>
#include <stdint.h>

#define B_  8
#define N_  256
#define DE_ 768
#define DH_ 192
#define L_  2
#define G3  576     // 3*DH
#define G6  1152    // 6*DH

__device__ __forceinline__ float bflo(uint32_t u) { return __uint_as_float(u << 16); }
__device__ __forceinline__ float bfhi(uint32_t u) { return __uint_as_float(u & 0xffff0000u); }
__device__ __forceinline__ uint32_t f2bf(float f) {
    uint32_t x = __float_as_uint(f);
    x += 0x7fffu + ((x >> 16) & 1u);          // RNE
    return x >> 16;
}
__device__ __forceinline__ float sigm(float x)  { return 1.f / (1.f + __expf(-x)); }
__device__ __forceinline__ float tanhf_(float x){ return 1.f - 2.f / (1.f + __expf(2.f * x)); }

// ---------------------------------------------------------------------------
// Prepack:
//   WpreT fp32 [k][r]   : rows [cwih | pwhh]  (PRE GEMM)
//   WbigT bf16 [k][r]   : rows [cwhh | pwih]  (per-step matvec from M)
//   Wpair u32  [k][d]   : pack(wr0[d][k], wr1[d][k])  (production matvec)
//   biasPre = [cbih | pbhh], gbias = [cbhh | pbih]
// ---------------------------------------------------------------------------
__global__ void prepack_kernel(
    const float* __restrict__ wr0, const float* __restrict__ wr1,
    const float* __restrict__ c_wih, const float* __restrict__ c_whh,
    const float* __restrict__ c_bih, const float* __restrict__ c_bhh,
    const float* __restrict__ p_wih, const float* __restrict__ p_whh,
    const float* __restrict__ p_bih, const float* __restrict__ p_bhh,
    float* __restrict__ WpreT, unsigned short* __restrict__ WbigT,
    uint32_t* __restrict__ Wpair, float* __restrict__ biasPre, float* __restrict__ gbias)
{
    int idx = blockIdx.x * blockDim.x + threadIdx.x;
    if (idx >= DH_ * G6) return;
    int k = idx / G6, r = idx - k * G6;
    for (int l = 0; l < L_; ++l) {
        const float* cwih = c_wih + l * G3 * DH_;
        const float* cwhh = c_whh + l * G3 * DH_;
        const float* pwih = p_wih + l * G3 * DH_;
        const float* pwhh = p_whh + l * G3 * DH_;
        float wpre = (r < G3) ? cwih[r * DH_ + k] : pwhh[(r - G3) * DH_ + k];
        WpreT[l * DH_ * G6 + k * G6 + r] = wpre;
        float wbig = (r < G3) ? cwhh[r * DH_ + k] : pwih[(r - G3) * DH_ + k];
        WbigT[l * DH_ * G6 + k * G6 + r] = (unsigned short)f2bf(wbig);
        if (idx < DH_ * DH_) {
            int kk = idx / DH_, d = idx - kk * DH_;
            uint32_t pk = f2bf(wr0[l * DH_ * DH_ + d * DH_ + kk])
                        | (f2bf(wr1[l * DH_ * DH_ + d * DH_ + kk]) << 16);
            Wpair[l * DH_ * DH_ + kk * DH_ + d] = pk;
        }
        if (idx < G6) {
            biasPre[l * G6 + idx] = (idx < G3) ? c_bih[l * G3 + idx] : p_bhh[l * G3 + idx - G3];
            gbias [l * G6 + idx] = (idx < G3) ? c_bhh[l * G3 + idx] : p_bih[l * G3 + idx - G3];
        }
    }
}

// ---------------------------------------------------------------------------
// Generic small GEMM (parallel phases): C = relu?(A @ B + bias)
// ---------------------------------------------------------------------------
#define GR 8
__global__ __launch_bounds__(192) void gemm_kernel(
    const float* __restrict__ A, int lda, const float* __restrict__ Bm,
    const float* __restrict__ bias, float* __restrict__ C, int ldc,
    int K, int cols, int relu)
{
    __shared__ float sA[GR][64];
    const int c  = blockIdx.y * 192 + threadIdx.x;
    const int r0 = blockIdx.x * GR;
    float acc[GR] = {0.f, 0.f, 0.f, 0.f, 0.f, 0.f, 0.f, 0.f};
    for (int k0 = 0; k0 < K; k0 += 64) {
        for (int idx = threadIdx.x; idx < GR * 64; idx += 192) {
            int rr = idx >> 6, kk = idx & 63;
            sA[rr][kk] = A[(size_t)(r0 + rr) * lda + k0 + kk];
        }
        __syncthreads();
        #pragma unroll 8
        for (int kk = 0; kk < 64; ++kk) {
            float bv = Bm[(size_t)(k0 + kk) * cols + c];
            #pragma unroll
            for (int rr = 0; rr < GR; ++rr) acc[rr] += sA[rr][kk] * bv;
        }
        __syncthreads();
    }
    float bv = bias[c];
    #pragma unroll
    for (int rr = 0; rr < GR; ++rr) {
        float v = acc[rr] + bv;
        if (relu) v = fmaxf(v, 0.f);
        C[(size_t)(r0 + rr) * ldc + c] = v;
    }
}

// ---------------------------------------------------------------------------
// Sequential scan: one WG per batch, 256 steps, 8 barriers/step.
// Streaming loops use explicit 16-deep uint32 load batches (16 VGPRs) for MLP.
// Scalar per-step reads (adj/smask/x/PRE rows) prefetched one step ahead.
// Softmax computed without max-subtraction (scores provably in +-~3).
// ---------------------------------------------------------------------------
__global__ __launch_bounds__(576) void scan_kernel(
    const float* __restrict__ xin,  float* __restrict__ hout,
    const float* __restrict__ PRE,  const float* __restrict__ adj,
    const float* __restrict__ smask,
    const uint32_t* __restrict__ Wbig32,   // [192][576] dwords: (col 2t, col 2t+1)
    const uint32_t* __restrict__ Wpair32,  // [192][192] dwords: (wr0[d][k], wr1[d][k])
    const float* __restrict__ gbias, const float* __restrict__ gatw, // [384] = wq|wk
    uint32_t* __restrict__ V32, float* __restrict__ As)
{
    const int b = blockIdx.x;
    const int t = threadIdx.x;
    const int wave = t >> 6, lane = t & 63;
    const int g3i = t / DH_;            // 0..2
    const int dd  = t - g3i * DH_;      // 0..191

    __shared__ float sKsc[N_], sA0[N_], sA1[N_];
    __shared__ float sX[DH_], sM[DH_], sH[DH_];
    __shared__ float sG[G6];
    __shared__ float sRedS[4], sRedX[3], sRedK[3];

    const float* adjB = adj   + (size_t)b * N_ * N_;
    const float* smB  = smask + (size_t)b * N_ * N_;
    float* AsB        = As    + (size_t)b * (L_ * N_ * N_);
    uint32_t* V32b    = V32   + (size_t)b * N_ * DH_;

    // ---- persistent registers (loaded once) --------------------------------
    float wqv = 0.f, wkv = 0.f;
    float gb0 = 0.f, gb1 = 0.f, gb2 = 0.f, gb3 = 0.f, gb4 = 0.f, gb5 = 0.f;
    float xv = 0.f, aAdj = 0.f, aSm = 0.f;
    float p0 = 0.f, p1 = 0.f, p2 = 0.f, p3 = 0.f, p4 = 0.f, p5 = 0.f;
    if (t < DH_) {
        wqv = gatw[t];
        gb0 = gbias[t];        gb1 = gbias[DH_ + t];      gb2 = gbias[2 * DH_ + t];
        gb3 = gbias[G3 + t];   gb4 = gbias[G3 + DH_ + t]; gb5 = gbias[G3 + 2 * DH_ + t];
        xv = xin[(size_t)(b * N_) * G3 + t];
        const float* pn = PRE + (size_t)(b * N_) * G6 + t;
        p0 = pn[0];  p1 = pn[DH_]; p2 = pn[2 * DH_];
        p3 = pn[G3]; p4 = pn[G3 + DH_]; p5 = pn[G3 + 2 * DH_];
    }
    if (t >= 384) wkv = gatw[DH_ + (t - 384)];
    if (t < N_) sKsc[t] = 0.f;
    if (t < DH_) sX[t] = xv;
    {
        float px = (t < DH_) ? xv * wqv : 0.f;
        #pragma unroll
        for (int o = 32; o; o >>= 1) px += __shfl_xor(px, o);
        if (t < DH_ && lane == 0) sRedX[wave] = px;
    }
    __syncthreads();
    float xq = sRedX[0] + sRedX[1] + sRedX[2];

    for (int i = 0; i < N_; ++i) {
        const int row = b * N_ + i;
        if (i == 0) {
            if (t < N_) { sA0[t] = 0.f; sA1[t] = 0.f; AsB[t] = 0.f; }
            if (t < DH_) sM[t] = 0.f;
            if (t < N_) { aAdj = adjB[N_ + t]; aSm = smB[N_ + t]; }      // row 1
            if (t < DH_) xv = xin[(size_t)(row + 1) * G3 + t];
            __syncthreads();
        } else {
            // ---- attention (no max-pass; scores bounded) -------------------
            float e = 0.f;
            if (t < N_ && t < i && aAdj > 0.5f) e = __expf(xq + sKsc[t]);
            float ps = e;
            #pragma unroll
            for (int o = 32; o; o >>= 1) ps += __shfl_xor(ps, o);
            if (wave < 4 && lane == 0) sRedS[wave] = ps;
            __syncthreads();                                             // B1
            float ssum = sRedS[0] + sRedS[1] + sRedS[2] + sRedS[3];
            if (t < N_) {
                float a = e / ssum;
                AsB[(size_t)i * N_ + t] = a;
                float a0 = a * aSm;
                sA0[t] = a0; sA1[t] = a - a0;
            }
            __syncthreads();                                             // B2
            // prefetch next-step scalar rows (drained 2+ kcy later at B3)
            {
                int inx = (i + 1 < N_) ? i + 1 : N_ - 1;
                if (t < N_) { aAdj = adjB[(size_t)inx * N_ + t]; aSm = smB[(size_t)inx * N_ + t]; }
                if (t < DH_) xv = xin[(size_t)(b * N_ + inx) * G3 + t];
            }
            // ---- M-accum: 3-way j split, 8-wide load batches ---------------
            {
                float acc = 0.f;
                const uint32_t* vp = V32b + dd;
                int cnt = (i > g3i) ? (i - g3i + 2) / 3 : 0;
                int j = g3i;
                int nb = cnt >> 3;
                for (int bb = 0; bb < nb; ++bb) {
                    uint32_t wv[8];
                    #pragma unroll
                    for (int e8 = 0; e8 < 8; ++e8) wv[e8] = vp[(size_t)(j + 3 * e8) * DH_];
                    #pragma unroll
                    for (int e8 = 0; e8 < 8; ++e8) {
                        float w0 = sA0[j + 3 * e8], w1 = sA1[j + 3 * e8];
                        acc = fmaf(w0, bflo(wv[e8]), acc);
                        acc = fmaf(w1, bfhi(wv[e8]), acc);
                    }
                    j += 24;
                }
                for (; j < i; j += 3) {
                    uint32_t w = vp[(size_t)j * DH_];
                    acc = fmaf(sA0[j], bflo(w), acc);
                    acc = fmaf(sA1[j], bfhi(w), acc);
                }
                sG[t] = acc;
            }
            __syncthreads();                                             // B3
            if (t < DH_) sM[t] = sG[t] + sG[DH_ + t] + sG[2 * DH_ + t];
            __syncthreads();                                             // B4
        }

        // ---- g = M @ [cwhh|pwih]^T : 576 thr x 2 cols, 16-deep batches -----
        {
            const uint32_t* wp = Wbig32 + t;
            float a0 = 0.f, a1 = 0.f;
            #pragma unroll
            for (int k0 = 0; k0 < DH_; k0 += 16) {
                uint32_t wv[16];
                #pragma unroll
                for (int e16 = 0; e16 < 16; ++e16) wv[e16] = wp[(size_t)(k0 + e16) * G3];
                #pragma unroll
                for (int e16 = 0; e16 < 16; ++e16) {
                    float mk = sM[k0 + e16];
                    a0 = fmaf(mk, bflo(wv[e16]), a0);
                    a1 = fmaf(mk, bfhi(wv[e16]), a1);
                }
            }
            sG[2 * t] = a0; sG[2 * t + 1] = a1;
        }
        __syncthreads();                                                 // B5

        // ---- GRU gates: Hnew = C + P  (PRE/gbias already in registers) ----
        if (t < DH_) {
            float Mv = sM[t], xvv = sX[t];
            float r1 = sigm(p0 + sG[t] + gb0);
            float z1 = sigm(p1 + sG[DH_ + t] + gb1);
            float n1 = tanhf_(p2 + r1 * (sG[2 * DH_ + t] + gb2));
            float Cv = (1.f - z1) * n1 + z1 * Mv;
            float r2 = sigm(sG[G3 + t] + gb3 + p3);
            float z2 = sigm(sG[G3 + DH_ + t] + gb4 + p4);
            float n2 = tanhf_(sG[G3 + 2 * DH_ + t] + gb5 + r2 * p5);
            float Pv = (1.f - z2) * n2 + z2 * xvv;
            float Hn = Cv + Pv;
            sH[t] = Hn;
            hout[(size_t)row * G3 + t] = Hn;
        }
        __syncthreads();                                                 // B6

        // ---- production (+ next-step xq partials + PRE prefetch) -----------
        float pa0 = 0.f, pa1 = 0.f;
        {
            int inx = (i + 1 < N_) ? i + 1 : N_ - 1;
            if (t < DH_) {
                const float* pn = PRE + (size_t)(b * N_ + inx) * G6 + t;
                p0 = pn[0];  p1 = pn[DH_]; p2 = pn[2 * DH_];
                p3 = pn[G3]; p4 = pn[G3 + DH_]; p5 = pn[G3 + 2 * DH_];
            }
            if (t < 2 * DH_) {
                int kp = t / DH_, d = t - kp * DH_;     // kp: k-half, d: pair index
                const uint32_t* pp = Wpair32 + (size_t)(kp * 96) * DH_ + d;
                float a0 = 0.f, a1 = 0.f;
                const float* hh = sH + kp * 96;
                #pragma unroll
                for (int k0 = 0; k0 < 96; k0 += 16) {
                    uint32_t wv[16];
                    #pragma unroll
                    for (int e16 = 0; e16 < 16; ++e16) wv[e16] = pp[(size_t)(k0 + e16) * DH_];
                    #pragma unroll
                    for (int e16 = 0; e16 < 16; ++e16) {
                        float hk = hh[k0 + e16];
                        a0 = fmaf(hk, bflo(wv[e16]), a0);
                        a1 = fmaf(hk, bfhi(wv[e16]), a1);
                    }
                }
                if (kp == 1) { sG[d] = a0; sG[DH_ + d] = a1; }
                else         { pa0 = a0; pa1 = a1; }
            } else if (t >= 384) {
                // Ksc_i = Hnew . wk  on waves 6-8
                float pr = sH[t - 384] * wkv;
                #pragma unroll
                for (int o = 32; o; o >>= 1) pr += __shfl_xor(pr, o);
                if (lane == 0) sRedK[wave - 6] = pr;
            }
            float px = (t < DH_) ? xv * wqv : 0.f;
            #pragma unroll
            for (int o = 32; o; o >>= 1) px += __shfl_xor(px, o);
            if (t < DH_ && lane == 0) sRedX[wave] = px;
            if (t < DH_) sX[t] = xv;
        }
        __syncthreads();                                                 // B7
        if (t < DH_) {
            float f0 = pa0 + sG[t], f1 = pa1 + sG[DH_ + t];
            V32b[(size_t)i * DH_ + t] = f2bf(f0) | (f2bf(f1) << 16);
        }
        if (t == 384) sKsc[i] = sRedK[0] + sRedK[1] + sRedK[2];
        xq = sRedX[0] + sRedX[1] + sRedX[2];
        __syncthreads();                                                 // B8
    }
}

// ---------------------------------------------------------------------------
extern "C" void kernel_launch(void* const* d_in, const int* in_sizes, int n_in,
                              void* d_out, int out_size, void* d_ws, size_t ws_size,
                              hipStream_t stream)
{
    const float* features = (const float*)d_in[0];
    const float* adj      = (const float*)d_in[1];
    const float* smask    = (const float*)d_in[2];
    const float* fc1_w = (const float*)d_in[5];
    const float* fc1_b = (const float*)d_in[6];
    const float* gat_w = (const float*)d_in[7];
    const float* wr0   = (const float*)d_in[9];
    const float* wr1   = (const float*)d_in[10];
    const float* c_wih = (const float*)d_in[11];
    const float* c_whh = (const float*)d_in[12];
    const float* c_bih = (const float*)d_in[13];
    const float* c_bhh = (const float*)d_in[14];
    const float* p_wih = (const float*)d_in[15];
    const float* p_whh = (const float*)d_in[16];
    const float* p_bih = (const float*)d_in[17];
    const float* p_bhh = (const float*)d_in[18];
    const float* mw0 = (const float*)d_in[19];
    const float* mb0 = (const float*)d_in[20];
    const float* mw1 = (const float*)d_in[21];
    const float* mb1 = (const float*)d_in[22];
    const float* mw2 = (const float*)d_in[23];
    const float* mb2 = (const float*)d_in[24];
    float* out = (float*)d_out;

    char* wsb = (char*)d_ws;
    size_t off = 0;
    auto carve = [&](size_t bytes) -> char* {
        char* p = wsb + off;
        off = (off + bytes + 255) & ~(size_t)255;
        return p;
    };
    float* Hcat            = (float*)carve(2048ull * 576 * 4);
    float* PRE             = (float*)carve(2048ull * 1152 * 4);
    float* WpreT           = (float*)carve(2ull * 192 * 1152 * 4);
    float* biasPre         = (float*)carve(2ull * 1152 * 4);
    float* gbias           = (float*)carve(2ull * 1152 * 4);
    unsigned short* WbigT  = (unsigned short*)carve(2ull * 192 * 1152 * 2);
    uint32_t* Wpair        = (uint32_t*)carve(2ull * 192 * 192 * 4);
    uint32_t* V32          = (uint32_t*)carve(8ull * 256 * 192 * 4);
    float* h1 = PRE;
    float* h2 = PRE + 2048 * 192;

    prepack_kernel<<<dim3((192 * 1152 + 255) / 256), 256, 0, stream>>>(
        wr0, wr1, c_wih, c_whh, c_bih, c_bhh, p_wih, p_whh, p_bih, p_bhh,
        WpreT, WbigT, Wpair, biasPre, gbias);

    gemm_kernel<<<dim3(256, 1), 192, 0, stream>>>(features, 768, fc1_w, fc1_b,
                                                  Hcat, 576, 768, 192, 1);
    for (int l = 0; l < 2; ++l) {
        gemm_kernel<<<dim3(256, 6), 192, 0, stream>>>(Hcat + l * 192, 576,
            WpreT + (size_t)l * 192 * 1152, biasPre + l * 1152, PRE, 1152, 192, 1152, 0);
        scan_kernel<<<dim3(8), 576, 0, stream>>>(Hcat + l * 192, Hcat + (l + 1) * 192,
            PRE, adj, smask,
            (const uint32_t*)(WbigT + (size_t)l * 192 * 1152),
            Wpair + (size_t)l * 192 * 192,
            gbias + l * 1152, gat_w + l * 384, V32,
            out + 393216 + l * 65536);
    }
    gemm_kernel<<<dim3(256, 1), 192, 0, stream>>>(Hcat, 576, mw0, mb0, h1, 192, 576, 192, 1);
    gemm_kernel<<<dim3(256, 1), 192, 0, stream>>>(h1, 192, mw1, mb1, h2, 192, 192, 192, 1);
    gemm_kernel<<<dim3(256, 1), 192, 0, stream>>>(h2, 192, mw2, mb2, out, 192, 192, 192, 0);
}

// Round 4
// 19778.697 us; speedup vs baseline: 1.1076x; 1.1076x over previous
//
#include <hip/hip_runtime.h>
#include <stdint.h>

#define B_  8
#define N_  256
#define DH_ 192
#define L_  2
#define G3  576
#define G6  1152

__device__ __forceinline__ float bflo(uint32_t u) { return __uint_as_float(u << 16); }
__device__ __forceinline__ float bfhi(uint32_t u) { return __uint_as_float(u & 0xffff0000u); }
__device__ __forceinline__ uint32_t f2bf(float f) {
    uint32_t x = __float_as_uint(f);
    x += 0x7fffu + ((x >> 16) & 1u);          // RNE
    return x >> 16;
}
__device__ __forceinline__ float sigm(float x)  { return 1.f / (1.f + __expf(-x)); }
__device__ __forceinline__ float tanhf_(float x){ return 1.f - 2.f / (1.f + __expf(2.f * x)); }

// ---------------------------------------------------------------------------
// Prepack per layer:
//   WpreT  fp32 [192 k][1152 r] : rows [cwih | pwhh]     (PRE GEMM, B-matrix)
//   W2     u32  [96 p][1152 c]  : pack(bf(Wbig[2p][c]), bf(Wbig[2p+1][c]))
//                                 Wbig[k][c] = (c<576)? cwhh[c][k] : pwih[c-576][k]
//   Wp32   u32  [192 k][192 d]  : pack(bf(wr0[d][k]), bf(wr1[d][k]))
//   biasPre fp32 [1152]         : [cbih|pbhh] with gbias folds for gate cols
//   gbx    fp32 [384]           : [cbhh[384..575] | pbih[384..575]]  (g2,g5)
// ---------------------------------------------------------------------------
__global__ void prepack_kernel(
    const float* __restrict__ wr0, const float* __restrict__ wr1,
    const float* __restrict__ c_wih, const float* __restrict__ c_whh,
    const float* __restrict__ c_bih, const float* __restrict__ c_bhh,
    const float* __restrict__ p_wih, const float* __restrict__ p_whh,
    const float* __restrict__ p_bih, const float* __restrict__ p_bhh,
    float* __restrict__ WpreT, uint32_t* __restrict__ W2,
    uint32_t* __restrict__ Wp32, float* __restrict__ biasPre, float* __restrict__ gbx)
{
    int idx = blockIdx.x * blockDim.x + threadIdx.x;
    if (idx >= DH_ * G6) return;
    for (int l = 0; l < L_; ++l) {
        const float* cwih = c_wih + l * G3 * DH_;
        const float* cwhh = c_whh + l * G3 * DH_;
        const float* pwih = p_wih + l * G3 * DH_;
        const float* pwhh = p_whh + l * G3 * DH_;
        {   // WpreT
            int k = idx / G6, r = idx - k * G6;
            float w = (r < G3) ? cwih[r * DH_ + k] : pwhh[(r - G3) * DH_ + k];
            WpreT[l * DH_ * G6 + k * G6 + r] = w;
        }
        if (idx < 96 * G6) {   // W2
            int p = idx / G6, c = idx - p * G6;
            float w0 = (c < G3) ? cwhh[c * DH_ + 2 * p]     : pwih[(c - G3) * DH_ + 2 * p];
            float w1 = (c < G3) ? cwhh[c * DH_ + 2 * p + 1] : pwih[(c - G3) * DH_ + 2 * p + 1];
            W2[l * 96 * G6 + p * G6 + c] = f2bf(w0) | (f2bf(w1) << 16);
        }
        if (idx < DH_ * DH_) {  // Wp32
            int k = idx / DH_, d = idx - k * DH_;
            Wp32[l * DH_ * DH_ + k * DH_ + d] =
                f2bf(wr0[l * DH_ * DH_ + d * DH_ + k]) |
                (f2bf(wr1[l * DH_ * DH_ + d * DH_ + k]) << 16);
        }
        if (idx < G6) {  // biasPre with folds
            float base = (idx < G3) ? c_bih[l * G3 + idx] : p_bhh[l * G3 + idx - G3];
            float fold = 0.f;
            if (idx < 384)                    fold = c_bhh[l * G3 + idx];
            else if (idx >= G3 && idx < 960)  fold = p_bih[l * G3 + idx - G3];
            biasPre[l * G6 + idx] = base + fold;
        }
        if (idx < 384) {
            gbx[l * 384 + idx] = (idx < DH_) ? c_bhh[l * G3 + 384 + idx]
                                             : p_bih[l * G3 + 384 + (idx - DH_)];
        }
    }
}

// ---------------------------------------------------------------------------
// Generic small GEMM (parallel phases): C = relu?(A @ B + bias)
// ---------------------------------------------------------------------------
#define GR 8
__global__ __launch_bounds__(192) void gemm_kernel(
    const float* __restrict__ A, int lda, const float* __restrict__ Bm,
    const float* __restrict__ bias, float* __restrict__ C, int ldc,
    int K, int cols, int relu)
{
    __shared__ float sA[GR][64];
    const int c  = blockIdx.y * 192 + threadIdx.x;
    const int r0 = blockIdx.x * GR;
    float acc[GR] = {0.f, 0.f, 0.f, 0.f, 0.f, 0.f, 0.f, 0.f};
    for (int k0 = 0; k0 < K; k0 += 64) {
        for (int idx = threadIdx.x; idx < GR * 64; idx += 192) {
            int rr = idx >> 6, kk = idx & 63;
            sA[rr][kk] = A[(size_t)(r0 + rr) * lda + k0 + kk];
        }
        __syncthreads();
        #pragma unroll 8
        for (int kk = 0; kk < 64; ++kk) {
            float bv = Bm[(size_t)(k0 + kk) * cols + c];
            #pragma unroll
            for (int rr = 0; rr < GR; ++rr) acc[rr] += sA[rr][kk] * bv;
        }
        __syncthreads();
    }
    float bv = bias[c];
    #pragma unroll
    for (int rr = 0; rr < GR; ++rr) {
        float v = acc[rr] + bv;
        if (relu) v = fmaxf(v, 0.f);
        C[(size_t)(r0 + rr) * ldc + c] = v;
    }
}

// ---------------------------------------------------------------------------
// Scan with resident weights. One WG (512 thr) per batch.
//   M = u0@wr0^T + u1@wr1^T  where u{0,1} = sum_j beta{0,1}_j * H_j  (V-cache
//   eliminated by linearity). Wbig: cols 0-511 in registers (1 col/thread),
//   cols 512-895 in LDS, cols 896-1151 streamed from L2. Wpair in registers
//   (t<384, 2 threads/col). H history bf16-packed in global (written here).
// ---------------------------------------------------------------------------
__global__ __launch_bounds__(512, 2) void scan_kernel(
    const float* __restrict__ xin,  float* __restrict__ hout,
    const float* __restrict__ PRE,  const float* __restrict__ adj,
    const float* __restrict__ smask,
    const uint32_t* __restrict__ W2,    // [96][1152]
    const uint32_t* __restrict__ Wp32,  // [192][192]
    const float* __restrict__ gbx,      // [384]
    const float* __restrict__ gatw,     // [384] = wq | wk
    uint32_t* __restrict__ Hbf,         // [B][256][96] packed bf16 pairs
    float* __restrict__ As)
{
    const int b = blockIdx.x;
    const int t = threadIdx.x;
    const int lane = t & 63, wave = t >> 6;

    __shared__ uint32_t Wlds[96][384];          // 147,456 B
    __shared__ float sG[G6];                    // 4,608 B (matvec out / u-partials)
    __shared__ float sA0[N_], sA1[N_];          // 2,048 B
    __shared__ float sKsc[N_];                  // 1,024 B
    __shared__ float sX[DH_], sM[DH_], sH[DH_], su0[DH_], su1[DH_];  // 3,840 B
    __shared__ float sRedS[4], sRedX[3], sRedK[3];

    const float* adjB = adj   + (size_t)b * N_ * N_;
    const float* smB  = smask + (size_t)b * N_ * N_;
    float* AsB        = As    + (size_t)b * (L_ * N_ * N_);
    uint32_t* Hb      = Hbf   + (size_t)b * N_ * 96;

    // persistent scalars
    float wqv = 0.f, wkv = 0.f, g2 = 0.f, g5 = 0.f;
    if (t < DH_) { wqv = gatw[t]; wkv = gatw[DH_ + t]; g2 = gbx[t]; g5 = gbx[DH_ + t]; }

    // register-resident weights
    uint32_t wreg[96];                          // Wbig col t (t<512)
    #pragma unroll
    for (int p = 0; p < 96; ++p) wreg[p] = W2[(size_t)p * G6 + t];
    uint32_t wpair[96];                         // Wpair col t>>1, k-half t&1
    {
        const uint32_t* wp = Wp32 + (size_t)((t & 1) * 96) * DH_ + (t >> 1);
        if (t < 384) {
            #pragma unroll
            for (int p = 0; p < 96; ++p) wpair[p] = wp[(size_t)p * DH_];
        }
    }
    // LDS-resident Wbig cols 512..895
    for (int q = t; q < 96 * 384; q += 512) {
        int p = q / 384, c = q - p * 384;
        Wlds[p][c] = W2[(size_t)p * G6 + 512 + c];
    }
    if (t < N_) sKsc[t] = 0.f;
    if (t < DH_) {
        float xv = xin[(size_t)(b * N_) * G3 + t];
        sX[t] = xv;
        float px = xv * wqv;
        #pragma unroll
        for (int o = 32; o; o >>= 1) px += __shfl_xor(px, o);
        if (lane == 0) sRedX[wave] = px;
    }
    __syncthreads();
    float xq = sRedX[0] + sRedX[1] + sRedX[2];

    // ---- step 0 (M = 0) ----------------------------------------------------
    if (t < N_) AsB[t] = 0.f;
    if (t < DH_) {
        const float* pre = PRE + (size_t)(b * N_) * G6;
        float p0 = pre[t], p1 = pre[DH_ + t], p2 = pre[384 + t];
        float p3 = pre[G3 + t], p4 = pre[768 + t], p5 = pre[960 + t];
        float r1 = sigm(p0), z1 = sigm(p1), n1 = tanhf_(p2 + r1 * g2);
        float Cv = (1.f - z1) * n1;
        float r2 = sigm(p3), z2 = sigm(p4), n2 = tanhf_(g5 + r2 * p5);
        float Pv = (1.f - z2) * n2 + z2 * sX[t];
        float Hn = Cv + Pv;
        sH[t] = Hn;
        hout[(size_t)(b * N_) * G3 + t] = Hn;
    }
    __syncthreads();
    if (t < 96) Hb[t] = f2bf(sH[2 * t]) | (f2bf(sH[2 * t + 1]) << 16);
    if (t < DH_) {
        float kp2 = sH[t] * wkv;
        #pragma unroll
        for (int o = 32; o; o >>= 1) kp2 += __shfl_xor(kp2, o);
        if (lane == 0) sRedK[wave] = kp2;
        float xv = xin[(size_t)(b * N_ + 1) * G3 + t];
        sX[t] = xv;
        float px = xv * wqv;
        #pragma unroll
        for (int o = 32; o; o >>= 1) px += __shfl_xor(px, o);
        if (lane == 0) sRedX[wave] = px;
    }
    __syncthreads();
    xq = sRedX[0] + sRedX[1] + sRedX[2];
    float kslast = sRedK[0] + sRedK[1] + sRedK[2];

    // ---- main loop ---------------------------------------------------------
    for (int i = 1; i < N_; ++i) {
        const int row = b * N_ + i;
        // A: attention scores (no max-pass; scores bounded)
        float e = 0.f, smv = 0.f;
        if (t < N_) {
            float av = adjB[(size_t)i * N_ + t];
            smv = smB[(size_t)i * N_ + t];
            float ks = sKsc[t];
            if (t == i - 1) { ks = kslast; sKsc[t] = kslast; }
            if (t < i && av > 0.5f) e = __expf(xq + ks);
        }
        {
            float ps = e;
            #pragma unroll
            for (int o = 32; o; o >>= 1) ps += __shfl_xor(ps, o);
            if (t < N_ && lane == 0) sRedS[wave] = ps;
        }
        __syncthreads();                                         // B1
        if (t < N_) {
            float ssum = sRedS[0] + sRedS[1] + sRedS[2] + sRedS[3];
            float a = e / ssum;
            AsB[(size_t)i * N_ + t] = a;
            float b0 = a * smv;
            sA0[t] = b0; sA1[t] = a - b0;
        }
        __syncthreads();                                         // B2
        // C: u-partials (t<288: k-pair kq, 3-way j-split jp)
        if (t < 288) {
            int kq = t % 96, jp = t / 96;
            float ua = 0.f, ub = 0.f, uc = 0.f, ud = 0.f;
            const uint32_t* hp = Hb + kq;
            int j = jp;
            while (j + 21 < i) {
                uint32_t hv[8];
                #pragma unroll
                for (int s = 0; s < 8; ++s) hv[s] = hp[(size_t)(j + 3 * s) * 96];
                #pragma unroll
                for (int s = 0; s < 8; ++s) {
                    float b0 = sA0[j + 3 * s], b1 = sA1[j + 3 * s];
                    float lo = bflo(hv[s]), hi = bfhi(hv[s]);
                    ua = fmaf(b0, lo, ua); ub = fmaf(b0, hi, ub);
                    uc = fmaf(b1, lo, uc); ud = fmaf(b1, hi, ud);
                }
                j += 24;
            }
            for (; j < i; j += 3) {
                uint32_t hv = hp[(size_t)j * 96];
                float b0 = sA0[j], b1 = sA1[j];
                ua = fmaf(b0, bflo(hv), ua); ub = fmaf(b0, bfhi(hv), ub);
                uc = fmaf(b1, bflo(hv), uc); ud = fmaf(b1, bfhi(hv), ud);
            }
            float* up = sG + jp * 384 + 4 * kq;
            up[0] = ua; up[1] = ub; up[2] = uc; up[3] = ud;
        }
        __syncthreads();                                         // B3
        // D: combine u partials
        if (t < 384) {
            float v = sG[t] + sG[384 + t] + sG[768 + t];
            int kq = t >> 2, q = t & 3;
            if (q < 2) su0[2 * kq + q] = v; else su1[2 * kq + q - 2] = v;
        }
        __syncthreads();                                         // B4
        // E: M = u0@wr0^T + u1@wr1^T  (register Wpair)
        if (t < 384) {
            const float* u0p = su0 + (t & 1) * 96;
            const float* u1p = su1 + (t & 1) * 96;
            float m = 0.f;
            #pragma unroll
            for (int p = 0; p < 96; ++p) {
                uint32_t w = wpair[p];
                m = fmaf(u0p[p], bflo(w), m);
                m = fmaf(u1p[p], bfhi(w), m);
            }
            m += __shfl_xor(m, 1);
            if ((t & 1) == 0) sM[t >> 1] = m;
        }
        __syncthreads();                                         // B5
        // F: g = M @ Wbig  (reg cols + LDS cols + streamed cols)
        {
            const int kp = t & 1, cs = 896 + (t >> 1);
            const uint32_t* wsp = W2 + (size_t)(48 * kp) * G6 + cs;
            float g = 0.f, s = 0.f;
            #pragma unroll
            for (int bb = 0; bb < 6; ++bb) {
                uint32_t wv[8];
                #pragma unroll
                for (int e8 = 0; e8 < 8; ++e8) wv[e8] = wsp[(size_t)(bb * 8 + e8) * G6];
                #pragma unroll
                for (int q = 0; q < 16; ++q) {
                    int p = bb * 16 + q;
                    uint32_t w = wreg[p];
                    g = fmaf(sM[2 * p], bflo(w), g);
                    g = fmaf(sM[2 * p + 1], bfhi(w), g);
                }
                #pragma unroll
                for (int e8 = 0; e8 < 8; ++e8) {
                    int p = 48 * kp + bb * 8 + e8;
                    uint32_t w = wv[e8];
                    s = fmaf(sM[2 * p], bflo(w), s);
                    s = fmaf(sM[2 * p + 1], bfhi(w), s);
                }
            }
            sG[t] = g;
            s += __shfl_xor(s, 1);
            if (kp == 0) sG[cs] = s;
            if (t < 384) {
                float gl = 0.f;
                #pragma unroll
                for (int p = 0; p < 96; ++p) {
                    uint32_t w = Wlds[p][t];
                    gl = fmaf(sM[2 * p], bflo(w), gl);
                    gl = fmaf(sM[2 * p + 1], bfhi(w), gl);
                }
                sG[512 + t] = gl;
            }
        }
        __syncthreads();                                         // B6
        // G: GRU gates, Hnew = C + P
        if (t < DH_) {
            const float* pre = PRE + (size_t)row * G6;
            float p0 = pre[t], p1 = pre[DH_ + t], p2 = pre[384 + t];
            float p3 = pre[G3 + t], p4 = pre[768 + t], p5 = pre[960 + t];
            float Mv = sM[t], xvv = sX[t];
            float r1 = sigm(p0 + sG[t]);
            float z1 = sigm(p1 + sG[DH_ + t]);
            float n1 = tanhf_(p2 + r1 * (sG[384 + t] + g2));
            float Cv = (1.f - z1) * n1 + z1 * Mv;
            float r2 = sigm(sG[G3 + t] + p3);
            float z2 = sigm(sG[768 + t] + p4);
            float n2 = tanhf_(sG[960 + t] + g5 + r2 * p5);
            float Pv = (1.f - z2) * n2 + z2 * xvv;
            float Hn = Cv + Pv;
            sH[t] = Hn;
            hout[(size_t)row * G3 + t] = Hn;
        }
        __syncthreads();                                         // B7
        // H: tail — H history, Ksc_i partials, next x / xq partials
        if (t < 96) Hb[(size_t)i * 96 + t] = f2bf(sH[2 * t]) | (f2bf(sH[2 * t + 1]) << 16);
        if (t < DH_) {
            float kp2 = sH[t] * wkv;
            #pragma unroll
            for (int o = 32; o; o >>= 1) kp2 += __shfl_xor(kp2, o);
            if (lane == 0) sRedK[wave] = kp2;
            int inx = (i < N_ - 1) ? i + 1 : N_ - 1;
            float xv = xin[(size_t)(b * N_ + inx) * G3 + t];
            sX[t] = xv;
            float px = xv * wqv;
            #pragma unroll
            for (int o = 32; o; o >>= 1) px += __shfl_xor(px, o);
            if (lane == 0) sRedX[wave] = px;
        }
        __syncthreads();                                         // B8
        xq = sRedX[0] + sRedX[1] + sRedX[2];
        kslast = sRedK[0] + sRedK[1] + sRedK[2];
    }
}

// ---------------------------------------------------------------------------
extern "C" void kernel_launch(void* const* d_in, const int* in_sizes, int n_in,
                              void* d_out, int out_size, void* d_ws, size_t ws_size,
                              hipStream_t stream)
{
    const float* features = (const float*)d_in[0];
    const float* adj      = (const float*)d_in[1];
    const float* smask    = (const float*)d_in[2];
    const float* fc1_w = (const float*)d_in[5];
    const float* fc1_b = (const float*)d_in[6];
    const float* gat_w = (const float*)d_in[7];
    const float* wr0   = (const float*)d_in[9];
    const float* wr1   = (const float*)d_in[10];
    const float* c_wih = (const float*)d_in[11];
    const float* c_whh = (const float*)d_in[12];
    const float* c_bih = (const float*)d_in[13];
    const float* c_bhh = (const float*)d_in[14];
    const float* p_wih = (const float*)d_in[15];
    const float* p_whh = (const float*)d_in[16];
    const float* p_bih = (const float*)d_in[17];
    const float* p_bhh = (const float*)d_in[18];
    const float* mw0 = (const float*)d_in[19];
    const float* mb0 = (const float*)d_in[20];
    const float* mw1 = (const float*)d_in[21];
    const float* mb1 = (const float*)d_in[22];
    const float* mw2 = (const float*)d_in[23];
    const float* mb2 = (const float*)d_in[24];
    float* out = (float*)d_out;

    char* wsb = (char*)d_ws;
    size_t off = 0;
    auto carve = [&](size_t bytes) -> char* {
        char* p = wsb + off;
        off = (off + bytes + 255) & ~(size_t)255;
        return p;
    };
    float* Hcat     = (float*)carve(2048ull * 576 * 4);
    float* PRE      = (float*)carve(2048ull * 1152 * 4);
    float* WpreT    = (float*)carve(2ull * 192 * 1152 * 4);
    uint32_t* W2    = (uint32_t*)carve(2ull * 96 * 1152 * 4);
    uint32_t* Wp32  = (uint32_t*)carve(2ull * 192 * 192 * 4);
    float* biasPre  = (float*)carve(2ull * 1152 * 4);
    float* gbx      = (float*)carve(2ull * 384 * 4);
    uint32_t* Hbf   = (uint32_t*)carve(8ull * 256 * 96 * 4);
    float* h1 = PRE;
    float* h2 = PRE + 2048 * 192;

    prepack_kernel<<<dim3((192 * 1152 + 255) / 256), 256, 0, stream>>>(
        wr0, wr1, c_wih, c_whh, c_bih, c_bhh, p_wih, p_whh, p_bih, p_bhh,
        WpreT, W2, Wp32, biasPre, gbx);

    gemm_kernel<<<dim3(256, 1), 192, 0, stream>>>(features, 768, fc1_w, fc1_b,
                                                  Hcat, 576, 768, 192, 1);
    for (int l = 0; l < 2; ++l) {
        gemm_kernel<<<dim3(256, 6), 192, 0, stream>>>(Hcat + l * 192, 576,
            WpreT + (size_t)l * 192 * 1152, biasPre + l * 1152, PRE, 1152, 192, 1152, 0);
        scan_kernel<<<dim3(8), 512, 0, stream>>>(Hcat + l * 192, Hcat + (l + 1) * 192,
            PRE, adj, smask,
            W2 + (size_t)l * 96 * 1152,
            Wp32 + (size_t)l * 192 * 192,
            gbx + l * 384, gat_w + l * 384, Hbf,
            out + 393216 + l * 65536);
    }
    gemm_kernel<<<dim3(256, 1), 192, 0, stream>>>(Hcat, 576, mw0, mb0, h1, 192, 576, 192, 1);
    gemm_kernel<<<dim3(256, 1), 192, 0, stream>>>(h1, 192, mw1, mb1, h2, 192, 192, 192, 1);
    gemm_kernel<<<dim3(256, 1), 192, 0, stream>>>(h2, 192, mw2, mb2, out, 192, 192, 192, 0);
}

// Round 5
// 4752.210 us; speedup vs baseline: 4.6099x; 4.1620x over previous
//
#include <hip/hip_runtime.h>
#include <stdint.h>

#define B_  8
#define N_  256
#define DH_ 192
#define L_  2
#define G3  576
#define G6  1152
#define NW  4      // WGs per batch
#define DS  48     // d-slice per WG
#define KD  24     // Hb dwords per WG (48 bf16)
#define GC  288    // g-cols per WG (6 gates x 48)

__device__ __forceinline__ float bflo(uint32_t u) { return __uint_as_float(u << 16); }
__device__ __forceinline__ float bfhi(uint32_t u) { return __uint_as_float(u & 0xffff0000u); }
__device__ __forceinline__ uint32_t f2bf(float f) {
    uint32_t x = __float_as_uint(f);
    x += 0x7fffu + ((x >> 16) & 1u);          // RNE
    return x >> 16;
}
__device__ __forceinline__ float sigm(float x)  { return 1.f / (1.f + __expf(-x)); }
__device__ __forceinline__ float tanhf_(float x){ return 1.f - 2.f / (1.f + __expf(2.f * x)); }

// ---------------------------------------------------------------------------
// Prepack per layer:
//   WpreT fp32 [192][1152] : rows [cwih | pwhh]   (PRE GEMM B-matrix)
//   W4    u32  [4 w][96 p][288 c'] : c' = 48*j + dd -> Wbig col 192*j+48*w+dd,
//         pack(bf(Wbig[2p][c]), bf(Wbig[2p+1][c])),
//         Wbig[k][c] = (c<576)? cwhh[c][k] : pwih[c-576][k]
//   Wp32  u32  [192 k][192 d] : pack(bf(wr0[d][k]), bf(wr1[d][k]))
//   biasPre fp32 [1152] : [cbih|pbhh] + gate bias folds (r,z gates)
//   gbx   fp32 [384] : [cbhh_n | pbih_n]  (n-gate biases, applied in scan)
// ---------------------------------------------------------------------------
__global__ void prepack_kernel(
    const float* __restrict__ wr0, const float* __restrict__ wr1,
    const float* __restrict__ c_wih, const float* __restrict__ c_whh,
    const float* __restrict__ c_bih, const float* __restrict__ c_bhh,
    const float* __restrict__ p_wih, const float* __restrict__ p_whh,
    const float* __restrict__ p_bih, const float* __restrict__ p_bhh,
    float* __restrict__ WpreT, uint32_t* __restrict__ W4,
    uint32_t* __restrict__ Wp32, float* __restrict__ biasPre, float* __restrict__ gbx)
{
    int idx = blockIdx.x * blockDim.x + threadIdx.x;
    if (idx >= DH_ * G6) return;
    for (int l = 0; l < L_; ++l) {
        const float* cwih = c_wih + l * G3 * DH_;
        const float* cwhh = c_whh + l * G3 * DH_;
        const float* pwih = p_wih + l * G3 * DH_;
        const float* pwhh = p_whh + l * G3 * DH_;
        {   // WpreT
            int k = idx / G6, r = idx - k * G6;
            float w = (r < G3) ? cwih[r * DH_ + k] : pwhh[(r - G3) * DH_ + k];
            WpreT[l * DH_ * G6 + k * G6 + r] = w;
        }
        if (idx < NW * 96 * GC) {   // W4
            int w = idx / (96 * GC), rem = idx % (96 * GC);
            int p = rem / GC, c2 = rem % GC;
            int j = c2 / DS, dd = c2 % DS;
            int c = 192 * j + DS * w + dd;
            float w0 = (c < G3) ? cwhh[c * DH_ + 2 * p]     : pwih[(c - G3) * DH_ + 2 * p];
            float w1 = (c < G3) ? cwhh[c * DH_ + 2 * p + 1] : pwih[(c - G3) * DH_ + 2 * p + 1];
            W4[l * NW * 96 * GC + idx] = f2bf(w0) | (f2bf(w1) << 16);
        }
        if (idx < DH_ * DH_) {  // Wp32
            int k = idx / DH_, d = idx - k * DH_;
            Wp32[l * DH_ * DH_ + k * DH_ + d] =
                f2bf(wr0[l * DH_ * DH_ + d * DH_ + k]) |
                (f2bf(wr1[l * DH_ * DH_ + d * DH_ + k]) << 16);
        }
        if (idx < G6) {  // biasPre with r,z folds
            float base = (idx < G3) ? c_bih[l * G3 + idx] : p_bhh[l * G3 + idx - G3];
            float fold = 0.f;
            if (idx < 384)                    fold = c_bhh[l * G3 + idx];
            else if (idx >= G3 && idx < 960)  fold = p_bih[l * G3 + idx - G3];
            biasPre[l * G6 + idx] = base + fold;
        }
        if (idx < 384) {
            gbx[l * 384 + idx] = (idx < DH_) ? c_bhh[l * G3 + 384 + idx]
                                             : p_bih[l * G3 + 384 + (idx - DH_)];
        }
    }
}

// ---------------------------------------------------------------------------
// Generic small GEMM (parallel phases): C = relu?(A @ B + bias)
// ---------------------------------------------------------------------------
#define GR 8
__global__ __launch_bounds__(192) void gemm_kernel(
    const float* __restrict__ A, int lda, const float* __restrict__ Bm,
    const float* __restrict__ bias, float* __restrict__ C, int ldc,
    int K, int cols, int relu)
{
    __shared__ float sA[GR][64];
    const int c  = blockIdx.y * 192 + threadIdx.x;
    const int r0 = blockIdx.x * GR;
    float acc[GR] = {0.f, 0.f, 0.f, 0.f, 0.f, 0.f, 0.f, 0.f};
    for (int k0 = 0; k0 < K; k0 += 64) {
        for (int idx = threadIdx.x; idx < GR * 64; idx += 192) {
            int rr = idx >> 6, kk = idx & 63;
            sA[rr][kk] = A[(size_t)(r0 + rr) * lda + k0 + kk];
        }
        __syncthreads();
        #pragma unroll 8
        for (int kk = 0; kk < 64; ++kk) {
            float bv = Bm[(size_t)(k0 + kk) * cols + c];
            #pragma unroll
            for (int rr = 0; rr < GR; ++rr) acc[rr] += sA[rr][kk] * bv;
        }
        __syncthreads();
    }
    float bv = bias[c];
    #pragma unroll
    for (int rr = 0; rr < GR; ++rr) {
        float v = acc[rr] + bv;
        if (relu) v = fmaxf(v, 0.f);
        C[(size_t)(r0 + rr) * ldc + c] = v;
    }
}

// ---------------------------------------------------------------------------
// Multi-CU scan: 4 WGs per batch (32 blocks), all weights LDS-resident.
// Cross-WG per step: M-partials (192 f) and kdot scalar, exchanged via
// agent-scope atomics + monotonic stamp flags. H-history slice is WG-local.
// ---------------------------------------------------------------------------
__global__ __launch_bounds__(576, 1) void scan_kernel(
    const float* __restrict__ xin,  float* __restrict__ hout,   // row stride 576
    const float* __restrict__ PRE,  const float* __restrict__ adj,
    const float* __restrict__ smask,
    const uint32_t* __restrict__ W4,    // this layer: [4][96][288]
    const uint32_t* __restrict__ Wp32,  // this layer: [192][192]
    const float* __restrict__ gbx,      // this layer: [384]
    const float* __restrict__ gatw,     // this layer: [384] = wq | wk
    uint32_t* __restrict__ Hb,          // [8 b][4 w][24 kd][256 j]
    float* __restrict__ MP,             // [8][4][192]
    float* __restrict__ Kb,             // [8][4]
    int* __restrict__ flagM, int* __restrict__ flagH,  // [32] each
    float* __restrict__ As, int sbase)
{
    const int blk = blockIdx.x;
    const int b = blk & 7, w = blk >> 3;       // batch's 4 WGs share an XCD (heuristic)
    const int t = threadIdx.x;
    const int lane = t & 63, wave = t >> 6;
    const int dg0 = w * DS;

    __shared__ uint32_t Wlds[96 * GC];         // 110,592 B
    __shared__ uint32_t wrlds[DS * DH_];       //  36,864 B
    __shared__ float sA0[N_], sA1[N_], sKsc[N_];
    __shared__ float su0[DS], su1[DS], sM[DH_], sGc[GC], sHn[DS], sKp[DS];
    __shared__ float sRedS[4], sRedX[3], sKred[4];

    const float* adjB = adj   + (size_t)b * N_ * N_;
    const float* smB  = smask + (size_t)b * N_ * N_;
    float* AsB        = As    + (size_t)b * (L_ * N_ * N_);
    uint32_t* Hw      = Hb    + (size_t)(b * NW + w) * KD * N_;
    const int fi = b * NW;

    // ---- load LDS-resident weights -----------------------------------------
    const uint32_t* W4w = W4 + (size_t)w * 96 * GC;
    for (int q = t; q < 96 * GC; q += 576) Wlds[q] = W4w[q];
    const uint32_t* wps = Wp32 + (size_t)dg0 * DH_;
    for (int q = t; q < DS * DH_; q += 576) wrlds[q] = wps[q];

    float wqv = (t < DH_) ? gatw[t] : 0.f;
    float wkv = 0.f, g2b = 0.f, g5b = 0.f;
    if (t < DS) { wkv = gatw[DH_ + dg0 + t]; g2b = gbx[dg0 + t]; g5b = gbx[DH_ + dg0 + t]; }
    if (t < N_) sKsc[t] = 0.f;
    if (w == 0 && t < N_) AsB[t] = 0.f;

    // ---- step 0 (M = 0) ----------------------------------------------------
    float aAdj = 0.f, aSm = 0.f;
    if (t < N_) { aAdj = adjB[N_ + t]; aSm = smB[N_ + t]; }     // prefetch row 1
    if (t < DS) {
        const float* pre = PRE + (size_t)(b * N_) * G6 + dg0 + t;
        float xv = xin[(size_t)(b * N_) * G3 + dg0 + t];
        float r1 = sigm(pre[0]),   z1 = sigm(pre[192]), n1 = tanhf_(pre[384] + r1 * g2b);
        float Cv = (1.f - z1) * n1;
        float r2 = sigm(pre[576]), z2 = sigm(pre[768]), n2 = tanhf_(g5b + r2 * pre[960]);
        float Pv = (1.f - z2) * n2 + z2 * xv;
        float Hn = Cv + Pv;
        sHn[t] = Hn; sKp[t] = Hn * wkv;
        hout[(size_t)(b * N_) * G3 + dg0 + t] = Hn;
    }
    if (t < DH_) {      // xq for row 1
        float px = xin[(size_t)(b * N_ + 1) * G3 + t] * wqv;
        #pragma unroll
        for (int o = 32; o; o >>= 1) px += __shfl_xor(px, o);
        if (lane == 0) sRedX[wave] = px;
    }
    __syncthreads();
    if (t < KD) Hw[t * N_] = f2bf(sHn[2 * t]) | (f2bf(sHn[2 * t + 1]) << 16);
    if (t < 64) {
        float v = (t < DS) ? sKp[t] : 0.f;
        #pragma unroll
        for (int o = 32; o; o >>= 1) v += __shfl_xor(v, o);
        if (t == 0) {
            __hip_atomic_store(&Kb[fi + w], v, __ATOMIC_RELAXED, __HIP_MEMORY_SCOPE_AGENT);
            __hip_atomic_store(&flagH[fi + w], sbase + 1, __ATOMIC_RELEASE, __HIP_MEMORY_SCOPE_AGENT);
        }
    }
    if (t < NW) {
        while (__hip_atomic_load(&flagH[fi + t], __ATOMIC_ACQUIRE, __HIP_MEMORY_SCOPE_AGENT) < sbase + 1) {}
        sKred[t] = __hip_atomic_load(&Kb[fi + t], __ATOMIC_RELAXED, __HIP_MEMORY_SCOPE_AGENT);
    }
    __syncthreads();
    float xq = sRedX[0] + sRedX[1] + sRedX[2];

    // ---- main loop ---------------------------------------------------------
    for (int i = 1; i < N_; ++i) {
        const int row = b * N_ + i;
        const int stamp = sbase + 2 * i;
        // A: attention (no max-pass; scores bounded)
        float e = 0.f;
        if (t < N_) {
            float ks = sKsc[t];
            if (t == i - 1) { ks = sKred[0] + sKred[1] + sKred[2] + sKred[3]; sKsc[t] = ks; }
            if (t < i && aAdj > 0.5f) e = __expf(xq + ks);
        }
        {
            float ps = e;
            #pragma unroll
            for (int o = 32; o; o >>= 1) ps += __shfl_xor(ps, o);
            if (t < N_ && lane == 0) sRedS[wave] = ps;
        }
        __syncthreads();                                        // B1
        if (t < N_) {
            float ssum = sRedS[0] + sRedS[1] + sRedS[2] + sRedS[3];
            float a = e / ssum;
            if (w == 0) AsB[(size_t)i * N_ + t] = a;
            float b0 = a * aSm;
            sA0[t] = b0; sA1[t] = a - b0;
        }
        __syncthreads();                                        // B2
        // U: u-slice accumulation over WG-local H history (L1-hot)
        if (t < 384) {
            const int kd = t >> 4, jp = t & 15;
            const uint32_t* hp = Hw + kd * N_;
            float u0l = 0.f, u0h = 0.f, u1l = 0.f, u1h = 0.f;
            int j = jp;
            while (j + 48 < i) {
                uint32_t h0 = hp[j], h1 = hp[j + 16], h2 = hp[j + 32], h3 = hp[j + 48];
                float b0, b1;
                b0 = sA0[j];      b1 = sA1[j];
                u0l = fmaf(b0, bflo(h0), u0l); u0h = fmaf(b0, bfhi(h0), u0h);
                u1l = fmaf(b1, bflo(h0), u1l); u1h = fmaf(b1, bfhi(h0), u1h);
                b0 = sA0[j + 16]; b1 = sA1[j + 16];
                u0l = fmaf(b0, bflo(h1), u0l); u0h = fmaf(b0, bfhi(h1), u0h);
                u1l = fmaf(b1, bflo(h1), u1l); u1h = fmaf(b1, bfhi(h1), u1h);
                b0 = sA0[j + 32]; b1 = sA1[j + 32];
                u0l = fmaf(b0, bflo(h2), u0l); u0h = fmaf(b0, bfhi(h2), u0h);
                u1l = fmaf(b1, bflo(h2), u1l); u1h = fmaf(b1, bfhi(h2), u1h);
                b0 = sA0[j + 48]; b1 = sA1[j + 48];
                u0l = fmaf(b0, bflo(h3), u0l); u0h = fmaf(b0, bfhi(h3), u0h);
                u1l = fmaf(b1, bflo(h3), u1l); u1h = fmaf(b1, bfhi(h3), u1h);
                j += 64;
            }
            for (; j < i; j += 16) {
                uint32_t hv = hp[j];
                float b0 = sA0[j], b1 = sA1[j];
                u0l = fmaf(b0, bflo(hv), u0l); u0h = fmaf(b0, bfhi(hv), u0h);
                u1l = fmaf(b1, bflo(hv), u1l); u1h = fmaf(b1, bfhi(hv), u1h);
            }
            #pragma unroll
            for (int o = 1; o <= 8; o <<= 1) {
                u0l += __shfl_xor(u0l, o); u0h += __shfl_xor(u0h, o);
                u1l += __shfl_xor(u1l, o); u1h += __shfl_xor(u1h, o);
            }
            if (jp == 0) {
                su0[2 * kd] = u0l; su0[2 * kd + 1] = u0h;
                su1[2 * kd] = u1l; su1[2 * kd + 1] = u1h;
            }
        }
        __syncthreads();                                        // B3
        // Mp: M-partial over own k-slice (LDS wr), publish
        if (t < DH_) {
            float mp = 0.f;
            const uint32_t* wr = wrlds + t;
            #pragma unroll 8
            for (int k = 0; k < DS; ++k) {
                uint32_t ww = wr[k * DH_];
                mp = fmaf(su0[k], bflo(ww), mp);
                mp = fmaf(su1[k], bfhi(ww), mp);
            }
            __hip_atomic_store(&MP[(fi + w) * DH_ + t], mp, __ATOMIC_RELAXED, __HIP_MEMORY_SCOPE_AGENT);
        }
        __syncthreads();                                        // B4
        if (t == 0)
            __hip_atomic_store(&flagM[fi + w], stamp, __ATOMIC_RELEASE, __HIP_MEMORY_SCOPE_AGENT);
        {   // prefetch next adj/smask rows while spinning
            int inx = (i + 1 < N_) ? i + 1 : N_ - 1;
            if (t < N_) { aAdj = adjB[(size_t)inx * N_ + t]; aSm = smB[(size_t)inx * N_ + t]; }
        }
        if (t < NW)
            while (__hip_atomic_load(&flagM[fi + t], __ATOMIC_ACQUIRE, __HIP_MEMORY_SCOPE_AGENT) < stamp) {}
        __syncthreads();                                        // B5
        if (t < DH_) {
            float m = 0.f;
            #pragma unroll
            for (int w2 = 0; w2 < NW; ++w2)
                m += __hip_atomic_load(&MP[(fi + w2) * DH_ + t], __ATOMIC_RELAXED, __HIP_MEMORY_SCOPE_AGENT);
            sM[t] = m;
        }
        __syncthreads();                                        // B6
        // G: g-slice from LDS-resident Wbig cols  (+ PRE/x prefetch for gates)
        float pr0 = 0.f, pr1 = 0.f, pr2 = 0.f, pr3 = 0.f, pr4 = 0.f, pr5 = 0.f, xvv = 0.f;
        if (t < DS) {
            const float* pre = PRE + (size_t)row * G6 + dg0 + t;
            pr0 = pre[0];   pr1 = pre[192]; pr2 = pre[384];
            pr3 = pre[576]; pr4 = pre[768]; pr5 = pre[960];
            xvv = xin[(size_t)row * G3 + dg0 + t];
        }
        {
            const int c = t >> 1, kh = t & 1;
            const uint32_t* wl = Wlds + (48 * kh) * GC + c;
            float g = 0.f;
            #pragma unroll 8
            for (int p = 0; p < 48; ++p) {
                uint32_t ww = wl[p * GC];
                int pg = 48 * kh + p;
                g = fmaf(sM[2 * pg], bflo(ww), g);
                g = fmaf(sM[2 * pg + 1], bfhi(ww), g);
            }
            g += __shfl_xor(g, 1);
            if (kh == 0) sGc[c] = g;
        }
        __syncthreads();                                        // B7
        // gates (own d-slice) + next-step xq partials
        if (t < DS) {
            float Mv = sM[dg0 + t];
            float r1 = sigm(pr0 + sGc[t]);
            float z1 = sigm(pr1 + sGc[DS + t]);
            float n1 = tanhf_(pr2 + r1 * (sGc[2 * DS + t] + g2b));
            float Cv = (1.f - z1) * n1 + z1 * Mv;
            float r2 = sigm(sGc[3 * DS + t] + pr3);
            float z2 = sigm(sGc[4 * DS + t] + pr4);
            float n2 = tanhf_(sGc[5 * DS + t] + g5b + r2 * pr5);
            float Pv = (1.f - z2) * n2 + z2 * xvv;
            float Hn = Cv + Pv;
            sHn[t] = Hn; sKp[t] = Hn * wkv;
            hout[(size_t)row * G3 + dg0 + t] = Hn;
        }
        if (t < DH_) {
            int inx = (i + 1 < N_) ? i + 1 : N_ - 1;
            float px = xin[(size_t)(b * N_ + inx) * G3 + t] * wqv;
            #pragma unroll
            for (int o = 32; o; o >>= 1) px += __shfl_xor(px, o);
            if (lane == 0) sRedX[wave] = px;
        }
        __syncthreads();                                        // B8
        // tail: H history column, kdot exchange
        if (t < KD) Hw[t * N_ + i] = f2bf(sHn[2 * t]) | (f2bf(sHn[2 * t + 1]) << 16);
        if (t < 64) {
            float v = (t < DS) ? sKp[t] : 0.f;
            #pragma unroll
            for (int o = 32; o; o >>= 1) v += __shfl_xor(v, o);
            if (t == 0) {
                __hip_atomic_store(&Kb[fi + w], v, __ATOMIC_RELAXED, __HIP_MEMORY_SCOPE_AGENT);
                __hip_atomic_store(&flagH[fi + w], stamp + 1, __ATOMIC_RELEASE, __HIP_MEMORY_SCOPE_AGENT);
            }
        }
        if (t < NW) {
            while (__hip_atomic_load(&flagH[fi + t], __ATOMIC_ACQUIRE, __HIP_MEMORY_SCOPE_AGENT) < stamp + 1) {}
            sKred[t] = __hip_atomic_load(&Kb[fi + t], __ATOMIC_RELAXED, __HIP_MEMORY_SCOPE_AGENT);
        }
        __syncthreads();                                        // B9
        xq = sRedX[0] + sRedX[1] + sRedX[2];
    }
}

// ---------------------------------------------------------------------------
extern "C" void kernel_launch(void* const* d_in, const int* in_sizes, int n_in,
                              void* d_out, int out_size, void* d_ws, size_t ws_size,
                              hipStream_t stream)
{
    const float* features = (const float*)d_in[0];
    const float* adj      = (const float*)d_in[1];
    const float* smask    = (const float*)d_in[2];
    const float* fc1_w = (const float*)d_in[5];
    const float* fc1_b = (const float*)d_in[6];
    const float* gat_w = (const float*)d_in[7];
    const float* wr0   = (const float*)d_in[9];
    const float* wr1   = (const float*)d_in[10];
    const float* c_wih = (const float*)d_in[11];
    const float* c_whh = (const float*)d_in[12];
    const float* c_bih = (const float*)d_in[13];
    const float* c_bhh = (const float*)d_in[14];
    const float* p_wih = (const float*)d_in[15];
    const float* p_whh = (const float*)d_in[16];
    const float* p_bih = (const float*)d_in[17];
    const float* p_bhh = (const float*)d_in[18];
    const float* mw0 = (const float*)d_in[19];
    const float* mb0 = (const float*)d_in[20];
    const float* mw1 = (const float*)d_in[21];
    const float* mb1 = (const float*)d_in[22];
    const float* mw2 = (const float*)d_in[23];
    const float* mb2 = (const float*)d_in[24];
    float* out = (float*)d_out;

    char* wsb = (char*)d_ws;
    size_t off = 0;
    auto carve = [&](size_t bytes) -> char* {
        char* p = wsb + off;
        off = (off + bytes + 255) & ~(size_t)255;
        return p;
    };
    float* Hcat     = (float*)carve(2048ull * 576 * 4);
    float* PRE      = (float*)carve(2048ull * 1152 * 4);
    float* WpreT    = (float*)carve(2ull * 192 * 1152 * 4);
    uint32_t* W4    = (uint32_t*)carve(2ull * NW * 96 * GC * 4);
    uint32_t* Wp32  = (uint32_t*)carve(2ull * 192 * 192 * 4);
    float* biasPre  = (float*)carve(2ull * 1152 * 4);
    float* gbx      = (float*)carve(2ull * 384 * 4);
    uint32_t* Hb    = (uint32_t*)carve(8ull * NW * KD * 256 * 4);
    float* MPb      = (float*)carve(8ull * NW * 192 * 4);
    float* Kb       = (float*)carve(8ull * NW * 4);
    int* flagM      = (int*)carve(32 * 4);
    int* flagH      = (int*)carve(32 * 4);
    float* h1 = PRE;
    float* h2 = PRE + 2048 * 192;

    prepack_kernel<<<dim3((192 * 1152 + 255) / 256), 256, 0, stream>>>(
        wr0, wr1, c_wih, c_whh, c_bih, c_bhh, p_wih, p_whh, p_bih, p_bhh,
        WpreT, W4, Wp32, biasPre, gbx);

    gemm_kernel<<<dim3(256, 1), 192, 0, stream>>>(features, 768, fc1_w, fc1_b,
                                                  Hcat, 576, 768, 192, 1);
    for (int l = 0; l < 2; ++l) {
        gemm_kernel<<<dim3(256, 6), 192, 0, stream>>>(Hcat + l * 192, 576,
            WpreT + (size_t)l * 192 * 1152, biasPre + l * 1152, PRE, 1152, 192, 1152, 0);
        scan_kernel<<<dim3(32), 576, 0, stream>>>(Hcat + l * 192, Hcat + (l + 1) * 192,
            PRE, adj, smask,
            W4 + (size_t)l * NW * 96 * GC,
            Wp32 + (size_t)l * 192 * 192,
            gbx + l * 384, gat_w + l * 384,
            Hb, MPb, Kb, flagM, flagH,
            out + 393216 + l * 65536, 1 + l * 600);
    }
    gemm_kernel<<<dim3(256, 1), 192, 0, stream>>>(Hcat, 576, mw0, mb0, h1, 192, 576, 192, 1);
    gemm_kernel<<<dim3(256, 1), 192, 0, stream>>>(h1, 192, mw1, mb1, h2, 192, 192, 192, 1);
    gemm_kernel<<<dim3(256, 1), 192, 0, stream>>>(h2, 192, mw2, mb2, out, 192, 192, 192, 0);
}

// Round 6
// 3566.513 us; speedup vs baseline: 6.1424x; 1.3325x over previous
//
#include <hip/hip_runtime.h>
#include <stdint.h>

#define B_  8
#define N_  256
#define DH_ 192
#define L_  2
#define G3  576
#define G6  1152
#define NW  4      // WGs per batch
#define DS  48     // d-slice per WG
#define KD  24     // H-history dwords per WG (48 bf16)
#define GC  288    // g-cols per WG (6 gates x 48)

typedef unsigned long long u64;

__device__ __forceinline__ float bflo(uint32_t u) { return __uint_as_float(u << 16); }
__device__ __forceinline__ float bfhi(uint32_t u) { return __uint_as_float(u & 0xffff0000u); }
__device__ __forceinline__ uint32_t f2bf(float f) {
    uint32_t x = __float_as_uint(f);
    x += 0x7fffu + ((x >> 16) & 1u);          // RNE
    return x >> 16;
}
__device__ __forceinline__ float sigm(float x)  { return 1.f / (1.f + __expf(-x)); }
__device__ __forceinline__ float tanhf_(float x){ return 1.f - 2.f / (1.f + __expf(2.f * x)); }
__device__ __forceinline__ u64 packvs(float v, int st) {
    return ((u64)(uint32_t)st << 32) | __float_as_uint(v);
}

// ---------------------------------------------------------------------------
// Prepack per layer:
//   WpreT fp32 [192][1152] : rows [cwih | pwhh]  (PRE GEMM B-matrix)
//   W4  u32 [4 w][27648]: pos = p4*1152 + c2*4 + s; k-pair p = 4*p4+s (k=2p,2p+1);
//       c2 = 48*j + dd -> global col c = 192*j + 48*w + dd;
//       value = pack(bf(Wbig[2p][c]), bf(Wbig[2p+1][c]))
//       Wbig[k][c] = (c<576)? cwhh[c][k] : pwih[c-576][k]
//   Wr4 u32 [4 w][9216]: pos = kq*768 + d*4 + s; k = 48*w + 4*kq + s;
//       value = pack(bf(wr0[d][k]), bf(wr1[d][k]))
//   biasPre fp32 [1152] : [cbih|pbhh] + r,z-gate bias folds
//   gbx fp32 [384] : n-gate biases [cbhh_n | pbih_n]
// ---------------------------------------------------------------------------
__global__ void prepack_kernel(
    const float* __restrict__ wr0, const float* __restrict__ wr1,
    const float* __restrict__ c_wih, const float* __restrict__ c_whh,
    const float* __restrict__ c_bih, const float* __restrict__ c_bhh,
    const float* __restrict__ p_wih, const float* __restrict__ p_whh,
    const float* __restrict__ p_bih, const float* __restrict__ p_bhh,
    float* __restrict__ WpreT, uint32_t* __restrict__ W4,
    uint32_t* __restrict__ Wr4, float* __restrict__ biasPre, float* __restrict__ gbx)
{
    int idx = blockIdx.x * blockDim.x + threadIdx.x;
    if (idx >= DH_ * G6) return;
    for (int l = 0; l < L_; ++l) {
        const float* cwih = c_wih + l * G3 * DH_;
        const float* cwhh = c_whh + l * G3 * DH_;
        const float* pwih = p_wih + l * G3 * DH_;
        const float* pwhh = p_whh + l * G3 * DH_;
        {   // WpreT
            int k = idx / G6, r = idx - k * G6;
            float w = (r < G3) ? cwih[r * DH_ + k] : pwhh[(r - G3) * DH_ + k];
            WpreT[l * DH_ * G6 + k * G6 + r] = w;
        }
        if (idx < NW * 27648) {   // W4
            int w = idx / 27648, pos = idx % 27648;
            int p4 = pos / 1152, rem = pos % 1152;
            int c2 = rem >> 2, s = rem & 3;
            int p = 4 * p4 + s;
            int j = c2 / DS, dd = c2 % DS;
            int c = 192 * j + DS * w + dd;
            float w0 = (c < G3) ? cwhh[c * DH_ + 2 * p]     : pwih[(c - G3) * DH_ + 2 * p];
            float w1 = (c < G3) ? cwhh[c * DH_ + 2 * p + 1] : pwih[(c - G3) * DH_ + 2 * p + 1];
            W4[l * NW * 27648 + idx] = f2bf(w0) | (f2bf(w1) << 16);
        }
        if (idx < NW * 9216) {   // Wr4
            int w = idx / 9216, pos = idx % 9216;
            int kq = pos / 768, rem = pos % 768;
            int d = rem >> 2, s = rem & 3;
            int k = DS * w + 4 * kq + s;
            Wr4[l * NW * 9216 + idx] =
                f2bf(wr0[l * DH_ * DH_ + d * DH_ + k]) |
                (f2bf(wr1[l * DH_ * DH_ + d * DH_ + k]) << 16);
        }
        if (idx < G6) {  // biasPre with r,z folds
            float base = (idx < G3) ? c_bih[l * G3 + idx] : p_bhh[l * G3 + idx - G3];
            float fold = 0.f;
            if (idx < 384)                    fold = c_bhh[l * G3 + idx];
            else if (idx >= G3 && idx < 960)  fold = p_bih[l * G3 + idx - G3];
            biasPre[l * G6 + idx] = base + fold;
        }
        if (idx < 384) {
            gbx[l * 384 + idx] = (idx < DH_) ? c_bhh[l * G3 + 384 + idx]
                                             : p_bih[l * G3 + 384 + (idx - DH_)];
        }
    }
}

// ---------------------------------------------------------------------------
// Generic small GEMM (parallel phases): C = relu?(A @ B + bias)
// ---------------------------------------------------------------------------
#define GR 8
__global__ __launch_bounds__(192) void gemm_kernel(
    const float* __restrict__ A, int lda, const float* __restrict__ Bm,
    const float* __restrict__ bias, float* __restrict__ C, int ldc,
    int K, int cols, int relu)
{
    __shared__ float sA[GR][64];
    const int c  = blockIdx.y * 192 + threadIdx.x;
    const int r0 = blockIdx.x * GR;
    float acc[GR] = {0.f, 0.f, 0.f, 0.f, 0.f, 0.f, 0.f, 0.f};
    for (int k0 = 0; k0 < K; k0 += 64) {
        for (int idx = threadIdx.x; idx < GR * 64; idx += 192) {
            int rr = idx >> 6, kk = idx & 63;
            sA[rr][kk] = A[(size_t)(r0 + rr) * lda + k0 + kk];
        }
        __syncthreads();
        #pragma unroll 8
        for (int kk = 0; kk < 64; ++kk) {
            float bv = Bm[(size_t)(k0 + kk) * cols + c];
            #pragma unroll
            for (int rr = 0; rr < GR; ++rr) acc[rr] += sA[rr][kk] * bv;
        }
        __syncthreads();
    }
    float bv = bias[c];
    #pragma unroll
    for (int rr = 0; rr < GR; ++rr) {
        float v = acc[rr] + bv;
        if (relu) v = fmaxf(v, 0.f);
        C[(size_t)(r0 + rr) * ldc + c] = v;
    }
}

// ---------------------------------------------------------------------------
// Multi-CU scan: 4 WGs per batch, weights LDS-resident (b128 layout).
// Cross-WG exchange via stamped u64 payloads (fp32|stamp) — no flags,
// no fences, equality-polled (poison-safe). 6 barriers/step.
// Idle waves (t>=384) stage next-step rows into LDS during the U phase.
// ---------------------------------------------------------------------------
__global__ __launch_bounds__(576, 1) void scan_kernel(
    const float* __restrict__ xin,  float* __restrict__ hout,   // row stride 576
    const float* __restrict__ PRE,  const float* __restrict__ adj,
    const float* __restrict__ smask,
    const uint32_t* __restrict__ W4,    // this layer: [4][27648]
    const uint32_t* __restrict__ Wr4,   // this layer: [4][9216]
    const float* __restrict__ gbx,      // this layer: [384]
    const float* __restrict__ gatw,     // this layer: [384] = wq | wk
    uint32_t* __restrict__ Hb,          // [8 b][4 w][24 kd][256 j]
    u64* __restrict__ MPs,              // [8][4][192] stamped
    u64* __restrict__ Kd,               // [8][4] stamped
    float* __restrict__ As, int sbase)
{
    const int blk = blockIdx.x;
    const int b = blk & 7, w = blk >> 3;
    const int t = threadIdx.x;
    const int lane = t & 63, wave = t >> 6;
    const int dg0 = w * DS;

    __shared__ uint4 Wlds4[24 * GC];            // 110,592 B
    __shared__ uint4 Wr4s[12 * DH_];            //  36,864 B
    __shared__ float sA0[N_], sA1[N_], sKsc[N_];
    __shared__ __align__(16) float sAdjN[N_], sSmN[N_];
    __shared__ __align__(16) float sXq[DH_], sPre[6 * DS], sXv[DS];
    __shared__ float sM[DH_], su0[DS], su1[DS], sGc[GC], sHn[DS];
    __shared__ float sRedS[4], sRedX[3];

    const float* adjB = adj   + (size_t)b * N_ * N_;
    const float* smB  = smask + (size_t)b * N_ * N_;
    float* AsB        = As    + (size_t)b * (L_ * N_ * N_);
    uint32_t* Hw      = Hb    + (size_t)(b * NW + w) * KD * N_;
    const int fi = b * NW;

    // ---- LDS-resident weights ---------------------------------------------
    {
        const uint32_t* W4w = W4 + (size_t)w * 27648;
        uint32_t* wl = (uint32_t*)Wlds4;
        for (int q = t; q < 27648; q += 576) wl[q] = W4w[q];
        const uint32_t* Wrw = Wr4 + (size_t)w * 9216;
        uint32_t* wr = (uint32_t*)Wr4s;
        for (int q = t; q < 9216; q += 576) wr[q] = Wrw[q];
    }

    float wqv = (t < DH_) ? gatw[t] : 0.f;
    float wkv = 0.f, g2b = 0.f, g5b = 0.f;
    if (t < DS) { wkv = gatw[DH_ + dg0 + t]; g2b = gbx[dg0 + t]; g5b = gbx[DH_ + dg0 + t]; }
    if (t < N_) sKsc[t] = 0.f;
    if (w == 0 && t < N_) AsB[t] = 0.f;

    // ---- step 0 (M = 0) ----------------------------------------------------
    {
        float hn = 0.f;
        if (t < DS) {
            const float* pre = PRE + (size_t)(b * N_) * G6 + dg0 + t;
            float xv = xin[(size_t)(b * N_) * G3 + dg0 + t];
            float r1 = sigm(pre[0]),   z1 = sigm(pre[192]), n1 = tanhf_(pre[384] + r1 * g2b);
            float Cv = (1.f - z1) * n1;
            float r2 = sigm(pre[576]), z2 = sigm(pre[768]), n2 = tanhf_(g5b + r2 * pre[960]);
            hn = Cv + (1.f - z2) * n2 + z2 * xv;
            sHn[t] = hn;
            hout[(size_t)(b * N_) * G3 + dg0 + t] = hn;
        }
        if (wave == 0) {
            float v = hn * wkv;
            #pragma unroll
            for (int o = 32; o; o >>= 1) v += __shfl_xor(v, o);
            if (lane == 0)
                __hip_atomic_store(&Kd[fi + w], packvs(v, sbase),
                                   __ATOMIC_RELAXED, __HIP_MEMORY_SCOPE_AGENT);
        }
        if (t < KD) Hw[(size_t)t * N_] = f2bf(sHn[2 * t]) | (f2bf(sHn[2 * t + 1]) << 16);
        // stage row 1 adj/sm + xin row 1 (for xq)
        for (int q = t; q < 176; q += 576) {
            if (q < 64)       *(float4*)&sAdjN[4 * q] = *(const float4*)(adjB + N_ + 4 * q);
            else if (q < 128) { int q2 = q - 64;  *(float4*)&sSmN[4 * q2] = *(const float4*)(smB + N_ + 4 * q2); }
            else              { int q2 = q - 128; *(float4*)&sXq[4 * q2] = *(const float4*)(xin + (size_t)(b * N_ + 1) * G3 + 4 * q2); }
        }
    }
    __syncthreads();
    {
        float px = (t < DH_) ? sXq[t] * wqv : 0.f;
        #pragma unroll
        for (int o = 32; o; o >>= 1) px += __shfl_xor(px, o);
        if (t < DH_ && lane == 0) sRedX[wave] = px;
    }
    __syncthreads();
    float xq = sRedX[0] + sRedX[1] + sRedX[2];

    // ---- main loop ---------------------------------------------------------
    for (int i = 1; i < N_; ++i) {
        const int row = b * N_ + i;
        const int stamp = sbase + i;
        // --- A: attention (single lane polls stamped kdot) ------------------
        float e = 0.f;
        {
            float ksn = 0.f;
            if (t == i - 1) {
                const uint32_t ex = (uint32_t)(stamp - 1);
                u64 k0, k1, k2, k3;
                do {
                    k0 = __hip_atomic_load(&Kd[fi + 0], __ATOMIC_RELAXED, __HIP_MEMORY_SCOPE_AGENT);
                    k1 = __hip_atomic_load(&Kd[fi + 1], __ATOMIC_RELAXED, __HIP_MEMORY_SCOPE_AGENT);
                    k2 = __hip_atomic_load(&Kd[fi + 2], __ATOMIC_RELAXED, __HIP_MEMORY_SCOPE_AGENT);
                    k3 = __hip_atomic_load(&Kd[fi + 3], __ATOMIC_RELAXED, __HIP_MEMORY_SCOPE_AGENT);
                } while ((uint32_t)(k0 >> 32) != ex || (uint32_t)(k1 >> 32) != ex ||
                         (uint32_t)(k2 >> 32) != ex || (uint32_t)(k3 >> 32) != ex);
                ksn = __uint_as_float((uint32_t)k0) + __uint_as_float((uint32_t)k1)
                    + __uint_as_float((uint32_t)k2) + __uint_as_float((uint32_t)k3);
                sKsc[t] = ksn;
            }
            if (t < N_ && t < i && sAdjN[t] > 0.5f) {
                float ks = (t == i - 1) ? ksn : sKsc[t];
                e = __expf(xq + ks);
            }
            float ps = e;
            #pragma unroll
            for (int o = 32; o; o >>= 1) ps += __shfl_xor(ps, o);
            if (t < N_ && lane == 0) sRedS[wave] = ps;
        }
        __syncthreads();                                         // B1
        if (t < N_) {
            float ssum = sRedS[0] + sRedS[1] + sRedS[2] + sRedS[3];
            float a = e / ssum;
            if (w == 0) AsB[(size_t)i * N_ + t] = a;
            float b0 = a * sSmN[t];
            sA0[t] = b0; sA1[t] = a - b0;
        }
        __syncthreads();                                         // B2
        // --- U (t<384) | staging (t>=384) -----------------------------------
        if (t < 384) {
            const int kd = t >> 4, jp = t & 15;
            const uint32_t* hp = Hw + (size_t)kd * N_;
            float u0l = 0.f, u0h = 0.f, u1l = 0.f, u1h = 0.f;
            int j = jp;
            while (j + 48 < i) {
                uint32_t h0 = hp[j], h1 = hp[j + 16], h2 = hp[j + 32], h3 = hp[j + 48];
                float b0, b1;
                b0 = sA0[j];      b1 = sA1[j];
                u0l = fmaf(b0, bflo(h0), u0l); u0h = fmaf(b0, bfhi(h0), u0h);
                u1l = fmaf(b1, bflo(h0), u1l); u1h = fmaf(b1, bfhi(h0), u1h);
                b0 = sA0[j + 16]; b1 = sA1[j + 16];
                u0l = fmaf(b0, bflo(h1), u0l); u0h = fmaf(b0, bfhi(h1), u0h);
                u1l = fmaf(b1, bflo(h1), u1l); u1h = fmaf(b1, bfhi(h1), u1h);
                b0 = sA0[j + 32]; b1 = sA1[j + 32];
                u0l = fmaf(b0, bflo(h2), u0l); u0h = fmaf(b0, bfhi(h2), u0h);
                u1l = fmaf(b1, bflo(h2), u1l); u1h = fmaf(b1, bfhi(h2), u1h);
                b0 = sA0[j + 48]; b1 = sA1[j + 48];
                u0l = fmaf(b0, bflo(h3), u0l); u0h = fmaf(b0, bfhi(h3), u0h);
                u1l = fmaf(b1, bflo(h3), u1l); u1h = fmaf(b1, bfhi(h3), u1h);
                j += 64;
            }
            for (; j < i; j += 16) {
                uint32_t hv = hp[j];
                float b0 = sA0[j], b1 = sA1[j];
                u0l = fmaf(b0, bflo(hv), u0l); u0h = fmaf(b0, bfhi(hv), u0h);
                u1l = fmaf(b1, bflo(hv), u1l); u1h = fmaf(b1, bfhi(hv), u1h);
            }
            #pragma unroll
            for (int o = 1; o <= 8; o <<= 1) {
                u0l += __shfl_xor(u0l, o); u0h += __shfl_xor(u0h, o);
                u1l += __shfl_xor(u1l, o); u1h += __shfl_xor(u1h, o);
            }
            if (jp == 0) {
                su0[2 * kd] = u0l; su0[2 * kd + 1] = u0h;
                su1[2 * kd] = u1l; su1[2 * kd + 1] = u1h;
            }
        } else {
            const int u = t - 384;
            const int inx = (i + 1 < N_) ? i + 1 : N_ - 1;
            for (int q = u; q < 260; q += 192) {
                if (q < 64)
                    *(float4*)&sAdjN[4 * q] = *(const float4*)(adjB + (size_t)inx * N_ + 4 * q);
                else if (q < 128) { int q2 = q - 64;
                    *(float4*)&sSmN[4 * q2] = *(const float4*)(smB + (size_t)inx * N_ + 4 * q2); }
                else if (q < 140) { int q2 = q - 128;
                    *(float4*)&sXv[4 * q2] = *(const float4*)(xin + (size_t)row * G3 + dg0 + 4 * q2); }
                else if (q < 212) { int q2 = q - 140; int g = q2 / 12, o = q2 - 12 * g;
                    *(float4*)&sPre[g * DS + 4 * o] =
                        *(const float4*)(PRE + (size_t)row * G6 + g * DH_ + dg0 + 4 * o); }
                else { int q2 = q - 212;
                    *(float4*)&sXq[4 * q2] = *(const float4*)(xin + (size_t)(b * N_ + inx) * G3 + 4 * q2); }
            }
        }
        __syncthreads();                                         // B3
        // --- Mp + stamped exchange (t<192) ----------------------------------
        if (t < DH_) {
            float mp = 0.f;
            #pragma unroll 4
            for (int kq = 0; kq < 12; ++kq) {
                uint4 wv = Wr4s[kq * DH_ + t];
                const int k0 = 4 * kq;
                mp = fmaf(su0[k0 + 0], bflo(wv.x), mp); mp = fmaf(su1[k0 + 0], bfhi(wv.x), mp);
                mp = fmaf(su0[k0 + 1], bflo(wv.y), mp); mp = fmaf(su1[k0 + 1], bfhi(wv.y), mp);
                mp = fmaf(su0[k0 + 2], bflo(wv.z), mp); mp = fmaf(su1[k0 + 2], bfhi(wv.z), mp);
                mp = fmaf(su0[k0 + 3], bflo(wv.w), mp); mp = fmaf(su1[k0 + 3], bfhi(wv.w), mp);
            }
            __hip_atomic_store(&MPs[(size_t)(fi + w) * DH_ + t], packvs(mp, stamp),
                               __ATOMIC_RELAXED, __HIP_MEMORY_SCOPE_AGENT);
            const int w1 = (w + 1) & 3, w2 = (w + 2) & 3, w3 = (w + 3) & 3;
            u64* pA = &MPs[(size_t)(fi + w1) * DH_ + t];
            u64* pB = &MPs[(size_t)(fi + w2) * DH_ + t];
            u64* pC = &MPs[(size_t)(fi + w3) * DH_ + t];
            const uint32_t ex = (uint32_t)stamp;
            u64 vA, vB, vC;
            do {
                vA = __hip_atomic_load(pA, __ATOMIC_RELAXED, __HIP_MEMORY_SCOPE_AGENT);
                vB = __hip_atomic_load(pB, __ATOMIC_RELAXED, __HIP_MEMORY_SCOPE_AGENT);
                vC = __hip_atomic_load(pC, __ATOMIC_RELAXED, __HIP_MEMORY_SCOPE_AGENT);
            } while ((uint32_t)(vA >> 32) != ex || (uint32_t)(vB >> 32) != ex ||
                     (uint32_t)(vC >> 32) != ex);
            sM[t] = mp + __uint_as_float((uint32_t)vA)
                       + __uint_as_float((uint32_t)vB)
                       + __uint_as_float((uint32_t)vC);
        }
        __syncthreads();                                         // B4
        // --- G: g-slice from b128 LDS weights -------------------------------
        {
            const int c = t >> 1, kh = t & 1;
            const uint4* wp = Wlds4 + (12 * kh) * GC + c;
            float g = 0.f;
            #pragma unroll 4
            for (int p4 = 0; p4 < 12; ++p4) {
                uint4 wv = wp[p4 * GC];
                const int m0 = 8 * (12 * kh + p4);
                g = fmaf(sM[m0 + 0], bflo(wv.x), g); g = fmaf(sM[m0 + 1], bfhi(wv.x), g);
                g = fmaf(sM[m0 + 2], bflo(wv.y), g); g = fmaf(sM[m0 + 3], bfhi(wv.y), g);
                g = fmaf(sM[m0 + 4], bflo(wv.z), g); g = fmaf(sM[m0 + 5], bfhi(wv.z), g);
                g = fmaf(sM[m0 + 6], bflo(wv.w), g); g = fmaf(sM[m0 + 7], bfhi(wv.w), g);
            }
            g += __shfl_xor(g, 1);
            if (kh == 0) sGc[c] = g;
        }
        __syncthreads();                                         // B5
        // --- gates + kdot + history + next-xq -------------------------------
        {
            float hn = 0.f;
            if (t < DS) {
                float Mv = sM[dg0 + t];
                float r1 = sigm(sPre[t] + sGc[t]);
                float z1 = sigm(sPre[DS + t] + sGc[DS + t]);
                float n1 = tanhf_(sPre[2 * DS + t] + r1 * (sGc[2 * DS + t] + g2b));
                float Cv = (1.f - z1) * n1 + z1 * Mv;
                float r2 = sigm(sGc[3 * DS + t] + sPre[3 * DS + t]);
                float z2 = sigm(sGc[4 * DS + t] + sPre[4 * DS + t]);
                float n2 = tanhf_(sGc[5 * DS + t] + g5b + r2 * sPre[5 * DS + t]);
                hn = Cv + (1.f - z2) * n2 + z2 * sXv[t];
                sHn[t] = hn;
                hout[(size_t)row * G3 + dg0 + t] = hn;
            }
            if (wave == 0) {
                float v = hn * wkv;
                #pragma unroll
                for (int o = 32; o; o >>= 1) v += __shfl_xor(v, o);
                if (lane == 0)
                    __hip_atomic_store(&Kd[fi + w], packvs(v, stamp),
                                       __ATOMIC_RELAXED, __HIP_MEMORY_SCOPE_AGENT);
            }
            if (t < KD) Hw[(size_t)t * N_ + i] = f2bf(sHn[2 * t]) | (f2bf(sHn[2 * t + 1]) << 16);
            float px = (t < DH_) ? sXq[t] * wqv : 0.f;
            #pragma unroll
            for (int o = 32; o; o >>= 1) px += __shfl_xor(px, o);
            if (t < DH_ && lane == 0) sRedX[wave] = px;
        }
        __syncthreads();                                         // B6
        xq = sRedX[0] + sRedX[1] + sRedX[2];
    }
}

// ---------------------------------------------------------------------------
extern "C" void kernel_launch(void* const* d_in, const int* in_sizes, int n_in,
                              void* d_out, int out_size, void* d_ws, size_t ws_size,
                              hipStream_t stream)
{
    const float* features = (const float*)d_in[0];
    const float* adj      = (const float*)d_in[1];
    const float* smask    = (const float*)d_in[2];
    const float* fc1_w = (const float*)d_in[5];
    const float* fc1_b = (const float*)d_in[6];
    const float* gat_w = (const float*)d_in[7];
    const float* wr0   = (const float*)d_in[9];
    const float* wr1   = (const float*)d_in[10];
    const float* c_wih = (const float*)d_in[11];
    const float* c_whh = (const float*)d_in[12];
    const float* c_bih = (const float*)d_in[13];
    const float* c_bhh = (const float*)d_in[14];
    const float* p_wih = (const float*)d_in[15];
    const float* p_whh = (const float*)d_in[16];
    const float* p_bih = (const float*)d_in[17];
    const float* p_bhh = (const float*)d_in[18];
    const float* mw0 = (const float*)d_in[19];
    const float* mb0 = (const float*)d_in[20];
    const float* mw1 = (const float*)d_in[21];
    const float* mb1 = (const float*)d_in[22];
    const float* mw2 = (const float*)d_in[23];
    const float* mb2 = (const float*)d_in[24];
    float* out = (float*)d_out;

    char* wsb = (char*)d_ws;
    size_t off = 0;
    auto carve = [&](size_t bytes) -> char* {
        char* p = wsb + off;
        off = (off + bytes + 255) & ~(size_t)255;
        return p;
    };
    float* Hcat     = (float*)carve(2048ull * 576 * 4);
    float* PRE      = (float*)carve(2048ull * 1152 * 4);
    float* WpreT    = (float*)carve(2ull * 192 * 1152 * 4);
    uint32_t* W4    = (uint32_t*)carve(2ull * NW * 27648 * 4);
    uint32_t* Wr4   = (uint32_t*)carve(2ull * NW * 9216 * 4);
    float* biasPre  = (float*)carve(2ull * 1152 * 4);
    float* gbx      = (float*)carve(2ull * 384 * 4);
    uint32_t* Hb    = (uint32_t*)carve(8ull * NW * KD * 256 * 4);
    u64* MPs        = (u64*)carve(8ull * NW * 192 * 8);
    u64* Kd         = (u64*)carve(8ull * NW * 8);
    float* h1 = PRE;
    float* h2 = PRE + 2048 * 192;

    prepack_kernel<<<dim3((192 * 1152 + 255) / 256), 256, 0, stream>>>(
        wr0, wr1, c_wih, c_whh, c_bih, c_bhh, p_wih, p_whh, p_bih, p_bhh,
        WpreT, W4, Wr4, biasPre, gbx);

    gemm_kernel<<<dim3(256, 1), 192, 0, stream>>>(features, 768, fc1_w, fc1_b,
                                                  Hcat, 576, 768, 192, 1);
    for (int l = 0; l < 2; ++l) {
        gemm_kernel<<<dim3(256, 6), 192, 0, stream>>>(Hcat + l * 192, 576,
            WpreT + (size_t)l * 192 * 1152, biasPre + l * 1152, PRE, 1152, 192, 1152, 0);
        scan_kernel<<<dim3(32), 576, 0, stream>>>(Hcat + l * 192, Hcat + (l + 1) * 192,
            PRE, adj, smask,
            W4 + (size_t)l * NW * 27648,
            Wr4 + (size_t)l * NW * 9216,
            gbx + l * 384, gat_w + l * 384,
            Hb, MPs, Kd,
            out + 393216 + l * 65536, 1 + l * 1000);
    }
    gemm_kernel<<<dim3(256, 1), 192, 0, stream>>>(Hcat, 576, mw0, mb0, h1, 192, 576, 192, 1);
    gemm_kernel<<<dim3(256, 1), 192, 0, stream>>>(h1, 192, mw1, mb1, h2, 192, 192, 192, 1);
    gemm_kernel<<<dim3(256, 1), 192, 0, stream>>>(h2, 192, mw2, mb2, out, 192, 192, 192, 0);
}

// Round 7
// 3474.195 us; speedup vs baseline: 6.3057x; 1.0266x over previous
//
#include <hip/hip_runtime.h>
#include <stdint.h>

#define B_  8
#define N_  256
#define DH_ 192
#define L_  2
#define G3  576
#define G6  1152
#define NW  4      // WGs per batch
#define DS  48     // d-slice per WG
#define KD  24     // H-history dwords per WG (48 bf16)
#define GC  288    // g-cols per WG (6 gates x 48)

typedef unsigned long long u64;

__device__ __forceinline__ float bflo(uint32_t u) { return __uint_as_float(u << 16); }
__device__ __forceinline__ float bfhi(uint32_t u) { return __uint_as_float(u & 0xffff0000u); }
__device__ __forceinline__ uint32_t f2bf(float f) {
    uint32_t x = __float_as_uint(f);
    x += 0x7fffu + ((x >> 16) & 1u);          // RNE
    return x >> 16;
}
__device__ __forceinline__ float sigm(float x)  { return 1.f / (1.f + __expf(-x)); }
__device__ __forceinline__ float tanhf_(float x){ return 1.f - 2.f / (1.f + __expf(2.f * x)); }
__device__ __forceinline__ u64 packvs(float v, int st) {
    return ((u64)(uint32_t)st << 32) | __float_as_uint(v);
}

// ---------------------------------------------------------------------------
// Prepack per layer (same layouts as round 6):
//   WpreT fp32 [192][1152] : rows [cwih | pwhh]  (PRE GEMM B-matrix)
//   W4  u32 [4 w][27648]: pos = p4*1152 + c2*4 + s; k-pair p = 4*p4+s;
//       c2 = 48*j + dd -> global col c = 192*j + 48*w + dd;
//       value = pack(bf(Wbig[2p][c]), bf(Wbig[2p+1][c]))
//   Wr4 u32 [4 w][9216]: pos = kq*768 + d*4 + s; k = 48*w + 4*kq + s;
//       value = pack(bf(wr0[d][k]), bf(wr1[d][k]))
//   biasPre fp32 [1152] : [cbih|pbhh] + r,z-gate bias folds
//   gbx fp32 [384] : n-gate biases [cbhh_n | pbih_n]
// ---------------------------------------------------------------------------
__global__ void prepack_kernel(
    const float* __restrict__ wr0, const float* __restrict__ wr1,
    const float* __restrict__ c_wih, const float* __restrict__ c_whh,
    const float* __restrict__ c_bih, const float* __restrict__ c_bhh,
    const float* __restrict__ p_wih, const float* __restrict__ p_whh,
    const float* __restrict__ p_bih, const float* __restrict__ p_bhh,
    float* __restrict__ WpreT, uint32_t* __restrict__ W4,
    uint32_t* __restrict__ Wr4, float* __restrict__ biasPre, float* __restrict__ gbx)
{
    int idx = blockIdx.x * blockDim.x + threadIdx.x;
    if (idx >= DH_ * G6) return;
    for (int l = 0; l < L_; ++l) {
        const float* cwih = c_wih + l * G3 * DH_;
        const float* cwhh = c_whh + l * G3 * DH_;
        const float* pwih = p_wih + l * G3 * DH_;
        const float* pwhh = p_whh + l * G3 * DH_;
        {   // WpreT
            int k = idx / G6, r = idx - k * G6;
            float w = (r < G3) ? cwih[r * DH_ + k] : pwhh[(r - G3) * DH_ + k];
            WpreT[l * DH_ * G6 + k * G6 + r] = w;
        }
        if (idx < NW * 27648) {   // W4
            int w = idx / 27648, pos = idx % 27648;
            int p4 = pos / 1152, rem = pos % 1152;
            int c2 = rem >> 2, s = rem & 3;
            int p = 4 * p4 + s;
            int j = c2 / DS, dd = c2 % DS;
            int c = 192 * j + DS * w + dd;
            float w0 = (c < G3) ? cwhh[c * DH_ + 2 * p]     : pwih[(c - G3) * DH_ + 2 * p];
            float w1 = (c < G3) ? cwhh[c * DH_ + 2 * p + 1] : pwih[(c - G3) * DH_ + 2 * p + 1];
            W4[l * NW * 27648 + idx] = f2bf(w0) | (f2bf(w1) << 16);
        }
        if (idx < NW * 9216) {   // Wr4
            int w = idx / 9216, pos = idx % 9216;
            int kq = pos / 768, rem = pos % 768;
            int d = rem >> 2, s = rem & 3;
            int k = DS * w + 4 * kq + s;
            Wr4[l * NW * 9216 + idx] =
                f2bf(wr0[l * DH_ * DH_ + d * DH_ + k]) |
                (f2bf(wr1[l * DH_ * DH_ + d * DH_ + k]) << 16);
        }
        if (idx < G6) {  // biasPre with r,z folds
            float base = (idx < G3) ? c_bih[l * G3 + idx] : p_bhh[l * G3 + idx - G3];
            float fold = 0.f;
            if (idx < 384)                    fold = c_bhh[l * G3 + idx];
            else if (idx >= G3 && idx < 960)  fold = p_bih[l * G3 + idx - G3];
            biasPre[l * G6 + idx] = base + fold;
        }
        if (idx < 384) {
            gbx[l * 384 + idx] = (idx < DH_) ? c_bhh[l * G3 + 384 + idx]
                                             : p_bih[l * G3 + 384 + (idx - DH_)];
        }
    }
}

// ---------------------------------------------------------------------------
// Generic small GEMM (parallel phases): C = relu?(A @ B + bias)
// ---------------------------------------------------------------------------
#define GR 8
__global__ __launch_bounds__(192) void gemm_kernel(
    const float* __restrict__ A, int lda, const float* __restrict__ Bm,
    const float* __restrict__ bias, float* __restrict__ C, int ldc,
    int K, int cols, int relu)
{
    __shared__ float sA[GR][64];
    const int c  = blockIdx.y * 192 + threadIdx.x;
    const int r0 = blockIdx.x * GR;
    float acc[GR] = {0.f, 0.f, 0.f, 0.f, 0.f, 0.f, 0.f, 0.f};
    for (int k0 = 0; k0 < K; k0 += 64) {
        for (int idx = threadIdx.x; idx < GR * 64; idx += 192) {
            int rr = idx >> 6, kk = idx & 63;
            sA[rr][kk] = A[(size_t)(r0 + rr) * lda + k0 + kk];
        }
        __syncthreads();
        #pragma unroll 8
        for (int kk = 0; kk < 64; ++kk) {
            float bv = Bm[(size_t)(k0 + kk) * cols + c];
            #pragma unroll
            for (int rr = 0; rr < GR; ++rr) acc[rr] += sA[rr][kk] * bv;
        }
        __syncthreads();
    }
    float bv = bias[c];
    #pragma unroll
    for (int rr = 0; rr < GR; ++rr) {
        float v = acc[rr] + bv;
        if (relu) v = fmaxf(v, 0.f);
        C[(size_t)(r0 + rr) * ldc + c] = v;
    }
}

// ---------------------------------------------------------------------------
// Multi-CU scan, round 7: unnormalized-softmax restructure hides the kdot
// RT under the U phase (poller = t 575); the j=i-1 attention term is folded
// into Mp analytically (reusing the same Wr4s loads). 5 barriers/step,
// single exposed cross-WG RT (M exchange).
// ---------------------------------------------------------------------------
__global__ __launch_bounds__(576, 1) void scan_kernel(
    const float* __restrict__ xin,  float* __restrict__ hout,   // row stride 576
    const float* __restrict__ PRE,  const float* __restrict__ adj,
    const float* __restrict__ smask,
    const uint32_t* __restrict__ W4,    // this layer: [4][27648]
    const uint32_t* __restrict__ Wr4,   // this layer: [4][9216]
    const float* __restrict__ gbx,      // this layer: [384]
    const float* __restrict__ gatw,     // this layer: [384] = wq | wk
    uint32_t* __restrict__ Hb,          // [8 b][4 w][24 kd][256 j]
    u64* __restrict__ MPs,              // [8][4][192] stamped
    u64* __restrict__ Kd,               // [8][4] stamped
    float* __restrict__ As, int sbase)
{
    const int blk = blockIdx.x;
    const int b = blk & 7, w = blk >> 3;
    const int t = threadIdx.x;
    const int lane = t & 63, wave = t >> 6;
    const int dg0 = w * DS;

    __shared__ uint4 Wlds4[24 * GC];            // 110,592 B
    __shared__ uint4 Wr4s[12 * DH_];            //  36,864 B
    __shared__ float sA0[N_], sA1[N_], sKsc[N_];
    __shared__ __align__(16) float sAdjN[N_], sSmN[N_];
    __shared__ __align__(16) float sXq[DH_], sPre[6 * DS], sXv[DS];
    __shared__ float sM[DH_], su0[DS], su1[DS], sGc[GC], sHn[DS];
    __shared__ float sRedS[4], sRedX[3];
    __shared__ float sSaved[4];   // [0]=adj(i,i-1) [1]=sm(i,i-1) [2]=invS

    const float* adjB = adj   + (size_t)b * N_ * N_;
    const float* smB  = smask + (size_t)b * N_ * N_;
    float* AsB        = As    + (size_t)b * (L_ * N_ * N_);
    uint32_t* Hw      = Hb    + (size_t)(b * NW + w) * KD * N_;
    const int fi = b * NW;

    // ---- LDS-resident weights ---------------------------------------------
    {
        const uint32_t* W4w = W4 + (size_t)w * 27648;
        uint32_t* wl = (uint32_t*)Wlds4;
        for (int q = t; q < 27648; q += 576) wl[q] = W4w[q];
        const uint32_t* Wrw = Wr4 + (size_t)w * 9216;
        uint32_t* wr = (uint32_t*)Wr4s;
        for (int q = t; q < 9216; q += 576) wr[q] = Wrw[q];
    }

    float wqv = (t < DH_) ? gatw[t] : 0.f;
    float wkv = 0.f, g2b = 0.f, g5b = 0.f;
    if (t < DS) { wkv = gatw[DH_ + dg0 + t]; g2b = gbx[dg0 + t]; g5b = gbx[DH_ + dg0 + t]; }
    if (t < N_) sKsc[t] = 0.f;
    if (w == 0 && t < N_) AsB[t] = 0.f;

    // ---- step 0 (M = 0) ----------------------------------------------------
    {
        float hn = 0.f;
        if (t < DS) {
            const float* pre = PRE + (size_t)(b * N_) * G6 + dg0 + t;
            float xv = xin[(size_t)(b * N_) * G3 + dg0 + t];
            float r1 = sigm(pre[0]),   z1 = sigm(pre[192]), n1 = tanhf_(pre[384] + r1 * g2b);
            float Cv = (1.f - z1) * n1;
            float r2 = sigm(pre[576]), z2 = sigm(pre[768]), n2 = tanhf_(g5b + r2 * pre[960]);
            hn = Cv + (1.f - z2) * n2 + z2 * xv;
            sHn[t] = hn;
            hout[(size_t)(b * N_) * G3 + dg0 + t] = hn;
        }
        if (wave == 0) {
            float v = hn * wkv;
            #pragma unroll
            for (int o = 32; o; o >>= 1) v += __shfl_xor(v, o);
            if (lane == 0)
                __hip_atomic_store(&Kd[fi + w], packvs(v, sbase),
                                   __ATOMIC_RELAXED, __HIP_MEMORY_SCOPE_AGENT);
        }
        if (t < KD) Hw[(size_t)t * N_] = f2bf(sHn[2 * t]) | (f2bf(sHn[2 * t + 1]) << 16);
        // stage row 1 adj/sm + xin row 1 (for xq)
        for (int q = t; q < 176; q += 576) {
            if (q < 64)       *(float4*)&sAdjN[4 * q] = *(const float4*)(adjB + N_ + 4 * q);
            else if (q < 128) { int q2 = q - 64;  *(float4*)&sSmN[4 * q2] = *(const float4*)(smB + N_ + 4 * q2); }
            else              { int q2 = q - 128; *(float4*)&sXq[4 * q2] = *(const float4*)(xin + (size_t)(b * N_ + 1) * G3 + 4 * q2); }
        }
    }
    __syncthreads();
    {
        float px = (t < DH_) ? sXq[t] * wqv : 0.f;
        #pragma unroll
        for (int o = 32; o; o >>= 1) px += __shfl_xor(px, o);
        if (t < DH_ && lane == 0) sRedX[wave] = px;
    }
    __syncthreads();
    float xq = sRedX[0] + sRedX[1] + sRedX[2];

    // ---- main loop ---------------------------------------------------------
    for (int i = 1; i < N_; ++i) {
        const int row = b * N_ + i;
        const int stamp = sbase + i;
        // --- A: unnormalized scores for j <= i-2 (no kdot dependency) -------
        {
            float e = 0.f;
            if (t == i - 1) { sSaved[0] = sAdjN[t]; sSaved[1] = sSmN[t]; }
            if (t < N_) {
                if (t < i - 1 && sAdjN[t] > 0.5f) e = __expf(xq + sKsc[t]);
                float b0 = e * sSmN[t];
                sA0[t] = b0; sA1[t] = e - b0;
            }
            float ps = e;
            #pragma unroll
            for (int o = 32; o; o >>= 1) ps += __shfl_xor(ps, o);
            if (t < N_ && lane == 0) sRedS[wave] = ps;
        }
        __syncthreads();                                         // B1
        // --- U over j<=i-2 (t<384) | staging + kdot poll (t>=384) -----------
        if (t < 384) {
            const int ilim = i - 1;
            const int kd = t >> 4, jp = t & 15;
            const uint32_t* hp = Hw + (size_t)kd * N_;
            float u0l = 0.f, u0h = 0.f, u1l = 0.f, u1h = 0.f;
            int j = jp;
            while (j + 48 < ilim) {
                uint32_t h0 = hp[j], h1 = hp[j + 16], h2 = hp[j + 32], h3 = hp[j + 48];
                float b0, b1;
                b0 = sA0[j];      b1 = sA1[j];
                u0l = fmaf(b0, bflo(h0), u0l); u0h = fmaf(b0, bfhi(h0), u0h);
                u1l = fmaf(b1, bflo(h0), u1l); u1h = fmaf(b1, bfhi(h0), u1h);
                b0 = sA0[j + 16]; b1 = sA1[j + 16];
                u0l = fmaf(b0, bflo(h1), u0l); u0h = fmaf(b0, bfhi(h1), u0h);
                u1l = fmaf(b1, bflo(h1), u1l); u1h = fmaf(b1, bfhi(h1), u1h);
                b0 = sA0[j + 32]; b1 = sA1[j + 32];
                u0l = fmaf(b0, bflo(h2), u0l); u0h = fmaf(b0, bfhi(h2), u0h);
                u1l = fmaf(b1, bflo(h2), u1l); u1h = fmaf(b1, bfhi(h2), u1h);
                b0 = sA0[j + 48]; b1 = sA1[j + 48];
                u0l = fmaf(b0, bflo(h3), u0l); u0h = fmaf(b0, bfhi(h3), u0h);
                u1l = fmaf(b1, bflo(h3), u1l); u1h = fmaf(b1, bfhi(h3), u1h);
                j += 64;
            }
            for (; j < ilim; j += 16) {
                uint32_t hv = hp[j];
                float b0 = sA0[j], b1 = sA1[j];
                u0l = fmaf(b0, bflo(hv), u0l); u0h = fmaf(b0, bfhi(hv), u0h);
                u1l = fmaf(b1, bflo(hv), u1l); u1h = fmaf(b1, bfhi(hv), u1h);
            }
            #pragma unroll
            for (int o = 1; o <= 8; o <<= 1) {
                u0l += __shfl_xor(u0l, o); u0h += __shfl_xor(u0h, o);
                u1l += __shfl_xor(u1l, o); u1h += __shfl_xor(u1h, o);
            }
            if (jp == 0) {
                su0[2 * kd] = u0l; su0[2 * kd + 1] = u0h;
                su1[2 * kd] = u1l; su1[2 * kd + 1] = u1h;
            }
        } else {
            const int u = t - 384;
            const int inx = (i + 1 < N_) ? i + 1 : N_ - 1;
            for (int q = u; q < 260; q += 192) {
                if (q < 64)
                    *(float4*)&sAdjN[4 * q] = *(const float4*)(adjB + (size_t)inx * N_ + 4 * q);
                else if (q < 128) { int q2 = q - 64;
                    *(float4*)&sSmN[4 * q2] = *(const float4*)(smB + (size_t)inx * N_ + 4 * q2); }
                else if (q < 140) { int q2 = q - 128;
                    *(float4*)&sXv[4 * q2] = *(const float4*)(xin + (size_t)row * G3 + dg0 + 4 * q2); }
                else if (q < 212) { int q2 = q - 140; int g = q2 / 12, o = q2 - 12 * g;
                    *(float4*)&sPre[g * DS + 4 * o] =
                        *(const float4*)(PRE + (size_t)row * G6 + g * DH_ + dg0 + 4 * o); }
                else { int q2 = q - 212;
                    *(float4*)&sXq[4 * q2] = *(const float4*)(xin + (size_t)(b * N_ + inx) * G3 + 4 * q2); }
            }
            if (t == 575) {     // kdot poll, hidden under U
                const uint32_t ex = (uint32_t)(stamp - 1);
                u64 k0, k1, k2, k3;
                do {
                    k0 = __hip_atomic_load(&Kd[fi + 0], __ATOMIC_RELAXED, __HIP_MEMORY_SCOPE_AGENT);
                    k1 = __hip_atomic_load(&Kd[fi + 1], __ATOMIC_RELAXED, __HIP_MEMORY_SCOPE_AGENT);
                    k2 = __hip_atomic_load(&Kd[fi + 2], __ATOMIC_RELAXED, __HIP_MEMORY_SCOPE_AGENT);
                    k3 = __hip_atomic_load(&Kd[fi + 3], __ATOMIC_RELAXED, __HIP_MEMORY_SCOPE_AGENT);
                } while ((uint32_t)(k0 >> 32) != ex || (uint32_t)(k1 >> 32) != ex ||
                         (uint32_t)(k2 >> 32) != ex || (uint32_t)(k3 >> 32) != ex);
                float kdot = __uint_as_float((uint32_t)k0) + __uint_as_float((uint32_t)k1)
                           + __uint_as_float((uint32_t)k2) + __uint_as_float((uint32_t)k3);
                float adjI1 = sSaved[0], smI1 = sSaved[1];
                float e1 = (adjI1 > 0.5f) ? __expf(xq + kdot) : 0.f;
                float S = sRedS[0] + sRedS[1] + sRedS[2] + sRedS[3] + e1;
                sKsc[i - 1] = kdot;
                float c0 = e1 * smI1;
                sA0[i - 1] = c0; sA1[i - 1] = e1 - c0;
                sSaved[2] = 1.f / S;
            }
        }
        __syncthreads();                                         // B2
        // --- Mp with inline j=i-1 fixup + stamped exchange (t<192) ----------
        if (t < DH_) {
            float mp = 0.f, h0a = 0.f, h1a = 0.f;
            #pragma unroll 4
            for (int kq = 0; kq < 12; ++kq) {
                uint4 wv = Wr4s[kq * DH_ + t];
                const int k0 = 4 * kq;
                float lo, hi;
                lo = bflo(wv.x); hi = bfhi(wv.x);
                mp = fmaf(su0[k0 + 0], lo, mp); mp = fmaf(su1[k0 + 0], hi, mp);
                h0a = fmaf(sHn[k0 + 0], lo, h0a); h1a = fmaf(sHn[k0 + 0], hi, h1a);
                lo = bflo(wv.y); hi = bfhi(wv.y);
                mp = fmaf(su0[k0 + 1], lo, mp); mp = fmaf(su1[k0 + 1], hi, mp);
                h0a = fmaf(sHn[k0 + 1], lo, h0a); h1a = fmaf(sHn[k0 + 1], hi, h1a);
                lo = bflo(wv.z); hi = bfhi(wv.z);
                mp = fmaf(su0[k0 + 2], lo, mp); mp = fmaf(su1[k0 + 2], hi, mp);
                h0a = fmaf(sHn[k0 + 2], lo, h0a); h1a = fmaf(sHn[k0 + 2], hi, h1a);
                lo = bflo(wv.w); hi = bfhi(wv.w);
                mp = fmaf(su0[k0 + 3], lo, mp); mp = fmaf(su1[k0 + 3], hi, mp);
                h0a = fmaf(sHn[k0 + 3], lo, h0a); h1a = fmaf(sHn[k0 + 3], hi, h1a);
            }
            float invS = sSaved[2];
            mp = (mp + sA0[i - 1] * h0a + sA1[i - 1] * h1a) * invS;
            __hip_atomic_store(&MPs[(size_t)(fi + w) * DH_ + t], packvs(mp, stamp),
                               __ATOMIC_RELAXED, __HIP_MEMORY_SCOPE_AGENT);
            const int w1 = (w + 1) & 3, w2 = (w + 2) & 3, w3 = (w + 3) & 3;
            u64* pA = &MPs[(size_t)(fi + w1) * DH_ + t];
            u64* pB = &MPs[(size_t)(fi + w2) * DH_ + t];
            u64* pC = &MPs[(size_t)(fi + w3) * DH_ + t];
            const uint32_t ex = (uint32_t)stamp;
            u64 vA, vB, vC;
            do {
                vA = __hip_atomic_load(pA, __ATOMIC_RELAXED, __HIP_MEMORY_SCOPE_AGENT);
                vB = __hip_atomic_load(pB, __ATOMIC_RELAXED, __HIP_MEMORY_SCOPE_AGENT);
                vC = __hip_atomic_load(pC, __ATOMIC_RELAXED, __HIP_MEMORY_SCOPE_AGENT);
            } while ((uint32_t)(vA >> 32) != ex || (uint32_t)(vB >> 32) != ex ||
                     (uint32_t)(vC >> 32) != ex);
            sM[t] = mp + __uint_as_float((uint32_t)vA)
                       + __uint_as_float((uint32_t)vB)
                       + __uint_as_float((uint32_t)vC);
        } else if (w == 0 && t < 448) {
            // normalized attention output write (all 256 cols)
            int j = t - 192;
            AsB[(size_t)i * N_ + j] = (sA0[j] + sA1[j]) * sSaved[2];
        }
        __syncthreads();                                         // B3
        // --- G: g-slice from b128 LDS weights -------------------------------
        {
            const int c = t >> 1, kh = t & 1;
            const uint4* wp = Wlds4 + (12 * kh) * GC + c;
            float g = 0.f;
            #pragma unroll 4
            for (int p4 = 0; p4 < 12; ++p4) {
                uint4 wv = wp[p4 * GC];
                const int m0 = 8 * (12 * kh + p4);
                g = fmaf(sM[m0 + 0], bflo(wv.x), g); g = fmaf(sM[m0 + 1], bfhi(wv.x), g);
                g = fmaf(sM[m0 + 2], bflo(wv.y), g); g = fmaf(sM[m0 + 3], bfhi(wv.y), g);
                g = fmaf(sM[m0 + 4], bflo(wv.z), g); g = fmaf(sM[m0 + 5], bfhi(wv.z), g);
                g = fmaf(sM[m0 + 6], bflo(wv.w), g); g = fmaf(sM[m0 + 7], bfhi(wv.w), g);
            }
            g += __shfl_xor(g, 1);
            if (kh == 0) sGc[c] = g;
        }
        __syncthreads();                                         // B4
        // --- gates + kdot publish + history + next-xq -----------------------
        {
            float hn = 0.f;
            if (t < DS) {
                float Mv = sM[dg0 + t];
                float r1 = sigm(sPre[t] + sGc[t]);
                float z1 = sigm(sPre[DS + t] + sGc[DS + t]);
                float n1 = tanhf_(sPre[2 * DS + t] + r1 * (sGc[2 * DS + t] + g2b));
                float Cv = (1.f - z1) * n1 + z1 * Mv;
                float r2 = sigm(sGc[3 * DS + t] + sPre[3 * DS + t]);
                float z2 = sigm(sGc[4 * DS + t] + sPre[4 * DS + t]);
                float n2 = tanhf_(sGc[5 * DS + t] + g5b + r2 * sPre[5 * DS + t]);
                hn = Cv + (1.f - z2) * n2 + z2 * sXv[t];
                sHn[t] = hn;
                hout[(size_t)row * G3 + dg0 + t] = hn;
            }
            if (wave == 0) {
                float v = hn * wkv;
                #pragma unroll
                for (int o = 32; o; o >>= 1) v += __shfl_xor(v, o);
                if (lane == 0)
                    __hip_atomic_store(&Kd[fi + w], packvs(v, stamp),
                                       __ATOMIC_RELAXED, __HIP_MEMORY_SCOPE_AGENT);
            }
            if (t < KD) Hw[(size_t)t * N_ + i] = f2bf(sHn[2 * t]) | (f2bf(sHn[2 * t + 1]) << 16);
            float px = (t < DH_) ? sXq[t] * wqv : 0.f;
            #pragma unroll
            for (int o = 32; o; o >>= 1) px += __shfl_xor(px, o);
            if (t < DH_ && lane == 0) sRedX[wave] = px;
        }
        __syncthreads();                                         // B5
        xq = sRedX[0] + sRedX[1] + sRedX[2];
    }
}

// ---------------------------------------------------------------------------
extern "C" void kernel_launch(void* const* d_in, const int* in_sizes, int n_in,
                              void* d_out, int out_size, void* d_ws, size_t ws_size,
                              hipStream_t stream)
{
    const float* features = (const float*)d_in[0];
    const float* adj      = (const float*)d_in[1];
    const float* smask    = (const float*)d_in[2];
    const float* fc1_w = (const float*)d_in[5];
    const float* fc1_b = (const float*)d_in[6];
    const float* gat_w = (const float*)d_in[7];
    const float* wr0   = (const float*)d_in[9];
    const float* wr1   = (const float*)d_in[10];
    const float* c_wih = (const float*)d_in[11];
    const float* c_whh = (const float*)d_in[12];
    const float* c_bih = (const float*)d_in[13];
    const float* c_bhh = (const float*)d_in[14];
    const float* p_wih = (const float*)d_in[15];
    const float* p_whh = (const float*)d_in[16];
    const float* p_bih = (const float*)d_in[17];
    const float* p_bhh = (const float*)d_in[18];
    const float* mw0 = (const float*)d_in[19];
    const float* mb0 = (const float*)d_in[20];
    const float* mw1 = (const float*)d_in[21];
    const float* mb1 = (const float*)d_in[22];
    const float* mw2 = (const float*)d_in[23];
    const float* mb2 = (const float*)d_in[24];
    float* out = (float*)d_out;

    char* wsb = (char*)d_ws;
    size_t off = 0;
    auto carve = [&](size_t bytes) -> char* {
        char* p = wsb + off;
        off = (off + bytes + 255) & ~(size_t)255;
        return p;
    };
    float* Hcat     = (float*)carve(2048ull * 576 * 4);
    float* PRE      = (float*)carve(2048ull * 1152 * 4);
    float* WpreT    = (float*)carve(2ull * 192 * 1152 * 4);
    uint32_t* W4    = (uint32_t*)carve(2ull * NW * 27648 * 4);
    uint32_t* Wr4   = (uint32_t*)carve(2ull * NW * 9216 * 4);
    float* biasPre  = (float*)carve(2ull * 1152 * 4);
    float* gbx      = (float*)carve(2ull * 384 * 4);
    uint32_t* Hb    = (uint32_t*)carve(8ull * NW * KD * 256 * 4);
    u64* MPs        = (u64*)carve(8ull * NW * 192 * 8);
    u64* Kd         = (u64*)carve(8ull * NW * 8);
    float* h1 = PRE;
    float* h2 = PRE + 2048 * 192;

    prepack_kernel<<<dim3((192 * 1152 + 255) / 256), 256, 0, stream>>>(
        wr0, wr1, c_wih, c_whh, c_bih, c_bhh, p_wih, p_whh, p_bih, p_bhh,
        WpreT, W4, Wr4, biasPre, gbx);

    gemm_kernel<<<dim3(256, 1), 192, 0, stream>>>(features, 768, fc1_w, fc1_b,
                                                  Hcat, 576, 768, 192, 1);
    for (int l = 0; l < 2; ++l) {
        gemm_kernel<<<dim3(256, 6), 192, 0, stream>>>(Hcat + l * 192, 576,
            WpreT + (size_t)l * 192 * 1152, biasPre + l * 1152, PRE, 1152, 192, 1152, 0);
        scan_kernel<<<dim3(32), 576, 0, stream>>>(Hcat + l * 192, Hcat + (l + 1) * 192,
            PRE, adj, smask,
            W4 + (size_t)l * NW * 27648,
            Wr4 + (size_t)l * NW * 9216,
            gbx + l * 384, gat_w + l * 384,
            Hb, MPs, Kd,
            out + 393216 + l * 65536, 1 + l * 1000);
    }
    gemm_kernel<<<dim3(256, 1), 192, 0, stream>>>(Hcat, 576, mw0, mb0, h1, 192, 576, 192, 1);
    gemm_kernel<<<dim3(256, 1), 192, 0, stream>>>(h1, 192, mw1, mb1, h2, 192, 192, 192, 1);
    gemm_kernel<<<dim3(256, 1), 192, 0, stream>>>(h2, 192, mw2, mb2, out, 192, 192, 192, 0);
}

// Round 8
// 2006.495 us; speedup vs baseline: 10.9181x; 1.7315x over previous
//
#include <hip/hip_runtime.h>
#include <stdint.h>

#define B_  8
#define N_  256
#define DH_ 192
#define L_  2
#define G3  576
#define G6  1152
#define NW  4      // WGs per batch per role
#define DS  48     // d-slice per WG
#define KD  24     // H-history dwords per WG (48 bf16)
#define GC  288    // g-cols per WG
#define STH 10001  // H1 channel stamp base
#define STP 20001  // PRE channel stamp base
#define STQ 25001  // xq channel stamp base

typedef unsigned long long u64;

__device__ __forceinline__ float bflo(uint32_t u) { return __uint_as_float(u << 16); }
__device__ __forceinline__ float bfhi(uint32_t u) { return __uint_as_float(u & 0xffff0000u); }
__device__ __forceinline__ uint32_t f2bf(float f) {
    uint32_t x = __float_as_uint(f);
    x += 0x7fffu + ((x >> 16) & 1u);          // RNE
    return x >> 16;
}
__device__ __forceinline__ float sigm(float x)  { return 1.f / (1.f + __expf(-x)); }
__device__ __forceinline__ float tanhf_(float x){ return 1.f - 2.f / (1.f + __expf(2.f * x)); }
__device__ __forceinline__ u64 packvs(float v, int st) {
    return ((u64)(uint32_t)st << 32) | __float_as_uint(v);
}
__device__ __forceinline__ u64 agload(const u64* p) {
    return __hip_atomic_load(p, __ATOMIC_RELAXED, __HIP_MEMORY_SCOPE_AGENT);
}
__device__ __forceinline__ void agstore(u64* p, u64 v) {
    __hip_atomic_store(p, v, __ATOMIC_RELAXED, __HIP_MEMORY_SCOPE_AGENT);
}

// ---------------------------------------------------------------------------
// Prepack per layer (r7 layouts + Wp4w worker slices for layer 2):
//   WpreT fp32 [192][1152] : rows [cwih | pwhh]  (PRE-l1 GEMM B-matrix)
//   W4  u32 [l][4 w][27648]: pos = p4*1152 + c2*4 + s; k-pair p = 4*p4+s;
//       c2 = 48*j + dd -> global col c = 192*j + 48*w + dd; over [cwhh|pwih]
//   Wr4 u32 [l][4 w][9216]: pos = kq*768 + d*4 + s; k = 48*w + 4*kq + s;
//       pack(bf(wr0[d][k]), bf(wr1[d][k]))
//   Wp4w u32 [4 w][27648]: same shape as W4, layer-2 [cwih|pwhh],
//       col r = 192*g + 48*w + d  (g = c2/48, d = c2%48)
//   biasPre fp32 [l][1152], gbx fp32 [l][384]
// ---------------------------------------------------------------------------
__global__ void prepack_kernel(
    const float* __restrict__ wr0, const float* __restrict__ wr1,
    const float* __restrict__ c_wih, const float* __restrict__ c_whh,
    const float* __restrict__ c_bih, const float* __restrict__ c_bhh,
    const float* __restrict__ p_wih, const float* __restrict__ p_whh,
    const float* __restrict__ p_bih, const float* __restrict__ p_bhh,
    float* __restrict__ WpreT, uint32_t* __restrict__ W4,
    uint32_t* __restrict__ Wr4, uint32_t* __restrict__ Wp4w,
    float* __restrict__ biasPre, float* __restrict__ gbx)
{
    int idx = blockIdx.x * blockDim.x + threadIdx.x;
    if (idx >= DH_ * G6) return;
    for (int l = 0; l < L_; ++l) {
        const float* cwih = c_wih + l * G3 * DH_;
        const float* cwhh = c_whh + l * G3 * DH_;
        const float* pwih = p_wih + l * G3 * DH_;
        const float* pwhh = p_whh + l * G3 * DH_;
        if (l == 0) {   // WpreT only layer 0 (layer-1 PRE is worker-computed)
            int k = idx / G6, r = idx - k * G6;
            float w = (r < G3) ? cwih[r * DH_ + k] : pwhh[(r - G3) * DH_ + k];
            WpreT[k * G6 + r] = w;
        }
        if (idx < NW * 27648) {   // W4
            int w = idx / 27648, pos = idx % 27648;
            int p4 = pos / 1152, rem = pos % 1152;
            int c2 = rem >> 2, s = rem & 3;
            int p = 4 * p4 + s;
            int j = c2 / DS, dd = c2 % DS;
            int c = 192 * j + DS * w + dd;
            float w0 = (c < G3) ? cwhh[c * DH_ + 2 * p]     : pwih[(c - G3) * DH_ + 2 * p];
            float w1 = (c < G3) ? cwhh[c * DH_ + 2 * p + 1] : pwih[(c - G3) * DH_ + 2 * p + 1];
            W4[l * NW * 27648 + idx] = f2bf(w0) | (f2bf(w1) << 16);
            if (l == 1) {   // Wp4w: same indexing, [cwih|pwhh] layer 2
                int r = 192 * j + DS * w + dd;
                float v0 = (r < G3) ? cwih[r * DH_ + 2 * p]     : pwhh[(r - G3) * DH_ + 2 * p];
                float v1 = (r < G3) ? cwih[r * DH_ + 2 * p + 1] : pwhh[(r - G3) * DH_ + 2 * p + 1];
                Wp4w[idx] = f2bf(v0) | (f2bf(v1) << 16);
            }
        }
        if (idx < NW * 9216) {   // Wr4
            int w = idx / 9216, pos = idx % 9216;
            int kq = pos / 768, rem = pos % 768;
            int d = rem >> 2, s = rem & 3;
            int k = DS * w + 4 * kq + s;
            Wr4[l * NW * 9216 + idx] =
                f2bf(wr0[l * DH_ * DH_ + d * DH_ + k]) |
                (f2bf(wr1[l * DH_ * DH_ + d * DH_ + k]) << 16);
        }
        if (idx < G6) {  // biasPre with r,z folds
            float base = (idx < G3) ? c_bih[l * G3 + idx] : p_bhh[l * G3 + idx - G3];
            float fold = 0.f;
            if (idx < 384)                    fold = c_bhh[l * G3 + idx];
            else if (idx >= G3 && idx < 960)  fold = p_bih[l * G3 + idx - G3];
            biasPre[l * G6 + idx] = base + fold;
        }
        if (idx < 384) {
            gbx[l * 384 + idx] = (idx < DH_) ? c_bhh[l * G3 + 384 + idx]
                                             : p_bih[l * G3 + 384 + (idx - DH_)];
        }
    }
}

// ---------------------------------------------------------------------------
// Generic small GEMM (parallel phases): C = relu?(A @ B + bias)
// ---------------------------------------------------------------------------
#define GR 8
__global__ __launch_bounds__(192) void gemm_kernel(
    const float* __restrict__ A, int lda, const float* __restrict__ Bm,
    const float* __restrict__ bias, float* __restrict__ C, int ldc,
    int K, int cols, int relu)
{
    __shared__ float sA[GR][64];
    const int c  = blockIdx.y * 192 + threadIdx.x;
    const int r0 = blockIdx.x * GR;
    float acc[GR] = {0.f, 0.f, 0.f, 0.f, 0.f, 0.f, 0.f, 0.f};
    for (int k0 = 0; k0 < K; k0 += 64) {
        for (int idx = threadIdx.x; idx < GR * 64; idx += 192) {
            int rr = idx >> 6, kk = idx & 63;
            sA[rr][kk] = A[(size_t)(r0 + rr) * lda + k0 + kk];
        }
        __syncthreads();
        #pragma unroll 8
        for (int kk = 0; kk < 64; ++kk) {
            float bv = Bm[(size_t)(k0 + kk) * cols + c];
            #pragma unroll
            for (int rr = 0; rr < GR; ++rr) acc[rr] += sA[rr][kk] * bv;
        }
        __syncthreads();
    }
    float bv = bias[c];
    #pragma unroll
    for (int rr = 0; rr < GR; ++rr) {
        float v = acc[rr] + bv;
        if (relu) v = fmaxf(v, 0.f);
        C[(size_t)(r0 + rr) * ldc + c] = v;
    }
}

// ---------------------------------------------------------------------------
// LDS layouts
// ---------------------------------------------------------------------------
struct ScanSm {
    uint4 Wlds4[24 * GC];            // 110,592 B
    uint4 Wr4s[12 * DH_];            //  36,864 B
    float sA0[N_], sA1[N_], sKsc[N_];
    float sAdjN[N_], sSmN[N_];
    float sXq[DH_], sPre[6 * DS], sXv[DS];
    float sM[DH_], su0[DS], su1[DS], sGc[GC], sHn[DS];
    float sRedS[4], sRedX[3], sSaved[4];
};
struct WorkSm {
    uint4 Wp4[24 * GC];              // 110,592 B
    float sX[DH_];
    float sPv[GC];
    float sRed[3];
};

// ---------------------------------------------------------------------------
// Scan body (r7 structure). ISL2=0: layer-1 (global staging, publishes H to Hc).
// ISL2=1: layer-2 (x/PRE/xq polled from stamped channels).
// ---------------------------------------------------------------------------
template<int ISL2>
__device__ void scan_body(
    ScanSm* S, int b, int w, int t,
    const float* __restrict__ xin, float* __restrict__ hout,
    const float* __restrict__ PREg, const float* __restrict__ adj,
    const float* __restrict__ smask,
    const uint32_t* __restrict__ W4l, const uint32_t* __restrict__ Wr4l,
    const float* __restrict__ gbxl, const float* __restrict__ gatwl,
    uint32_t* __restrict__ Hw, u64* __restrict__ MPsl, u64* __restrict__ Kdl,
    u64* __restrict__ HcW, const u64* __restrict__ HcR,
    const u64* __restrict__ PREcR, const u64* __restrict__ XQcR,
    float* __restrict__ AsB, int sbase)
{
    const int lane = t & 63, wave = t >> 6;
    const int dg0 = w * DS;
    const float* adjB = adj   + (size_t)b * N_ * N_;
    const float* smB  = smask + (size_t)b * N_ * N_;
    const int fi = b * NW;

    {   // LDS-resident weights
        uint32_t* wl = (uint32_t*)S->Wlds4;
        for (int q = t; q < 27648; q += 576) wl[q] = W4l[q];
        uint32_t* wr = (uint32_t*)S->Wr4s;
        for (int q = t; q < 9216; q += 576) wr[q] = Wr4l[q];
    }
    float wqv = (!ISL2 && t < DH_) ? gatwl[t] : 0.f;
    float wkv = 0.f, g2b = 0.f, g5b = 0.f;
    if (t < DS) { wkv = gatwl[DH_ + dg0 + t]; g2b = gbxl[dg0 + t]; g5b = gbxl[DH_ + dg0 + t]; }
    if (t < N_) S->sKsc[t] = 0.f;
    if (w == 0 && t < N_) AsB[t] = 0.f;

    // ---- prologue staging --------------------------------------------------
    if (!ISL2) {
        if (t < DS) {
            const float* pre = PREg + (size_t)(b * N_) * G6 + dg0 + t;
            S->sPre[t] = pre[0]; S->sPre[DS + t] = pre[192]; S->sPre[2 * DS + t] = pre[384];
            S->sPre[3 * DS + t] = pre[576]; S->sPre[4 * DS + t] = pre[768]; S->sPre[5 * DS + t] = pre[960];
            S->sXv[t] = xin[(size_t)(b * N_) * G3 + dg0 + t];
        }
        for (int q = t; q < 176; q += 576) {
            if (q < 64)       *(float4*)&S->sAdjN[4 * q] = *(const float4*)(adjB + N_ + 4 * q);
            else if (q < 128) { int q2 = q - 64;  *(float4*)&S->sSmN[4 * q2] = *(const float4*)(smB + N_ + 4 * q2); }
            else              { int q2 = q - 128; *(float4*)&S->sXq[4 * q2] = *(const float4*)(xin + (size_t)(b * N_ + 1) * G3 + 4 * q2); }
        }
    } else {
        for (int q = t; q < 321; q += 576) {
            if (q < 64)       *(float4*)&S->sAdjN[4 * q] = *(const float4*)(adjB + N_ + 4 * q);
            else if (q < 128) { int q2 = q - 64;  *(float4*)&S->sSmN[4 * q2] = *(const float4*)(smB + N_ + 4 * q2); }
            else if (q < 176) {
                int d = q - 128;
                const u64* p = HcR + ((size_t)(b * N_) * NW + w) * DS + d;
                u64 v; do { v = agload(p); } while ((uint32_t)(v >> 32) != (uint32_t)STH);
                S->sXv[d] = __uint_as_float((uint32_t)v);
            } else if (q < 320) {
                int qq = q - 176;
                const u64* p = PREcR + ((size_t)(b * N_) * NW + w) * 144 + qq;
                u64 v; do { v = agload(p); } while ((uint32_t)(v >> 32) != (uint32_t)STP);
                uint32_t pl = (uint32_t)v;
                S->sPre[2 * qq] = bflo(pl); S->sPre[2 * qq + 1] = bfhi(pl);
            } else {
                const u64* p = XQcR + b * N_ + 1;
                u64 v; do { v = agload(p); } while ((uint32_t)(v >> 32) != (uint32_t)(STQ + 1));
                S->sSaved[3] = __uint_as_float((uint32_t)v);
            }
        }
    }
    __syncthreads();
    // ---- step 0 gates (M = 0) ----------------------------------------------
    {
        float hn = 0.f;
        if (t < DS) {
            float xv = S->sXv[t];
            float r1 = sigm(S->sPre[t]), z1 = sigm(S->sPre[DS + t]);
            float n1 = tanhf_(S->sPre[2 * DS + t] + r1 * g2b);
            float Cv = (1.f - z1) * n1;
            float r2 = sigm(S->sPre[3 * DS + t]), z2 = sigm(S->sPre[4 * DS + t]);
            float n2 = tanhf_(g5b + r2 * S->sPre[5 * DS + t]);
            hn = Cv + (1.f - z2) * n2 + z2 * xv;
            S->sHn[t] = hn;
            hout[(size_t)(b * N_) * G3 + dg0 + t] = hn;
            if (!ISL2) HcW[((size_t)(b * N_) * NW + w) * DS + t] = packvs(hn, STH);
        }
        if (wave == 0) {
            float v = hn * wkv;
            #pragma unroll
            for (int o = 32; o; o >>= 1) v += __shfl_xor(v, o);
            if (lane == 0) agstore(&Kdl[fi + w], packvs(v, sbase));
        }
    }
    __syncthreads();
    if (t < KD) Hw[(size_t)t * N_] = f2bf(S->sHn[2 * t]) | (f2bf(S->sHn[2 * t + 1]) << 16);
    if (!ISL2) {
        float px = (t < DH_) ? S->sXq[t] * wqv : 0.f;
        #pragma unroll
        for (int o = 32; o; o >>= 1) px += __shfl_xor(px, o);
        if (t < DH_ && lane == 0) S->sRedX[wave] = px;
    }
    __syncthreads();
    float xq = ISL2 ? S->sSaved[3] : (S->sRedX[0] + S->sRedX[1] + S->sRedX[2]);

    // ---- main loop ---------------------------------------------------------
    for (int i = 1; i < N_; ++i) {
        const int row = b * N_ + i;
        const int stamp = sbase + i;
        // A: unnormalized scores j <= i-2
        {
            float e = 0.f;
            if (t == i - 1) { S->sSaved[0] = S->sAdjN[t]; S->sSaved[1] = S->sSmN[t]; }
            if (t < N_) {
                if (t < i - 1 && S->sAdjN[t] > 0.5f) e = __expf(xq + S->sKsc[t]);
                float b0 = e * S->sSmN[t];
                S->sA0[t] = b0; S->sA1[t] = e - b0;
            }
            float ps = e;
            #pragma unroll
            for (int o = 32; o; o >>= 1) ps += __shfl_xor(ps, o);
            if (t < N_ && lane == 0) S->sRedS[wave] = ps;
        }
        __syncthreads();                                         // B1
        // U (t<384) | staging + kdot poll (t>=384)
        if (t < 384) {
            const int ilim = i - 1;
            const int kd = t >> 4, jp = t & 15;
            const uint32_t* hp = Hw + (size_t)kd * N_;
            float u0l = 0.f, u0h = 0.f, u1l = 0.f, u1h = 0.f;
            int j = jp;
            while (j + 48 < ilim) {
                uint32_t h0 = hp[j], h1 = hp[j + 16], h2 = hp[j + 32], h3 = hp[j + 48];
                float b0, b1;
                b0 = S->sA0[j];      b1 = S->sA1[j];
                u0l = fmaf(b0, bflo(h0), u0l); u0h = fmaf(b0, bfhi(h0), u0h);
                u1l = fmaf(b1, bflo(h0), u1l); u1h = fmaf(b1, bfhi(h0), u1h);
                b0 = S->sA0[j + 16]; b1 = S->sA1[j + 16];
                u0l = fmaf(b0, bflo(h1), u0l); u0h = fmaf(b0, bfhi(h1), u0h);
                u1l = fmaf(b1, bflo(h1), u1l); u1h = fmaf(b1, bfhi(h1), u1h);
                b0 = S->sA0[j + 32]; b1 = S->sA1[j + 32];
                u0l = fmaf(b0, bflo(h2), u0l); u0h = fmaf(b0, bfhi(h2), u0h);
                u1l = fmaf(b1, bflo(h2), u1l); u1h = fmaf(b1, bfhi(h2), u1h);
                b0 = S->sA0[j + 48]; b1 = S->sA1[j + 48];
                u0l = fmaf(b0, bflo(h3), u0l); u0h = fmaf(b0, bfhi(h3), u0h);
                u1l = fmaf(b1, bflo(h3), u1l); u1h = fmaf(b1, bfhi(h3), u1h);
                j += 64;
            }
            for (; j < ilim; j += 16) {
                uint32_t hv = hp[j];
                float b0 = S->sA0[j], b1 = S->sA1[j];
                u0l = fmaf(b0, bflo(hv), u0l); u0h = fmaf(b0, bfhi(hv), u0h);
                u1l = fmaf(b1, bflo(hv), u1l); u1h = fmaf(b1, bfhi(hv), u1h);
            }
            #pragma unroll
            for (int o = 1; o <= 8; o <<= 1) {
                u0l += __shfl_xor(u0l, o); u0h += __shfl_xor(u0h, o);
                u1l += __shfl_xor(u1l, o); u1h += __shfl_xor(u1h, o);
            }
            if (jp == 0) {
                S->su0[2 * kd] = u0l; S->su0[2 * kd + 1] = u0h;
                S->su1[2 * kd] = u1l; S->su1[2 * kd + 1] = u1h;
            }
        } else {
            const int u = t - 384;
            const int inx = (i + 1 < N_) ? i + 1 : N_ - 1;
            if (!ISL2) {
                for (int q = u; q < 260; q += 192) {
                    if (q < 64)
                        *(float4*)&S->sAdjN[4 * q] = *(const float4*)(adjB + (size_t)inx * N_ + 4 * q);
                    else if (q < 128) { int q2 = q - 64;
                        *(float4*)&S->sSmN[4 * q2] = *(const float4*)(smB + (size_t)inx * N_ + 4 * q2); }
                    else if (q < 140) { int q2 = q - 128;
                        *(float4*)&S->sXv[4 * q2] = *(const float4*)(xin + (size_t)row * G3 + dg0 + 4 * q2); }
                    else if (q < 212) { int q2 = q - 140; int g = q2 / 12, o = q2 - 12 * g;
                        *(float4*)&S->sPre[g * DS + 4 * o] =
                            *(const float4*)(PREg + (size_t)row * G6 + g * DH_ + dg0 + 4 * o); }
                    else { int q2 = q - 212;
                        *(float4*)&S->sXq[4 * q2] = *(const float4*)(xin + (size_t)(b * N_ + inx) * G3 + 4 * q2); }
                }
            } else {
                for (int q = u; q < 321; q += 192) {
                    if (q < 64)
                        *(float4*)&S->sAdjN[4 * q] = *(const float4*)(adjB + (size_t)inx * N_ + 4 * q);
                    else if (q < 128) { int q2 = q - 64;
                        *(float4*)&S->sSmN[4 * q2] = *(const float4*)(smB + (size_t)inx * N_ + 4 * q2); }
                    else if (q < 176) {
                        int d = q - 128;
                        const u64* p = HcR + ((size_t)row * NW + w) * DS + d;
                        u64 v; do { v = agload(p); } while ((uint32_t)(v >> 32) != (uint32_t)(STH + i));
                        S->sXv[d] = __uint_as_float((uint32_t)v);
                    } else if (q < 320) {
                        int qq = q - 176;
                        const u64* p = PREcR + ((size_t)row * NW + w) * 144 + qq;
                        u64 v; do { v = agload(p); } while ((uint32_t)(v >> 32) != (uint32_t)(STP + i));
                        uint32_t pl = (uint32_t)v;
                        S->sPre[2 * qq] = bflo(pl); S->sPre[2 * qq + 1] = bfhi(pl);
                    } else {
                        const u64* p = XQcR + b * N_ + inx;
                        u64 v; do { v = agload(p); } while ((uint32_t)(v >> 32) != (uint32_t)(STQ + inx));
                        S->sSaved[3] = __uint_as_float((uint32_t)v);
                    }
                }
            }
            if (t == 575) {     // kdot poll, hidden under U
                const uint32_t ex = (uint32_t)(stamp - 1);
                u64 k0, k1, k2, k3;
                do {
                    k0 = agload(&Kdl[fi + 0]); k1 = agload(&Kdl[fi + 1]);
                    k2 = agload(&Kdl[fi + 2]); k3 = agload(&Kdl[fi + 3]);
                } while ((uint32_t)(k0 >> 32) != ex || (uint32_t)(k1 >> 32) != ex ||
                         (uint32_t)(k2 >> 32) != ex || (uint32_t)(k3 >> 32) != ex);
                float kdot = __uint_as_float((uint32_t)k0) + __uint_as_float((uint32_t)k1)
                           + __uint_as_float((uint32_t)k2) + __uint_as_float((uint32_t)k3);
                float adjI1 = S->sSaved[0], smI1 = S->sSaved[1];
                float e1 = (adjI1 > 0.5f) ? __expf(xq + kdot) : 0.f;
                float Ssum = S->sRedS[0] + S->sRedS[1] + S->sRedS[2] + S->sRedS[3] + e1;
                S->sKsc[i - 1] = kdot;
                float c0 = e1 * smI1;
                S->sA0[i - 1] = c0; S->sA1[i - 1] = e1 - c0;
                S->sSaved[2] = 1.f / Ssum;
            }
        }
        __syncthreads();                                         // B2
        // Mp with inline j=i-1 fixup + stamped exchange (t<192)
        if (t < DH_) {
            float mp = 0.f, h0a = 0.f, h1a = 0.f;
            #pragma unroll 4
            for (int kq = 0; kq < 12; ++kq) {
                uint4 wv = S->Wr4s[kq * DH_ + t];
                const int k0 = 4 * kq;
                float lo, hi;
                lo = bflo(wv.x); hi = bfhi(wv.x);
                mp = fmaf(S->su0[k0 + 0], lo, mp); mp = fmaf(S->su1[k0 + 0], hi, mp);
                h0a = fmaf(S->sHn[k0 + 0], lo, h0a); h1a = fmaf(S->sHn[k0 + 0], hi, h1a);
                lo = bflo(wv.y); hi = bfhi(wv.y);
                mp = fmaf(S->su0[k0 + 1], lo, mp); mp = fmaf(S->su1[k0 + 1], hi, mp);
                h0a = fmaf(S->sHn[k0 + 1], lo, h0a); h1a = fmaf(S->sHn[k0 + 1], hi, h1a);
                lo = bflo(wv.z); hi = bfhi(wv.z);
                mp = fmaf(S->su0[k0 + 2], lo, mp); mp = fmaf(S->su1[k0 + 2], hi, mp);
                h0a = fmaf(S->sHn[k0 + 2], lo, h0a); h1a = fmaf(S->sHn[k0 + 2], hi, h1a);
                lo = bflo(wv.w); hi = bfhi(wv.w);
                mp = fmaf(S->su0[k0 + 3], lo, mp); mp = fmaf(S->su1[k0 + 3], hi, mp);
                h0a = fmaf(S->sHn[k0 + 3], lo, h0a); h1a = fmaf(S->sHn[k0 + 3], hi, h1a);
            }
            float invS = S->sSaved[2];
            mp = (mp + S->sA0[i - 1] * h0a + S->sA1[i - 1] * h1a) * invS;
            agstore(&MPsl[(size_t)(fi + w) * DH_ + t], packvs(mp, stamp));
            const int w1 = (w + 1) & 3, w2 = (w + 2) & 3, w3 = (w + 3) & 3;
            u64* pA = &MPsl[(size_t)(fi + w1) * DH_ + t];
            u64* pB = &MPsl[(size_t)(fi + w2) * DH_ + t];
            u64* pC = &MPsl[(size_t)(fi + w3) * DH_ + t];
            const uint32_t ex = (uint32_t)stamp;
            u64 vA, vB, vC;
            do {
                vA = agload(pA); vB = agload(pB); vC = agload(pC);
            } while ((uint32_t)(vA >> 32) != ex || (uint32_t)(vB >> 32) != ex ||
                     (uint32_t)(vC >> 32) != ex);
            S->sM[t] = mp + __uint_as_float((uint32_t)vA)
                          + __uint_as_float((uint32_t)vB)
                          + __uint_as_float((uint32_t)vC);
        } else if (w == 0 && t < 448) {
            int j = t - 192;
            AsB[(size_t)i * N_ + j] = (S->sA0[j] + S->sA1[j]) * S->sSaved[2];
        }
        __syncthreads();                                         // B3
        // G: g-slice from b128 LDS weights
        {
            const int c = t >> 1, kh = t & 1;
            const uint4* wp = S->Wlds4 + (12 * kh) * GC + c;
            float g = 0.f;
            #pragma unroll 4
            for (int p4 = 0; p4 < 12; ++p4) {
                uint4 wv = wp[p4 * GC];
                const int m0 = 8 * (12 * kh + p4);
                g = fmaf(S->sM[m0 + 0], bflo(wv.x), g); g = fmaf(S->sM[m0 + 1], bfhi(wv.x), g);
                g = fmaf(S->sM[m0 + 2], bflo(wv.y), g); g = fmaf(S->sM[m0 + 3], bfhi(wv.y), g);
                g = fmaf(S->sM[m0 + 4], bflo(wv.z), g); g = fmaf(S->sM[m0 + 5], bfhi(wv.z), g);
                g = fmaf(S->sM[m0 + 6], bflo(wv.w), g); g = fmaf(S->sM[m0 + 7], bfhi(wv.w), g);
            }
            g += __shfl_xor(g, 1);
            if (kh == 0) S->sGc[c] = g;
        }
        __syncthreads();                                         // B4
        // gates + kdot/H publish + history + next-xq
        {
            float hn = 0.f;
            if (t < DS) {
                float Mv = S->sM[dg0 + t];
                float r1 = sigm(S->sPre[t] + S->sGc[t]);
                float z1 = sigm(S->sPre[DS + t] + S->sGc[DS + t]);
                float n1 = tanhf_(S->sPre[2 * DS + t] + r1 * (S->sGc[2 * DS + t] + g2b));
                float Cv = (1.f - z1) * n1 + z1 * Mv;
                float r2 = sigm(S->sGc[3 * DS + t] + S->sPre[3 * DS + t]);
                float z2 = sigm(S->sGc[4 * DS + t] + S->sPre[4 * DS + t]);
                float n2 = tanhf_(S->sGc[5 * DS + t] + g5b + r2 * S->sPre[5 * DS + t]);
                hn = Cv + (1.f - z2) * n2 + z2 * S->sXv[t];
                S->sHn[t] = hn;
                hout[(size_t)row * G3 + dg0 + t] = hn;
                if (!ISL2) HcW[((size_t)row * NW + w) * DS + t] = packvs(hn, STH + i);
            }
            if (wave == 0) {
                float v = hn * wkv;
                #pragma unroll
                for (int o = 32; o; o >>= 1) v += __shfl_xor(v, o);
                if (lane == 0) agstore(&Kdl[fi + w], packvs(v, stamp));
            }
            if (t < KD) Hw[(size_t)t * N_ + i] = f2bf(S->sHn[2 * t]) | (f2bf(S->sHn[2 * t + 1]) << 16);
            if (!ISL2) {
                float px = (t < DH_) ? S->sXq[t] * wqv : 0.f;
                #pragma unroll
                for (int o = 32; o; o >>= 1) px += __shfl_xor(px, o);
                if (t < DH_ && lane == 0) S->sRedX[wave] = px;
            }
        }
        __syncthreads();                                         // B5
        xq = ISL2 ? S->sSaved[3] : (S->sRedX[0] + S->sRedX[1] + S->sRedX[2]);
    }
}

// ---------------------------------------------------------------------------
// PRE worker: poll H1_i, compute layer-2 PRE_i col-slice (bf16 weights,
// LDS-resident), publish stamped. w==0 also publishes xq = H1_i . wq2.
// ---------------------------------------------------------------------------
__device__ void worker_body(WorkSm* Wm, int b, int w, int t,
    const uint32_t* __restrict__ Wp4g, const float* __restrict__ bias2,
    const float* __restrict__ wq2,
    const u64* __restrict__ HcR, u64* __restrict__ PREcW, u64* __restrict__ XQcW)
{
    const int lane = t & 63, wave = t >> 6;
    { uint32_t* wl = (uint32_t*)Wm->Wp4; for (int q = t; q < 27648; q += 576) wl[q] = Wp4g[q]; }
    const int c = t >> 1, kh = t & 1;
    float bv = 0.f;
    if (kh == 0) bv = bias2[192 * (c / DS) + w * DS + (c % DS)];
    float wqt = (t < DH_) ? wq2[t] : 0.f;
    for (int i = 0; i < N_; ++i) {
        if (t < DH_) {
            const u64* p = HcR + ((size_t)(b * N_ + i) * NW + (t / DS)) * DS + (t % DS);
            u64 v; do { v = agload(p); } while ((uint32_t)(v >> 32) != (uint32_t)(STH + i));
            Wm->sX[t] = __uint_as_float((uint32_t)v);
        }
        __syncthreads();
        {
            const uint4* wp = Wm->Wp4 + (12 * kh) * GC + c;
            float g = 0.f;
            #pragma unroll 4
            for (int p4 = 0; p4 < 12; ++p4) {
                uint4 wv = wp[p4 * GC];
                const int m0 = 8 * (12 * kh + p4);
                g = fmaf(Wm->sX[m0 + 0], bflo(wv.x), g); g = fmaf(Wm->sX[m0 + 1], bfhi(wv.x), g);
                g = fmaf(Wm->sX[m0 + 2], bflo(wv.y), g); g = fmaf(Wm->sX[m0 + 3], bfhi(wv.y), g);
                g = fmaf(Wm->sX[m0 + 4], bflo(wv.z), g); g = fmaf(Wm->sX[m0 + 5], bfhi(wv.z), g);
                g = fmaf(Wm->sX[m0 + 6], bflo(wv.w), g); g = fmaf(Wm->sX[m0 + 7], bfhi(wv.w), g);
            }
            g += __shfl_xor(g, 1);
            if (kh == 0) Wm->sPv[c] = g + bv;
        }
        if (w == 0) {
            float px = (t < DH_) ? Wm->sX[t] * wqt : 0.f;
            #pragma unroll
            for (int o = 32; o; o >>= 1) px += __shfl_xor(px, o);
            if (t < DH_ && lane == 0) Wm->sRed[wave] = px;
        }
        __syncthreads();
        if (t < 144) {
            u64 v = ((u64)(uint32_t)(STP + i) << 32)
                  | f2bf(Wm->sPv[2 * t]) | (f2bf(Wm->sPv[2 * t + 1]) << 16);
            agstore(&PREcW[((size_t)(b * N_ + i) * NW + w) * 144 + t], v);
        }
        if (w == 0 && t == 0)
            agstore(&XQcW[b * N_ + i],
                    packvs(Wm->sRed[0] + Wm->sRed[1] + Wm->sRed[2], STQ + i));
        __syncthreads();
    }
}

// ---------------------------------------------------------------------------
__global__ __launch_bounds__(576, 1) void pipeline_kernel(
    float* __restrict__ Hcat, const float* __restrict__ PREg,
    const float* __restrict__ adj, const float* __restrict__ smask,
    const uint32_t* __restrict__ W4, const uint32_t* __restrict__ Wr4,
    const uint32_t* __restrict__ Wp4w,
    const float* __restrict__ biasPre, const float* __restrict__ gbx,
    const float* __restrict__ gatw,
    uint32_t* __restrict__ Hb, u64* __restrict__ MPs, u64* __restrict__ Kd,
    u64* __restrict__ Hc, u64* __restrict__ PREc, u64* __restrict__ XQc,
    float* __restrict__ As)
{
    __shared__ __align__(16) char smem[sizeof(ScanSm)];
    const int blk = blockIdx.x, t = threadIdx.x;
    const int b = blk & 7, r12 = blk >> 3;
    const int role = r12 >> 2, w = r12 & 3;
    if (role == 0) {
        scan_body<0>((ScanSm*)smem, b, w, t,
            Hcat, Hcat + 192, PREg, adj, smask,
            W4, Wr4, gbx, gatw,
            Hb + (size_t)(b * NW + w) * KD * N_, MPs, Kd,
            Hc, nullptr, nullptr, nullptr,
            As + (size_t)b * (L_ * N_ * N_), 1);
    } else if (role == 2) {
        scan_body<1>((ScanSm*)smem, b, w, t,
            nullptr, Hcat + 384, nullptr, adj, smask,
            W4 + NW * 27648, Wr4 + NW * 9216, gbx + 384, gatw + 384,
            Hb + (size_t)(32 + b * NW + w) * KD * N_,
            MPs + (size_t)8 * NW * DH_, Kd + 8 * NW,
            nullptr, Hc, PREc, XQc,
            As + (size_t)b * (L_ * N_ * N_) + N_ * N_, 30001);
    } else {
        worker_body((WorkSm*)smem, b, w, t,
            Wp4w + (size_t)w * 27648, biasPre + G6, gatw + 384,
            Hc, PREc, XQc);
    }
}

// ---------------------------------------------------------------------------
extern "C" void kernel_launch(void* const* d_in, const int* in_sizes, int n_in,
                              void* d_out, int out_size, void* d_ws, size_t ws_size,
                              hipStream_t stream)
{
    const float* features = (const float*)d_in[0];
    const float* adj      = (const float*)d_in[1];
    const float* smask    = (const float*)d_in[2];
    const float* fc1_w = (const float*)d_in[5];
    const float* fc1_b = (const float*)d_in[6];
    const float* gat_w = (const float*)d_in[7];
    const float* wr0   = (const float*)d_in[9];
    const float* wr1   = (const float*)d_in[10];
    const float* c_wih = (const float*)d_in[11];
    const float* c_whh = (const float*)d_in[12];
    const float* c_bih = (const float*)d_in[13];
    const float* c_bhh = (const float*)d_in[14];
    const float* p_wih = (const float*)d_in[15];
    const float* p_whh = (const float*)d_in[16];
    const float* p_bih = (const float*)d_in[17];
    const float* p_bhh = (const float*)d_in[18];
    const float* mw0 = (const float*)d_in[19];
    const float* mb0 = (const float*)d_in[20];
    const float* mw1 = (const float*)d_in[21];
    const float* mb1 = (const float*)d_in[22];
    const float* mw2 = (const float*)d_in[23];
    const float* mb2 = (const float*)d_in[24];
    float* out = (float*)d_out;

    char* wsb = (char*)d_ws;
    size_t off = 0;
    auto carve = [&](size_t bytes) -> char* {
        char* p = wsb + off;
        off = (off + bytes + 255) & ~(size_t)255;
        return p;
    };
    float* Hcat     = (float*)carve(2048ull * 576 * 4);
    float* PREg     = (float*)carve(2048ull * 1152 * 4);
    float* WpreT    = (float*)carve(192ull * 1152 * 4);
    uint32_t* W4    = (uint32_t*)carve(2ull * NW * 27648 * 4);
    uint32_t* Wr4   = (uint32_t*)carve(2ull * NW * 9216 * 4);
    uint32_t* Wp4w  = (uint32_t*)carve((size_t)NW * 27648 * 4);
    float* biasPre  = (float*)carve(2ull * 1152 * 4);
    float* gbx      = (float*)carve(2ull * 384 * 4);
    uint32_t* Hb    = (uint32_t*)carve(64ull * KD * 256 * 4);
    u64* MPs        = (u64*)carve(2ull * 8 * NW * DH_ * 8);
    u64* Kd         = (u64*)carve(2ull * 8 * NW * 8);
    u64* Hc         = (u64*)carve(8ull * 256 * NW * DS * 8);    // 3.1 MB
    u64* PREc       = (u64*)carve(8ull * 256 * NW * 144 * 8);   // 9.4 MB
    u64* XQc        = (u64*)carve(8ull * 256 * 8);
    float* h1 = PREg;
    float* h2 = PREg + 2048 * 192;

    prepack_kernel<<<dim3((192 * 1152 + 255) / 256), 256, 0, stream>>>(
        wr0, wr1, c_wih, c_whh, c_bih, c_bhh, p_wih, p_whh, p_bih, p_bhh,
        WpreT, W4, Wr4, Wp4w, biasPre, gbx);

    gemm_kernel<<<dim3(256, 1), 192, 0, stream>>>(features, 768, fc1_w, fc1_b,
                                                  Hcat, 576, 768, 192, 1);
    // PRE for layer 1 only (layer-2 PRE is produced by workers in-pipeline)
    gemm_kernel<<<dim3(256, 6), 192, 0, stream>>>(Hcat, 576,
        WpreT, biasPre, PREg, 1152, 192, 1152, 0);

    pipeline_kernel<<<dim3(96), 576, 0, stream>>>(
        Hcat, PREg, adj, smask, W4, Wr4, Wp4w, biasPre, gbx, gat_w,
        Hb, MPs, Kd, Hc, PREc, XQc, out + 393216);

    gemm_kernel<<<dim3(256, 1), 192, 0, stream>>>(Hcat, 576, mw0, mb0, h1, 192, 576, 192, 1);
    gemm_kernel<<<dim3(256, 1), 192, 0, stream>>>(h1, 192, mw1, mb1, h2, 192, 192, 192, 1);
    gemm_kernel<<<dim3(256, 1), 192, 0, stream>>>(h2, 192, mw2, mb2, out, 192, 192, 192, 0);
}

// Round 9
// 1931.692 us; speedup vs baseline: 11.3409x; 1.0387x over previous
//
#include <hip/hip_runtime.h>
#include <stdint.h>

#define B_  8
#define N_  256
#define DH_ 192
#define L_  2
#define G3  576
#define G6  1152
#define NW  4      // WGs per batch per role
#define DS  48     // d-slice per WG
#define KD  24     // H-history dwords per WG (48 bf16)
#define GC  288    // g-cols per WG
#define STH 10001  // H1 channel stamp base
#define STP 20001  // PRE channel stamp base
#define STQ 25001  // xq channel stamp base
#define SPK 50000  // prepack done
#define SF1 50001  // fc1 done
#define SF2 50002  // PRE done
#define SDN 60001  // scan done

typedef unsigned long long u64;

__device__ __forceinline__ float bflo(uint32_t u) { return __uint_as_float(u << 16); }
__device__ __forceinline__ float bfhi(uint32_t u) { return __uint_as_float(u & 0xffff0000u); }
__device__ __forceinline__ uint32_t f2bf(float f) {
    uint32_t x = __float_as_uint(f);
    x += 0x7fffu + ((x >> 16) & 1u);          // RNE
    return x >> 16;
}
__device__ __forceinline__ float sigm(float x)  { return 1.f / (1.f + __expf(-x)); }
__device__ __forceinline__ float tanhf_(float x){ return 1.f - 2.f / (1.f + __expf(2.f * x)); }
__device__ __forceinline__ u64 packvs(float v, int st) {
    return ((u64)(uint32_t)st << 32) | __float_as_uint(v);
}
__device__ __forceinline__ u64 agload(const u64* p) {
    return __hip_atomic_load(p, __ATOMIC_RELAXED, __HIP_MEMORY_SCOPE_AGENT);
}
__device__ __forceinline__ void agstore(u64* p, u64 v) {
    __hip_atomic_store(p, v, __ATOMIC_RELAXED, __HIP_MEMORY_SCOPE_AGENT);
}

// ---------------------------------------------------------------------------
// LDS layouts (union in one 154KB block; ScanSm is the largest)
// ---------------------------------------------------------------------------
struct ScanSm {
    uint4 Wlds4[24 * GC];            // 110,592 B
    uint4 Wr4s[12 * DH_];            //  36,864 B
    float sA0[N_], sA1[N_], sKsc[N_];
    float sAdjN[N_], sSmN[N_];
    float sXq[DH_], sPre[6 * DS], sXv[DS];
    float sM[DH_], su0[DS], su1[DS], sGc[GC], sHn[DS];
    float sRedS[4], sRedX[3], sSaved[4];
};
struct WorkSm {
    uint4 Wp4[24 * GC];
    float sX[DH_];
    float sPv[GC];
    float sRed[3];
};
struct PrologSm {
    float sA[8][768];                // 24,576 B (fc1 A-stage; PRE uses [8][192])
    float sRed[3][8][192];           // 18,432 B
};
struct MlpSm {
    float sH[8][576];                // 18,432 B
    float sRed[3][8][192];
    float sT[8][192];                // h1 buffer
};

// ---------------------------------------------------------------------------
// Prepack slice (one idx of 221184): same layouts as round 8.
// ---------------------------------------------------------------------------
__device__ void prepack_slice(int idx,
    const float* __restrict__ wr0, const float* __restrict__ wr1,
    const float* __restrict__ c_wih, const float* __restrict__ c_whh,
    const float* __restrict__ c_bih, const float* __restrict__ c_bhh,
    const float* __restrict__ p_wih, const float* __restrict__ p_whh,
    const float* __restrict__ p_bih, const float* __restrict__ p_bhh,
    float* __restrict__ WpreT, uint32_t* __restrict__ W4,
    uint32_t* __restrict__ Wr4, uint32_t* __restrict__ Wp4w,
    float* __restrict__ biasPre, float* __restrict__ gbx)
{
    for (int l = 0; l < L_; ++l) {
        const float* cwih = c_wih + l * G3 * DH_;
        const float* cwhh = c_whh + l * G3 * DH_;
        const float* pwih = p_wih + l * G3 * DH_;
        const float* pwhh = p_whh + l * G3 * DH_;
        if (l == 0) {
            int k = idx / G6, r = idx - k * G6;
            float w = (r < G3) ? cwih[r * DH_ + k] : pwhh[(r - G3) * DH_ + k];
            WpreT[k * G6 + r] = w;
        }
        if (idx < NW * 27648) {
            int w = idx / 27648, pos = idx % 27648;
            int p4 = pos / 1152, rem = pos % 1152;
            int c2 = rem >> 2, s = rem & 3;
            int p = 4 * p4 + s;
            int j = c2 / DS, dd = c2 % DS;
            int c = 192 * j + DS * w + dd;
            float w0 = (c < G3) ? cwhh[c * DH_ + 2 * p]     : pwih[(c - G3) * DH_ + 2 * p];
            float w1 = (c < G3) ? cwhh[c * DH_ + 2 * p + 1] : pwih[(c - G3) * DH_ + 2 * p + 1];
            W4[l * NW * 27648 + idx] = f2bf(w0) | (f2bf(w1) << 16);
            if (l == 1) {
                int r = c;
                float v0 = (r < G3) ? cwih[r * DH_ + 2 * p]     : pwhh[(r - G3) * DH_ + 2 * p];
                float v1 = (r < G3) ? cwih[r * DH_ + 2 * p + 1] : pwhh[(r - G3) * DH_ + 2 * p + 1];
                Wp4w[idx] = f2bf(v0) | (f2bf(v1) << 16);
            }
        }
        if (idx < NW * 9216) {
            int w = idx / 9216, pos = idx % 9216;
            int kq = pos / 768, rem = pos % 768;
            int d = rem >> 2, s = rem & 3;
            int k = DS * w + 4 * kq + s;
            Wr4[l * NW * 9216 + idx] =
                f2bf(wr0[l * DH_ * DH_ + d * DH_ + k]) |
                (f2bf(wr1[l * DH_ * DH_ + d * DH_ + k]) << 16);
        }
        if (idx < G6) {
            float base = (idx < G3) ? c_bih[l * G3 + idx] : p_bhh[l * G3 + idx - G3];
            float fold = 0.f;
            if (idx < 384)                    fold = c_bhh[l * G3 + idx];
            else if (idx >= G3 && idx < 960)  fold = p_bih[l * G3 + idx - G3];
            biasPre[l * G6 + idx] = base + fold;
        }
        if (idx < 384) {
            gbx[l * 384 + idx] = (idx < DH_) ? c_bhh[l * G3 + 384 + idx]
                                             : p_bih[l * G3 + 384 + (idx - DH_)];
        }
    }
}

// ---------------------------------------------------------------------------
// Global sync among the 96 co-resident WGs via stamped flags.
// ---------------------------------------------------------------------------
__device__ void flag_sync(u64* flags, int wgid, int t, int stamp)
{
    __threadfence();                                   // release: L2 writeback
    __syncthreads();
    if (t == 0) agstore(&flags[wgid], packvs(0.f, stamp));
    if (t < 96) {
        while ((uint32_t)(agload(&flags[t]) >> 32) != (uint32_t)stamp) {}
    }
    __syncthreads();
    __threadfence();                                   // acquire: invalidate
    __syncthreads();
}

// ---------------------------------------------------------------------------
// Prologue: fc1 (H0 = relu(features@fc1_w+b)) then PRE-l1 = H0@WpreT+biasPre.
// All 96 WGs participate; tiles of 8 rows, stride 96.
// ---------------------------------------------------------------------------
__device__ void prologue(char* smem, int wgid, int t,
    const float* __restrict__ features, const float* __restrict__ fc1_w,
    const float* __restrict__ fc1_b, const float* __restrict__ WpreT,
    const float* __restrict__ biasPre,
    float* __restrict__ Hcat, float* __restrict__ PREg, u64* __restrict__ Fp)
{
    PrologSm* P = (PrologSm*)smem;
    const int c = t % 192, kg = t / 192;
    // ---- fc1 ----
    for (int tt = wgid; tt < 256; tt += 96) {
        const int r0 = tt * 8;
        for (int q = t; q < 1536; q += 576) {
            int r = q / 192, c4 = q % 192;
            *(float4*)&P->sA[r][4 * c4] = *(const float4*)(features + (size_t)(r0 + r) * 768 + 4 * c4);
        }
        __syncthreads();
        {
            const float* bp = fc1_w + (size_t)(kg * 256) * 192 + c;
            float acc[8] = {0.f, 0.f, 0.f, 0.f, 0.f, 0.f, 0.f, 0.f};
            #pragma unroll 8
            for (int kk = 0; kk < 256; ++kk) {
                float bv = bp[(size_t)kk * 192];
                #pragma unroll
                for (int rr = 0; rr < 8; ++rr) acc[rr] += P->sA[rr][kg * 256 + kk] * bv;
            }
            #pragma unroll
            for (int rr = 0; rr < 8; ++rr) P->sRed[kg][rr][c] = acc[rr];
        }
        __syncthreads();
        if (t < 192) {
            float bv = fc1_b[t];
            #pragma unroll
            for (int rr = 0; rr < 8; ++rr) {
                float v = P->sRed[0][rr][t] + P->sRed[1][rr][t] + P->sRed[2][rr][t] + bv;
                Hcat[(size_t)(r0 + rr) * G3 + t] = fmaxf(v, 0.f);
            }
        }
        __syncthreads();
    }
    flag_sync(Fp + 96, wgid, t, SF1);
    // ---- PRE-l1 ----
    {
        const float bpa = biasPre[t], bpb = biasPre[576 + t];
        for (int tt = wgid; tt < 256; tt += 96) {
            const int r0 = tt * 8;
            for (int q = t; q < 384; q += 576) {
                int r = q / 48, c4 = q % 48;
                *(float4*)&P->sA[r][4 * c4] = *(const float4*)(Hcat + (size_t)(r0 + r) * G3 + 4 * c4);
            }
            __syncthreads();
            {
                const float* b0 = WpreT + t;
                float a0[8] = {0.f,0.f,0.f,0.f,0.f,0.f,0.f,0.f};
                float a1[8] = {0.f,0.f,0.f,0.f,0.f,0.f,0.f,0.f};
                #pragma unroll 4
                for (int k = 0; k < 192; ++k) {
                    float bva = b0[(size_t)k * G6];
                    float bvb = b0[(size_t)k * G6 + 576];
                    #pragma unroll
                    for (int rr = 0; rr < 8; ++rr) {
                        float av = P->sA[rr][k];
                        a0[rr] += av * bva; a1[rr] += av * bvb;
                    }
                }
                #pragma unroll
                for (int rr = 0; rr < 8; ++rr) {
                    PREg[(size_t)(r0 + rr) * G6 + t]       = a0[rr] + bpa;
                    PREg[(size_t)(r0 + rr) * G6 + 576 + t] = a1[rr] + bpb;
                }
            }
            __syncthreads();
        }
    }
    flag_sync(Fp + 192, wgid, t, SF2);
}

// ---------------------------------------------------------------------------
// Epilogue: 3-layer MLP head on concat(H0|H1|H2). Polls 64 scan-done flags.
// ---------------------------------------------------------------------------
__device__ void mlp_tail(char* smem, int wgid, int t,
    const float* __restrict__ Hcat,
    const float* __restrict__ mw0, const float* __restrict__ mb0,
    const float* __restrict__ mw1, const float* __restrict__ mb1,
    const float* __restrict__ mw2, const float* __restrict__ mb2,
    float* __restrict__ out, u64* __restrict__ Fd)
{
    if (t < 64) {
        while ((uint32_t)(agload(&Fd[t]) >> 32) != (uint32_t)SDN) {}
    }
    __syncthreads();
    __threadfence();
    __syncthreads();
    MlpSm* M = (MlpSm*)smem;
    const int c = t % 192, kg = t / 192;
    for (int tt = wgid; tt < 256; tt += 96) {
        const int r0 = tt * 8;
        for (int q = t; q < 1152; q += 576) {
            int r = q / 144, c4 = q % 144;
            *(float4*)&M->sH[r][4 * c4] = *(const float4*)(Hcat + (size_t)(r0 + r) * G3 + 4 * c4);
        }
        __syncthreads();
        // h1 = relu(H @ mw0 + mb0), K=576 split 3x192
        {
            const float* bp = mw0 + (size_t)(kg * 192) * 192 + c;
            float acc[8] = {0.f,0.f,0.f,0.f,0.f,0.f,0.f,0.f};
            #pragma unroll 8
            for (int kk = 0; kk < 192; ++kk) {
                float bv = bp[(size_t)kk * 192];
                #pragma unroll
                for (int rr = 0; rr < 8; ++rr) acc[rr] += M->sH[rr][kg * 192 + kk] * bv;
            }
            #pragma unroll
            for (int rr = 0; rr < 8; ++rr) M->sRed[kg][rr][c] = acc[rr];
        }
        __syncthreads();
        if (t < 192) {
            float bv = mb0[t];
            #pragma unroll
            for (int rr = 0; rr < 8; ++rr)
                M->sT[rr][t] = fmaxf(M->sRed[0][rr][t] + M->sRed[1][rr][t] + M->sRed[2][rr][t] + bv, 0.f);
        }
        __syncthreads();
        // h2 = relu(h1 @ mw1 + mb1), K=192 split 3x64
        {
            const float* bp = mw1 + (size_t)(kg * 64) * 192 + c;
            float acc[8] = {0.f,0.f,0.f,0.f,0.f,0.f,0.f,0.f};
            #pragma unroll 8
            for (int kk = 0; kk < 64; ++kk) {
                float bv = bp[(size_t)kk * 192];
                #pragma unroll
                for (int rr = 0; rr < 8; ++rr) acc[rr] += M->sT[rr][kg * 64 + kk] * bv;
            }
            #pragma unroll
            for (int rr = 0; rr < 8; ++rr) M->sRed[kg][rr][c] = acc[rr];
        }
        __syncthreads();
        if (t < 192) {
            float bv = mb1[t];
            #pragma unroll
            for (int rr = 0; rr < 8; ++rr)
                M->sH[rr][t] = fmaxf(M->sRed[0][rr][t] + M->sRed[1][rr][t] + M->sRed[2][rr][t] + bv, 0.f);
        }
        __syncthreads();
        // logits = h2 @ mw2 + mb2
        {
            const float* bp = mw2 + (size_t)(kg * 64) * 192 + c;
            float acc[8] = {0.f,0.f,0.f,0.f,0.f,0.f,0.f,0.f};
            #pragma unroll 8
            for (int kk = 0; kk < 64; ++kk) {
                float bv = bp[(size_t)kk * 192];
                #pragma unroll
                for (int rr = 0; rr < 8; ++rr) acc[rr] += M->sH[rr][kg * 64 + kk] * bv;
            }
            #pragma unroll
            for (int rr = 0; rr < 8; ++rr) M->sRed[kg][rr][c] = acc[rr];
        }
        __syncthreads();
        if (t < 192) {
            float bv = mb2[t];
            #pragma unroll
            for (int rr = 0; rr < 8; ++rr)
                out[(size_t)(r0 + rr) * 192 + t] =
                    M->sRed[0][rr][t] + M->sRed[1][rr][t] + M->sRed[2][rr][t] + bv;
        }
        __syncthreads();
    }
}

// ---------------------------------------------------------------------------
// Scan body (unchanged r8 structure). ISL2=0: layer-1; ISL2=1: layer-2.
// ---------------------------------------------------------------------------
template<int ISL2>
__device__ void scan_body(
    ScanSm* S, int b, int w, int t,
    const float* __restrict__ xin, float* __restrict__ hout,
    const float* __restrict__ PREg, const float* __restrict__ adj,
    const float* __restrict__ smask,
    const uint32_t* __restrict__ W4l, const uint32_t* __restrict__ Wr4l,
    const float* __restrict__ gbxl, const float* __restrict__ gatwl,
    uint32_t* __restrict__ Hw, u64* __restrict__ MPsl, u64* __restrict__ Kdl,
    u64* __restrict__ HcW, const u64* __restrict__ HcR,
    const u64* __restrict__ PREcR, const u64* __restrict__ XQcR,
    float* __restrict__ AsB, int sbase)
{
    const int lane = t & 63, wave = t >> 6;
    const int dg0 = w * DS;
    const float* adjB = adj   + (size_t)b * N_ * N_;
    const float* smB  = smask + (size_t)b * N_ * N_;
    const int fi = b * NW;

    {
        uint32_t* wl = (uint32_t*)S->Wlds4;
        for (int q = t; q < 27648; q += 576) wl[q] = W4l[q];
        uint32_t* wr = (uint32_t*)S->Wr4s;
        for (int q = t; q < 9216; q += 576) wr[q] = Wr4l[q];
    }
    float wqv = (!ISL2 && t < DH_) ? gatwl[t] : 0.f;
    float wkv = 0.f, g2b = 0.f, g5b = 0.f;
    if (t < DS) { wkv = gatwl[DH_ + dg0 + t]; g2b = gbxl[dg0 + t]; g5b = gbxl[DH_ + dg0 + t]; }
    if (t < N_) S->sKsc[t] = 0.f;
    if (w == 0 && t < N_) AsB[t] = 0.f;

    if (!ISL2) {
        if (t < DS) {
            const float* pre = PREg + (size_t)(b * N_) * G6 + dg0 + t;
            S->sPre[t] = pre[0]; S->sPre[DS + t] = pre[192]; S->sPre[2 * DS + t] = pre[384];
            S->sPre[3 * DS + t] = pre[576]; S->sPre[4 * DS + t] = pre[768]; S->sPre[5 * DS + t] = pre[960];
            S->sXv[t] = xin[(size_t)(b * N_) * G3 + dg0 + t];
        }
        for (int q = t; q < 176; q += 576) {
            if (q < 64)       *(float4*)&S->sAdjN[4 * q] = *(const float4*)(adjB + N_ + 4 * q);
            else if (q < 128) { int q2 = q - 64;  *(float4*)&S->sSmN[4 * q2] = *(const float4*)(smB + N_ + 4 * q2); }
            else              { int q2 = q - 128; *(float4*)&S->sXq[4 * q2] = *(const float4*)(xin + (size_t)(b * N_ + 1) * G3 + 4 * q2); }
        }
    } else {
        for (int q = t; q < 321; q += 576) {
            if (q < 64)       *(float4*)&S->sAdjN[4 * q] = *(const float4*)(adjB + N_ + 4 * q);
            else if (q < 128) { int q2 = q - 64;  *(float4*)&S->sSmN[4 * q2] = *(const float4*)(smB + N_ + 4 * q2); }
            else if (q < 176) {
                int d = q - 128;
                const u64* p = HcR + ((size_t)(b * N_) * NW + w) * DS + d;
                u64 v; do { v = agload(p); } while ((uint32_t)(v >> 32) != (uint32_t)STH);
                S->sXv[d] = __uint_as_float((uint32_t)v);
            } else if (q < 320) {
                int qq = q - 176;
                const u64* p = PREcR + ((size_t)(b * N_) * NW + w) * 144 + qq;
                u64 v; do { v = agload(p); } while ((uint32_t)(v >> 32) != (uint32_t)STP);
                uint32_t pl = (uint32_t)v;
                S->sPre[2 * qq] = bflo(pl); S->sPre[2 * qq + 1] = bfhi(pl);
            } else {
                const u64* p = XQcR + b * N_ + 1;
                u64 v; do { v = agload(p); } while ((uint32_t)(v >> 32) != (uint32_t)(STQ + 1));
                S->sSaved[3] = __uint_as_float((uint32_t)v);
            }
        }
    }
    __syncthreads();
    {
        float hn = 0.f;
        if (t < DS) {
            float xv = S->sXv[t];
            float r1 = sigm(S->sPre[t]), z1 = sigm(S->sPre[DS + t]);
            float n1 = tanhf_(S->sPre[2 * DS + t] + r1 * g2b);
            float Cv = (1.f - z1) * n1;
            float r2 = sigm(S->sPre[3 * DS + t]), z2 = sigm(S->sPre[4 * DS + t]);
            float n2 = tanhf_(g5b + r2 * S->sPre[5 * DS + t]);
            hn = Cv + (1.f - z2) * n2 + z2 * xv;
            S->sHn[t] = hn;
            hout[(size_t)(b * N_) * G3 + dg0 + t] = hn;
            if (!ISL2) HcW[((size_t)(b * N_) * NW + w) * DS + t] = packvs(hn, STH);
        }
        if (wave == 0) {
            float v = hn * wkv;
            #pragma unroll
            for (int o = 32; o; o >>= 1) v += __shfl_xor(v, o);
            if (lane == 0) agstore(&Kdl[fi + w], packvs(v, sbase));
        }
    }
    __syncthreads();
    if (t < KD) Hw[(size_t)t * N_] = f2bf(S->sHn[2 * t]) | (f2bf(S->sHn[2 * t + 1]) << 16);
    if (!ISL2) {
        float px = (t < DH_) ? S->sXq[t] * wqv : 0.f;
        #pragma unroll
        for (int o = 32; o; o >>= 1) px += __shfl_xor(px, o);
        if (t < DH_ && lane == 0) S->sRedX[wave] = px;
    }
    __syncthreads();
    float xq = ISL2 ? S->sSaved[3] : (S->sRedX[0] + S->sRedX[1] + S->sRedX[2]);

    for (int i = 1; i < N_; ++i) {
        const int row = b * N_ + i;
        const int stamp = sbase + i;
        {
            float e = 0.f;
            if (t == i - 1) { S->sSaved[0] = S->sAdjN[t]; S->sSaved[1] = S->sSmN[t]; }
            if (t < N_) {
                if (t < i - 1 && S->sAdjN[t] > 0.5f) e = __expf(xq + S->sKsc[t]);
                float b0 = e * S->sSmN[t];
                S->sA0[t] = b0; S->sA1[t] = e - b0;
            }
            float ps = e;
            #pragma unroll
            for (int o = 32; o; o >>= 1) ps += __shfl_xor(ps, o);
            if (t < N_ && lane == 0) S->sRedS[wave] = ps;
        }
        __syncthreads();                                         // B1
        if (t < 384) {
            const int ilim = i - 1;
            const int kd = t >> 4, jp = t & 15;
            const uint32_t* hp = Hw + (size_t)kd * N_;
            float u0l = 0.f, u0h = 0.f, u1l = 0.f, u1h = 0.f;
            int j = jp;
            while (j + 48 < ilim) {
                uint32_t h0 = hp[j], h1 = hp[j + 16], h2 = hp[j + 32], h3 = hp[j + 48];
                float b0, b1;
                b0 = S->sA0[j];      b1 = S->sA1[j];
                u0l = fmaf(b0, bflo(h0), u0l); u0h = fmaf(b0, bfhi(h0), u0h);
                u1l = fmaf(b1, bflo(h0), u1l); u1h = fmaf(b1, bfhi(h0), u1h);
                b0 = S->sA0[j + 16]; b1 = S->sA1[j + 16];
                u0l = fmaf(b0, bflo(h1), u0l); u0h = fmaf(b0, bfhi(h1), u0h);
                u1l = fmaf(b1, bflo(h1), u1l); u1h = fmaf(b1, bfhi(h1), u1h);
                b0 = S->sA0[j + 32]; b1 = S->sA1[j + 32];
                u0l = fmaf(b0, bflo(h2), u0l); u0h = fmaf(b0, bfhi(h2), u0h);
                u1l = fmaf(b1, bflo(h2), u1l); u1h = fmaf(b1, bfhi(h2), u1h);
                b0 = S->sA0[j + 48]; b1 = S->sA1[j + 48];
                u0l = fmaf(b0, bflo(h3), u0l); u0h = fmaf(b0, bfhi(h3), u0h);
                u1l = fmaf(b1, bflo(h3), u1l); u1h = fmaf(b1, bfhi(h3), u1h);
                j += 64;
            }
            for (; j < ilim; j += 16) {
                uint32_t hv = hp[j];
                float b0 = S->sA0[j], b1 = S->sA1[j];
                u0l = fmaf(b0, bflo(hv), u0l); u0h = fmaf(b0, bfhi(hv), u0h);
                u1l = fmaf(b1, bflo(hv), u1l); u1h = fmaf(b1, bfhi(hv), u1h);
            }
            #pragma unroll
            for (int o = 1; o <= 8; o <<= 1) {
                u0l += __shfl_xor(u0l, o); u0h += __shfl_xor(u0h, o);
                u1l += __shfl_xor(u1l, o); u1h += __shfl_xor(u1h, o);
            }
            if (jp == 0) {
                S->su0[2 * kd] = u0l; S->su0[2 * kd + 1] = u0h;
                S->su1[2 * kd] = u1l; S->su1[2 * kd + 1] = u1h;
            }
        } else {
            const int u = t - 384;
            const int inx = (i + 1 < N_) ? i + 1 : N_ - 1;
            if (!ISL2) {
                for (int q = u; q < 260; q += 192) {
                    if (q < 64)
                        *(float4*)&S->sAdjN[4 * q] = *(const float4*)(adjB + (size_t)inx * N_ + 4 * q);
                    else if (q < 128) { int q2 = q - 64;
                        *(float4*)&S->sSmN[4 * q2] = *(const float4*)(smB + (size_t)inx * N_ + 4 * q2); }
                    else if (q < 140) { int q2 = q - 128;
                        *(float4*)&S->sXv[4 * q2] = *(const float4*)(xin + (size_t)row * G3 + dg0 + 4 * q2); }
                    else if (q < 212) { int q2 = q - 140; int g = q2 / 12, o = q2 - 12 * g;
                        *(float4*)&S->sPre[g * DS + 4 * o] =
                            *(const float4*)(PREg + (size_t)row * G6 + g * DH_ + dg0 + 4 * o); }
                    else { int q2 = q - 212;
                        *(float4*)&S->sXq[4 * q2] = *(const float4*)(xin + (size_t)(b * N_ + inx) * G3 + 4 * q2); }
                }
            } else {
                for (int q = u; q < 321; q += 192) {
                    if (q < 64)
                        *(float4*)&S->sAdjN[4 * q] = *(const float4*)(adjB + (size_t)inx * N_ + 4 * q);
                    else if (q < 128) { int q2 = q - 64;
                        *(float4*)&S->sSmN[4 * q2] = *(const float4*)(smB + (size_t)inx * N_ + 4 * q2); }
                    else if (q < 176) {
                        int d = q - 128;
                        const u64* p = HcR + ((size_t)row * NW + w) * DS + d;
                        u64 v; do { v = agload(p); } while ((uint32_t)(v >> 32) != (uint32_t)(STH + i));
                        S->sXv[d] = __uint_as_float((uint32_t)v);
                    } else if (q < 320) {
                        int qq = q - 176;
                        const u64* p = PREcR + ((size_t)row * NW + w) * 144 + qq;
                        u64 v; do { v = agload(p); } while ((uint32_t)(v >> 32) != (uint32_t)(STP + i));
                        uint32_t pl = (uint32_t)v;
                        S->sPre[2 * qq] = bflo(pl); S->sPre[2 * qq + 1] = bfhi(pl);
                    } else {
                        const u64* p = XQcR + b * N_ + inx;
                        u64 v; do { v = agload(p); } while ((uint32_t)(v >> 32) != (uint32_t)(STQ + inx));
                        S->sSaved[3] = __uint_as_float((uint32_t)v);
                    }
                }
            }
            if (t == 575) {
                const uint32_t ex = (uint32_t)(stamp - 1);
                u64 k0, k1, k2, k3;
                do {
                    k0 = agload(&Kdl[fi + 0]); k1 = agload(&Kdl[fi + 1]);
                    k2 = agload(&Kdl[fi + 2]); k3 = agload(&Kdl[fi + 3]);
                } while ((uint32_t)(k0 >> 32) != ex || (uint32_t)(k1 >> 32) != ex ||
                         (uint32_t)(k2 >> 32) != ex || (uint32_t)(k3 >> 32) != ex);
                float kdot = __uint_as_float((uint32_t)k0) + __uint_as_float((uint32_t)k1)
                           + __uint_as_float((uint32_t)k2) + __uint_as_float((uint32_t)k3);
                float adjI1 = S->sSaved[0], smI1 = S->sSaved[1];
                float e1 = (adjI1 > 0.5f) ? __expf(xq + kdot) : 0.f;
                float Ssum = S->sRedS[0] + S->sRedS[1] + S->sRedS[2] + S->sRedS[3] + e1;
                S->sKsc[i - 1] = kdot;
                float c0 = e1 * smI1;
                S->sA0[i - 1] = c0; S->sA1[i - 1] = e1 - c0;
                S->sSaved[2] = 1.f / Ssum;
            }
        }
        __syncthreads();                                         // B2
        if (t < DH_) {
            float mp = 0.f, h0a = 0.f, h1a = 0.f;
            #pragma unroll 4
            for (int kq = 0; kq < 12; ++kq) {
                uint4 wv = S->Wr4s[kq * DH_ + t];
                const int k0 = 4 * kq;
                float lo, hi;
                lo = bflo(wv.x); hi = bfhi(wv.x);
                mp = fmaf(S->su0[k0 + 0], lo, mp); mp = fmaf(S->su1[k0 + 0], hi, mp);
                h0a = fmaf(S->sHn[k0 + 0], lo, h0a); h1a = fmaf(S->sHn[k0 + 0], hi, h1a);
                lo = bflo(wv.y); hi = bfhi(wv.y);
                mp = fmaf(S->su0[k0 + 1], lo, mp); mp = fmaf(S->su1[k0 + 1], hi, mp);
                h0a = fmaf(S->sHn[k0 + 1], lo, h0a); h1a = fmaf(S->sHn[k0 + 1], hi, h1a);
                lo = bflo(wv.z); hi = bfhi(wv.z);
                mp = fmaf(S->su0[k0 + 2], lo, mp); mp = fmaf(S->su1[k0 + 2], hi, mp);
                h0a = fmaf(S->sHn[k0 + 2], lo, h0a); h1a = fmaf(S->sHn[k0 + 2], hi, h1a);
                lo = bflo(wv.w); hi = bfhi(wv.w);
                mp = fmaf(S->su0[k0 + 3], lo, mp); mp = fmaf(S->su1[k0 + 3], hi, mp);
                h0a = fmaf(S->sHn[k0 + 3], lo, h0a); h1a = fmaf(S->sHn[k0 + 3], hi, h1a);
            }
            float invS = S->sSaved[2];
            mp = (mp + S->sA0[i - 1] * h0a + S->sA1[i - 1] * h1a) * invS;
            agstore(&MPsl[(size_t)(fi + w) * DH_ + t], packvs(mp, stamp));
            const int w1 = (w + 1) & 3, w2 = (w + 2) & 3, w3 = (w + 3) & 3;
            u64* pA = &MPsl[(size_t)(fi + w1) * DH_ + t];
            u64* pB = &MPsl[(size_t)(fi + w2) * DH_ + t];
            u64* pC = &MPsl[(size_t)(fi + w3) * DH_ + t];
            const uint32_t ex = (uint32_t)stamp;
            u64 vA, vB, vC;
            do {
                vA = agload(pA); vB = agload(pB); vC = agload(pC);
            } while ((uint32_t)(vA >> 32) != ex || (uint32_t)(vB >> 32) != ex ||
                     (uint32_t)(vC >> 32) != ex);
            S->sM[t] = mp + __uint_as_float((uint32_t)vA)
                          + __uint_as_float((uint32_t)vB)
                          + __uint_as_float((uint32_t)vC);
        } else if (w == 0 && t < 448) {
            int j = t - 192;
            AsB[(size_t)i * N_ + j] = (S->sA0[j] + S->sA1[j]) * S->sSaved[2];
        }
        __syncthreads();                                         // B3
        {
            const int c = t >> 1, kh = t & 1;
            const uint4* wp = S->Wlds4 + (12 * kh) * GC + c;
            float g = 0.f;
            #pragma unroll 4
            for (int p4 = 0; p4 < 12; ++p4) {
                uint4 wv = wp[p4 * GC];
                const int m0 = 8 * (12 * kh + p4);
                g = fmaf(S->sM[m0 + 0], bflo(wv.x), g); g = fmaf(S->sM[m0 + 1], bfhi(wv.x), g);
                g = fmaf(S->sM[m0 + 2], bflo(wv.y), g); g = fmaf(S->sM[m0 + 3], bfhi(wv.y), g);
                g = fmaf(S->sM[m0 + 4], bflo(wv.z), g); g = fmaf(S->sM[m0 + 5], bfhi(wv.z), g);
                g = fmaf(S->sM[m0 + 6], bflo(wv.w), g); g = fmaf(S->sM[m0 + 7], bfhi(wv.w), g);
            }
            g += __shfl_xor(g, 1);
            if (kh == 0) S->sGc[c] = g;
        }
        __syncthreads();                                         // B4
        {
            float hn = 0.f;
            if (t < DS) {
                float Mv = S->sM[dg0 + t];
                float r1 = sigm(S->sPre[t] + S->sGc[t]);
                float z1 = sigm(S->sPre[DS + t] + S->sGc[DS + t]);
                float n1 = tanhf_(S->sPre[2 * DS + t] + r1 * (S->sGc[2 * DS + t] + g2b));
                float Cv = (1.f - z1) * n1 + z1 * Mv;
                float r2 = sigm(S->sGc[3 * DS + t] + S->sPre[3 * DS + t]);
                float z2 = sigm(S->sGc[4 * DS + t] + S->sPre[4 * DS + t]);
                float n2 = tanhf_(S->sGc[5 * DS + t] + g5b + r2 * S->sPre[5 * DS + t]);
                hn = Cv + (1.f - z2) * n2 + z2 * S->sXv[t];
                S->sHn[t] = hn;
                hout[(size_t)row * G3 + dg0 + t] = hn;
                if (!ISL2) HcW[((size_t)row * NW + w) * DS + t] = packvs(hn, STH + i);
            }
            if (wave == 0) {
                float v = hn * wkv;
                #pragma unroll
                for (int o = 32; o; o >>= 1) v += __shfl_xor(v, o);
                if (lane == 0) agstore(&Kdl[fi + w], packvs(v, stamp));
            }
            if (t < KD) Hw[(size_t)t * N_ + i] = f2bf(S->sHn[2 * t]) | (f2bf(S->sHn[2 * t + 1]) << 16);
            if (!ISL2) {
                float px = (t < DH_) ? S->sXq[t] * wqv : 0.f;
                #pragma unroll
                for (int o = 32; o; o >>= 1) px += __shfl_xor(px, o);
                if (t < DH_ && lane == 0) S->sRedX[wave] = px;
            }
        }
        __syncthreads();                                         // B5
        xq = ISL2 ? S->sSaved[3] : (S->sRedX[0] + S->sRedX[1] + S->sRedX[2]);
    }
}

// ---------------------------------------------------------------------------
// PRE worker (unchanged r8)
// ---------------------------------------------------------------------------
__device__ void worker_body(WorkSm* Wm, int b, int w, int t,
    const uint32_t* __restrict__ Wp4g, const float* __restrict__ bias2,
    const float* __restrict__ wq2,
    const u64* __restrict__ HcR, u64* __restrict__ PREcW, u64* __restrict__ XQcW)
{
    const int lane = t & 63, wave = t >> 6;
    { uint32_t* wl = (uint32_t*)Wm->Wp4; for (int q = t; q < 27648; q += 576) wl[q] = Wp4g[q]; }
    const int c = t >> 1, kh = t & 1;
    float bv = 0.f;
    if (kh == 0) bv = bias2[192 * (c / DS) + w * DS + (c % DS)];
    float wqt = (t < DH_) ? wq2[t] : 0.f;
    for (int i = 0; i < N_; ++i) {
        if (t < DH_) {
            const u64* p = HcR + ((size_t)(b * N_ + i) * NW + (t / DS)) * DS + (t % DS);
            u64 v; do { v = agload(p); } while ((uint32_t)(v >> 32) != (uint32_t)(STH + i));
            Wm->sX[t] = __uint_as_float((uint32_t)v);
        }
        __syncthreads();
        {
            const uint4* wp = Wm->Wp4 + (12 * kh) * GC + c;
            float g = 0.f;
            #pragma unroll 4
            for (int p4 = 0; p4 < 12; ++p4) {
                uint4 wv = wp[p4 * GC];
                const int m0 = 8 * (12 * kh + p4);
                g = fmaf(Wm->sX[m0 + 0], bflo(wv.x), g); g = fmaf(Wm->sX[m0 + 1], bfhi(wv.x), g);
                g = fmaf(Wm->sX[m0 + 2], bflo(wv.y), g); g = fmaf(Wm->sX[m0 + 3], bfhi(wv.y), g);
                g = fmaf(Wm->sX[m0 + 4], bflo(wv.z), g); g = fmaf(Wm->sX[m0 + 5], bfhi(wv.z), g);
                g = fmaf(Wm->sX[m0 + 6], bflo(wv.w), g); g = fmaf(Wm->sX[m0 + 7], bfhi(wv.w), g);
            }
            g += __shfl_xor(g, 1);
            if (kh == 0) Wm->sPv[c] = g + bv;
        }
        if (w == 0) {
            float px = (t < DH_) ? Wm->sX[t] * wqt : 0.f;
            #pragma unroll
            for (int o = 32; o; o >>= 1) px += __shfl_xor(px, o);
            if (t < DH_ && lane == 0) Wm->sRed[wave] = px;
        }
        __syncthreads();
        if (t < 144) {
            u64 v = ((u64)(uint32_t)(STP + i) << 32)
                  | f2bf(Wm->sPv[2 * t]) | (f2bf(Wm->sPv[2 * t + 1]) << 16);
            agstore(&PREcW[((size_t)(b * N_ + i) * NW + w) * 144 + t], v);
        }
        if (w == 0 && t == 0)
            agstore(&XQcW[b * N_ + i],
                    packvs(Wm->sRed[0] + Wm->sRed[1] + Wm->sRed[2], STQ + i));
        __syncthreads();
    }
}

// ---------------------------------------------------------------------------
// Single fused kernel: prepack + fc1 + PRE-l1 prologue, pipelined dual-layer
// scan + PRE workers, MLP epilogue.
// ---------------------------------------------------------------------------
__global__ __launch_bounds__(576, 1) void pipeline_kernel(
    const float* __restrict__ features, const float* __restrict__ fc1_w,
    const float* __restrict__ fc1_b,
    const float* __restrict__ adj, const float* __restrict__ smask,
    const float* __restrict__ gatw,
    const float* __restrict__ wr0, const float* __restrict__ wr1,
    const float* __restrict__ c_wih, const float* __restrict__ c_whh,
    const float* __restrict__ c_bih, const float* __restrict__ c_bhh,
    const float* __restrict__ p_wih, const float* __restrict__ p_whh,
    const float* __restrict__ p_bih, const float* __restrict__ p_bhh,
    const float* __restrict__ mw0, const float* __restrict__ mb0,
    const float* __restrict__ mw1, const float* __restrict__ mb1,
    const float* __restrict__ mw2, const float* __restrict__ mb2,
    float* __restrict__ Hcat, float* __restrict__ PREg,
    float* __restrict__ WpreT, uint32_t* __restrict__ W4,
    uint32_t* __restrict__ Wr4, uint32_t* __restrict__ Wp4w,
    float* __restrict__ biasPre, float* __restrict__ gbx,
    uint32_t* __restrict__ Hb, u64* __restrict__ MPs, u64* __restrict__ Kd,
    u64* __restrict__ Hc, u64* __restrict__ PREc, u64* __restrict__ XQc,
    u64* __restrict__ Fp, u64* __restrict__ Fd,
    float* __restrict__ out)
{
    __shared__ __align__(16) char smem[sizeof(ScanSm)];
    const int blk = blockIdx.x, t = threadIdx.x;
    const int wgid = blk;
    const int b = blk & 7, r12 = blk >> 3;
    const int role = r12 >> 2, w = r12 & 3;

    // ---- prepack slices (all WGs) ------------------------------------------
    for (int j = 0; j < 4; ++j) {
        int idx = wgid * 576 + t + 55296 * j;
        prepack_slice(idx, wr0, wr1, c_wih, c_whh, c_bih, c_bhh,
                      p_wih, p_whh, p_bih, p_bhh,
                      WpreT, W4, Wr4, Wp4w, biasPre, gbx);
    }
    flag_sync(Fp, wgid, t, SPK);

    // ---- fc1 + PRE-l1 prologue ---------------------------------------------
    prologue(smem, wgid, t, features, fc1_w, fc1_b, WpreT, biasPre,
             Hcat, PREg, Fp);

    // ---- roles -------------------------------------------------------------
    float* As = out + 393216;
    if (role == 0) {
        scan_body<0>((ScanSm*)smem, b, w, t,
            Hcat, Hcat + 192, PREg, adj, smask,
            W4, Wr4, gbx, gatw,
            Hb + (size_t)(b * NW + w) * KD * N_, MPs, Kd,
            Hc, nullptr, nullptr, nullptr,
            As + (size_t)b * (L_ * N_ * N_), 1);
        __threadfence();
        __syncthreads();
        if (t == 0) agstore(&Fd[b * 8 + w], packvs(0.f, SDN));
    } else if (role == 2) {
        scan_body<1>((ScanSm*)smem, b, w, t,
            nullptr, Hcat + 384, nullptr, adj, smask,
            W4 + NW * 27648, Wr4 + NW * 9216, gbx + 384, gatw + 384,
            Hb + (size_t)(32 + b * NW + w) * KD * N_,
            MPs + (size_t)8 * NW * DH_, Kd + 8 * NW,
            nullptr, Hc, PREc, XQc,
            As + (size_t)b * (L_ * N_ * N_) + N_ * N_, 30001);
        __threadfence();
        __syncthreads();
        if (t == 0) agstore(&Fd[b * 8 + 4 + w], packvs(0.f, SDN));
    } else {
        worker_body((WorkSm*)smem, b, w, t,
            Wp4w + (size_t)w * 27648, biasPre + G6, gatw + 384,
            Hc, PREc, XQc);
    }

    // ---- MLP epilogue (all WGs) --------------------------------------------
    mlp_tail(smem, wgid, t, Hcat, mw0, mb0, mw1, mb1, mw2, mb2, out, Fd);
}

// ---------------------------------------------------------------------------
extern "C" void kernel_launch(void* const* d_in, const int* in_sizes, int n_in,
                              void* d_out, int out_size, void* d_ws, size_t ws_size,
                              hipStream_t stream)
{
    const float* features = (const float*)d_in[0];
    const float* adj      = (const float*)d_in[1];
    const float* smask    = (const float*)d_in[2];
    const float* fc1_w = (const float*)d_in[5];
    const float* fc1_b = (const float*)d_in[6];
    const float* gat_w = (const float*)d_in[7];
    const float* wr0   = (const float*)d_in[9];
    const float* wr1   = (const float*)d_in[10];
    const float* c_wih = (const float*)d_in[11];
    const float* c_whh = (const float*)d_in[12];
    const float* c_bih = (const float*)d_in[13];
    const float* c_bhh = (const float*)d_in[14];
    const float* p_wih = (const float*)d_in[15];
    const float* p_whh = (const float*)d_in[16];
    const float* p_bih = (const float*)d_in[17];
    const float* p_bhh = (const float*)d_in[18];
    const float* mw0 = (const float*)d_in[19];
    const float* mb0 = (const float*)d_in[20];
    const float* mw1 = (const float*)d_in[21];
    const float* mb1 = (const float*)d_in[22];
    const float* mw2 = (const float*)d_in[23];
    const float* mb2 = (const float*)d_in[24];
    float* out = (float*)d_out;

    char* wsb = (char*)d_ws;
    size_t off = 0;
    auto carve = [&](size_t bytes) -> char* {
        char* p = wsb + off;
        off = (off + bytes + 255) & ~(size_t)255;
        return p;
    };
    float* Hcat     = (float*)carve(2048ull * 576 * 4);
    float* PREg     = (float*)carve(2048ull * 1152 * 4);
    float* WpreT    = (float*)carve(192ull * 1152 * 4);
    uint32_t* W4    = (uint32_t*)carve(2ull * NW * 27648 * 4);
    uint32_t* Wr4   = (uint32_t*)carve(2ull * NW * 9216 * 4);
    uint32_t* Wp4w  = (uint32_t*)carve((size_t)NW * 27648 * 4);
    float* biasPre  = (float*)carve(2ull * 1152 * 4);
    float* gbx      = (float*)carve(2ull * 384 * 4);
    uint32_t* Hb    = (uint32_t*)carve(64ull * KD * 256 * 4);
    u64* MPs        = (u64*)carve(2ull * 8 * NW * DH_ * 8);
    u64* Kd         = (u64*)carve(2ull * 8 * NW * 8);
    u64* Hc         = (u64*)carve(8ull * 256 * NW * DS * 8);
    u64* PREc       = (u64*)carve(8ull * 256 * NW * 144 * 8);
    u64* XQc        = (u64*)carve(8ull * 256 * 8);
    u64* Fp         = (u64*)carve(288ull * 8);
    u64* Fd         = (u64*)carve(64ull * 8);

    pipeline_kernel<<<dim3(96), 576, 0, stream>>>(
        features, fc1_w, fc1_b, adj, smask, gat_w,
        wr0, wr1, c_wih, c_whh, c_bih, c_bhh, p_wih, p_whh, p_bih, p_bhh,
        mw0, mb0, mw1, mb1, mw2, mb2,
        Hcat, PREg, WpreT, W4, Wr4, Wp4w, biasPre, gbx,
        Hb, MPs, Kd, Hc, PREc, XQc, Fp, Fd, out);
}